// Round 5
// baseline (1532.795 us; speedup 1.0000x reference)
//
#include <hip/hip_runtime.h>
#include <math.h>

#define B_ 8
#define N_ 4096
#define K_ 20
#define KS_ 24          // approx-select width; exact rescore trims to K_ (R3-validated margin)
#define BN_ (B_*N_)

typedef __attribute__((ext_vector_type(8))) short bf16x8;
typedef __attribute__((ext_vector_type(4))) float f32x4;

// ---------------------------------------------------------------- BN stats finalize (deterministic, fp64)
// R10: float atomicAdd stats were order-nondeterministic across graph replays ->
// kNN2 boundary flip -> post-timing divergence.  R11: the deterministic fp32
// order landed on the WRONG side of a ~1-ULP distance tie (absmax 0.1177).
// All stats now accumulate in DOUBLE (partials + reduce + mean/var/rstd), so our
// stats are ~exact; the x1b-feeding BN applies the reference's elementwise op
// order; rescore uses the reference's full d formula.  DO NOT reintroduce
// atomicAdd or fold these back into fp32/FMA on the conv1 path.
// part layout: [nb][2*H] doubles (sum(H), sumsq(H) per block row).
__global__ __launch_bounds__(256) void finalize_parts_kernel(
    const double* __restrict__ part, int nb, int H, double invCount, float* __restrict__ st)
{
    __shared__ double red[256], red2[256];
    const int c = blockIdx.x, t = threadIdx.x;
    double s = 0., s2 = 0.;
    for (int b = t; b < nb; b += 256) {
        s  += part[(size_t)b*2*H + c];
        s2 += part[(size_t)b*2*H + H + c];
    }
    red[t] = s; red2[t] = s2;
    __syncthreads();
    #pragma unroll
    for (int off = 128; off; off >>= 1) {
        if (t < off) { red[t] += red[t+off]; red2[t] += red2[t+off]; }
        __syncthreads();
    }
    if (t == 0) {
        double mean = red[0] * invCount;
        double var  = fmax(red2[0] * invCount - mean * mean, 0.);
        st[2*H + c] = (float)mean;
        st[3*H + c] = (float)(1.0 / sqrt(var + 1e-5));
    }
}

// ---------------------------------------------------------------- kNN, C=4
// R7-validated (value, candidate-index) lexicographic argmin — matches jax
// top_k tie-break; this kernel is reference-defining (no rescore guard), so
// its selection must stay EXACT.  DO NOT replace with DPP (R9) or relax.
// R14: VGPR_Count=64 showed d[64] was SPILLED TO SCRATCH in the 1024-thread
// version (launch_bounds capped the allocator) — the real bottleneck, not the
// shuffle chain.  Now 256-thread blocks with __launch_bounds__(256,2): 256-VGPR
// budget keeps d[64] in registers.  2-winner rounds (R13) reverted: neutral on
// the chain, extra DS ops.
__global__ __launch_bounds__(256, 2) void knn4_kernel(const float* __restrict__ x, int* __restrict__ idxout)
{
    __shared__ float4 xt[N_];   // 64 KB
    const int b = blockIdx.y;
    const int t = threadIdx.x;
    const float4* xg = (const float4*)x + b*N_;
    for (int e = t; e < N_; e += 256) xt[e] = xg[e];
    __syncthreads();
    const int w = t >> 6, L = t & 63;
    const int n = blockIdx.x*4 + w;
    const float4 q = xt[n];
    float d[64];
    #pragma unroll
    for (int s = 0; s < 64; ++s) {
        float4 v = xt[(s<<6) | L];
        float nn = v.x*v.x + v.y*v.y + v.z*v.z + v.w*v.w;
        float dp = q.x*v.x + q.y*v.y + q.z*v.z + q.w*v.w;
        d[s] = nn - 2.f*dp;   // |xn|^2 dropped: rank-equivalent
    }
    const float MX = 3.4e38f;
    float m1 = MX, m2 = MX, m3 = MX; int i1 = 0, i2 = 0, i3 = 0;
    #pragma unroll
    for (int j = 0; j < 64; ++j) {
        float v = d[j];
        bool c1 = v < m1, c2 = v < m2, c3 = v < m3;
        m3 = c2 ? m2 : (c3 ? v : m3);
        i3 = c2 ? i2 : (c3 ? j : i3);
        m2 = c1 ? m1 : (c2 ? v : m2);
        i2 = c1 ? i1 : (c2 ? j : i2);
        m1 = c1 ? v : m1;
        i1 = c1 ? j : i1;
    }
    unsigned long long used = 0;
    int mywin = 0;
    for (int r = 0; r < K_; ++r) {
        float bv = m1; int bg = (i1<<6) | L;
        #pragma unroll
        for (int off = 32; off; off >>= 1) {
            float ov = __shfl_xor(bv, off);
            int   og = __shfl_xor(bg, off);
            bool tk = (ov < bv) || (ov == bv && og < bg);
            bv = tk ? ov : bv; bg = tk ? og : bg;
        }
        if (L == r) mywin = bg;
        if (L == (bg & 63)) {
            used |= 1ull << i1;
            m1 = m2; i1 = i2; m2 = m3; i2 = i3; m3 = MX;
            if (m1 == MX) {
                m2 = MX; m3 = MX; i1 = 0; i2 = 0; i3 = 0;
                #pragma unroll
                for (int j = 0; j < 64; ++j) {
                    float v = ((used >> j) & 1ull) ? MX : d[j];
                    bool c1 = v < m1, c2 = v < m2, c3 = v < m3;
                    m3 = c2 ? m2 : (c3 ? v : m3);
                    i3 = c2 ? i2 : (c3 ? j : i3);
                    m2 = c1 ? m1 : (c2 ? v : m2);
                    i2 = c1 ? i1 : (c2 ? j : i2);
                    m1 = c1 ? v : m1;
                    i1 = c1 ? j : i1;
                }
            }
        }
    }
    if (L < K_) idxout[(b*N_ + n)*K_ + L] = mywin;
}

// ---------------------------------------------------------------- fp32 -> bf16 RNE
static __device__ inline unsigned short f2bf(float f)
{
    unsigned u = __float_as_uint(f);
    unsigned r = (u + 0x7fffu + ((u >> 16) & 1u)) >> 16;   // RNE
    return (unsigned short)r;
}

__global__ __launch_bounds__(256) void prep64_kernel(const float* __restrict__ x,
                                                     unsigned short* __restrict__ Xh,
                                                     unsigned short* __restrict__ Xl,
                                                     float* __restrict__ nrm)
{
    const int t = threadIdx.x, L = t & 63;
    const int row = blockIdx.x*4 + (t >> 6);
    const float v = x[row*64 + L];
    unsigned short h = f2bf(v);
    float hf = __uint_as_float((unsigned)h << 16);
    unsigned short l = f2bf(v - hf);
    Xh[row*64 + L] = h;
    Xl[row*64 + L] = l;
    float s = v * v;
    #pragma unroll
    for (int off = 32; off; off >>= 1) s += __shfl_xor(s, off);
    if (L == 0) nrm[row] = s;
}

// ---------------------------------------------------------------- kNN, C=64 via MFMA (split-bf16 Gram, approx)
// v7 (R14): d[64] ELIMINATED — it was scratch-resident (VGPR_Count=64 < 64
// floats) and its latency dominated the kernel (~80K cyc/wave of scratch ops).
// Each lane now keeps a sorted top-8 in registers (m[0..7]), built by scanning
// each ck's dist tile directly from LDS (branchless 8-level bubble insert,
// static indexing only — rule #20).  No used-mask, no rescan: a lane that wins
// 8 of the 24 extractions drops out (P ~ 5e-9/query; pool self-heals with
// next-best + KS_-K_ margin + exact rescore).  Keys carry the slot in the low
// 6 mantissa bits (R12); 2-winner butterfly rounds (R13); XOR-swizzled dist
// (R12, conflict-free).
__global__ __launch_bounds__(1024, 4) void knn64v4_kernel(
    const unsigned short* __restrict__ Xh, const unsigned short* __restrict__ Xl,
    const float* __restrict__ nrm, int* __restrict__ idx24)
{
    __shared__ float dist[16*1024];   // exactly 64 KB
    const int b = blockIdx.y, t = threadIdx.x;
    const int w = t >> 6, L = t & 63;
    const int q0 = blockIdx.x * 16;
    const int m = L & 15, q4 = L >> 4, kq = q4 * 8;
    const size_t rowbase = (size_t)b * N_ * 64;
    const int swzW = q4 << 4;         // write-side column XOR (qrow>>2 == q4)
    const int swzR = (w >> 2) << 4;   // read-side column XOR (query row w)

    const unsigned short* aph = Xh + rowbase + (size_t)(q0 + m)*64 + kq;
    const unsigned short* apl = Xl + rowbase + (size_t)(q0 + m)*64 + kq;
    const bf16x8 a_h0 = *(const bf16x8*)(aph);
    const bf16x8 a_h1 = *(const bf16x8*)(aph + 32);
    const bf16x8 a_l0 = *(const bf16x8*)(apl);
    const bf16x8 a_l1 = *(const bf16x8*)(apl + 32);

    const float MX = 3.4e38f;
    float sm[8];
    #pragma unroll
    for (int l = 0; l < 8; ++l) sm[l] = MX;

    #pragma unroll
    for (int ck = 0; ck < 4; ++ck) {
        const int cq = ck * 1024;
        const unsigned slotW = (unsigned)(ck*16 + w);   // global slot of this wave's candidates
        __syncthreads();
        #pragma unroll
        for (int tt = 0; tt < 4; ++tt) {
            const int cbase = w*64 + tt*16;
            const unsigned short* bph = Xh + rowbase + (size_t)(cq + cbase + m)*64 + kq;
            const unsigned short* bpl = Xl + rowbase + (size_t)(cq + cbase + m)*64 + kq;
            bf16x8 b_h0 = *(const bf16x8*)(bph);
            bf16x8 b_h1 = *(const bf16x8*)(bph + 32);
            bf16x8 b_l0 = *(const bf16x8*)(bpl);
            bf16x8 b_l1 = *(const bf16x8*)(bpl + 32);
            f32x4 acc = {0.f, 0.f, 0.f, 0.f};
            acc = __builtin_amdgcn_mfma_f32_16x16x32_bf16(a_h0, b_h0, acc, 0, 0, 0);
            acc = __builtin_amdgcn_mfma_f32_16x16x32_bf16(a_h1, b_h1, acc, 0, 0, 0);
            acc = __builtin_amdgcn_mfma_f32_16x16x32_bf16(a_l0, b_h0, acc, 0, 0, 0);
            acc = __builtin_amdgcn_mfma_f32_16x16x32_bf16(a_l1, b_h1, acc, 0, 0, 0);
            acc = __builtin_amdgcn_mfma_f32_16x16x32_bf16(a_h0, b_l0, acc, 0, 0, 0);
            acc = __builtin_amdgcn_mfma_f32_16x16x32_bf16(a_h1, b_l1, acc, 0, 0, 0);
            const float nv = nrm[b*N_ + cq + cbase + m];
            const int colW = (cbase + m) ^ swzW;
            #pragma unroll
            for (int r = 0; r < 4; ++r) {
                float dv = nv - 2.f*acc[r];
                unsigned key = (__float_as_uint(dv) & ~63u) | slotW;
                dist[(q4*4 + r)*1024 + colW] = __uint_as_float(key);
            }
        }
        __syncthreads();
        // scan this ck's 16 values straight from LDS into the sorted top-8
        #pragma unroll
        for (int s = 0; s < 16; ++s) {
            float v = dist[w*1024 + (((s<<6) + L) ^ swzR)];
            #pragma unroll
            for (int l = 0; l < 8; ++l) {
                float lo = fminf(sm[l], v);
                v = fmaxf(sm[l], v);
                sm[l] = lo;
            }
        }
    }

    int mywin = 0;
    for (int r = 0; r < KS_/2; ++r) {
        float a1 = sm[0], a2 = sm[1];
        #pragma unroll
        for (int off = 32; off; off >>= 1) {
            float b1 = __shfl_xor(a1, off);
            float b2 = __shfl_xor(a2, off);
            float lo = fminf(a1, b1);
            float hi = fmaxf(a1, b1);
            a2 = fminf(hi, fminf(a2, b2));
            a1 = lo;
        }
        const unsigned long long t1 = __ballot(sm[0] == a1);
        const int wl1 = (int)__ffsll((unsigned long long)t1) - 1;
        if (L == 2*r) mywin = (int)(((__float_as_uint(a1) & 63u) << 6) | (unsigned)wl1);
        if (L == wl1) {
            #pragma unroll
            for (int l = 0; l < 7; ++l) sm[l] = sm[l+1];
            sm[7] = MX;
        }
        // winner2 = min(butterfly 2nd, wl1's current min)  [uniform readlane]
        const float w1m = __shfl(sm[0], wl1);
        const float gv2 = fminf(a2, w1m);
        const unsigned long long t2 = __ballot(sm[0] == gv2);
        const int wl2 = (int)__ffsll((unsigned long long)t2) - 1;
        if (L == 2*r+1) mywin = (int)(((__float_as_uint(gv2) & 63u) << 6) | (unsigned)wl2);
        if (L == wl2) {
            #pragma unroll
            for (int l = 0; l < 7; ++l) sm[l] = sm[l+1];
            sm[7] = MX;
        }
    }
    if (L < KS_) idx24[((size_t)b*N_ + q0 + w)*KS_ + L] = mywin;
}

// ---------------------------------------------------------------- exact fp32 rescore of the KS_ candidates
// R11: d matches the reference formula exactly.  R13: two winners per round
// (10 rounds).  Exact without a readlane fix: every lane holds ONE always-valid
// candidate, so the butterfly's top-2 over (dv,MX) pairs is the true top-2;
// candidate indices are unique (extraction marks used), so pops are unambiguous.
__global__ __launch_bounds__(256) void rescore_kernel(const float* __restrict__ x1, const float* __restrict__ nrm,
                                                      const int* __restrict__ idx24, int* __restrict__ idxout)
{
    const int t = threadIdx.x, w = t >> 6, L = t & 63;
    const int p = blockIdx.x*4 + w;
    const int bbase = p & ~(N_-1);
    const float MX = 3.4e38f;
    float dv = MX; int di = 0x7fffffff;
    if (L < KS_) {
        const int ci = idx24[(size_t)p*KS_ + L];
        const float4* qr = (const float4*)(x1 + (size_t)p*64);
        const float4* cr = (const float4*)(x1 + (size_t)(bbase + ci)*64);
        float dot = 0.f;
        #pragma unroll
        for (int i = 0; i < 16; ++i) {
            float4 a = qr[i], bx = cr[i];
            dot += a.x*bx.x + a.y*bx.y + a.z*bx.z + a.w*bx.w;
        }
        dv = __fsub_rn(__fadd_rn(nrm[p], nrm[bbase + ci]), 2.f*dot);
        di = ci;
    }
    int myfin = 0;
    for (int r = 0; r < K_/2; ++r) {
        float v1 = dv; int g1 = di;
        float v2 = MX; int g2 = 0x7fffffff;
        #pragma unroll
        for (int off = 32; off; off >>= 1) {
            float ov1 = __shfl_xor(v1, off); int og1 = __shfl_xor(g1, off);
            float ov2 = __shfl_xor(v2, off); int og2 = __shfl_xor(g2, off);
            bool c1 = (ov1 < v1) || (ov1 == v1 && og1 < g1);
            float hv = c1 ? v1 : ov1; int hg = c1 ? g1 : og1;
            v1 = c1 ? ov1 : v1;       g1 = c1 ? og1 : g1;
            bool c2 = (ov2 < v2) || (ov2 == v2 && og2 < g2);
            float l2v = c2 ? ov2 : v2; int l2g = c2 ? og2 : g2;
            bool c3 = (l2v < hv) || (l2v == hv && l2g < hg);
            v2 = c3 ? l2v : hv;  g2 = c3 ? l2g : hg;
        }
        if (L == 2*r)   myfin = g1;
        if (L == 2*r+1) myfin = g2;
        if (di == g1 || di == g2) dv = MX;
    }
    if (L < K_) idxout[(size_t)p*K_ + L] = myfin;
}

// ---------------------------------------------------------------- P/Q precompute
__global__ __launch_bounds__(256) void pq1_kernel(const float* __restrict__ x, const float* __restrict__ W,
                                                  const float* __restrict__ b1,
                                                  float* __restrict__ P, float* __restrict__ Q)
{
    __shared__ float wd[256], wb[256];
    const int t = threadIdx.x;
    wd[t] = W[t] - W[256 + t];
    wb[t] = W[256 + t];
    __syncthreads();
    const int p = blockIdx.x*4 + (t >> 6), c = t & 63;
    const float4 xv = ((const float4*)x)[p];
    float Pv = b1[c] + xv.x*wd[c] + xv.y*wd[64+c] + xv.z*wd[128+c] + xv.w*wd[192+c];
    float Qv =         xv.x*wb[c] + xv.y*wb[64+c] + xv.z*wb[128+c] + xv.w*wb[192+c];
    P[p*64 + c] = Pv;
    Q[p*64 + c] = Qv;
}

__global__ __launch_bounds__(256) void pq2_kernel(const float* __restrict__ x1, const float* __restrict__ W,
                                                  const float* __restrict__ b1,
                                                  float* __restrict__ P, float* __restrict__ Q)
{
    __shared__ float wd[64*128], wb[64*128];
    const int t = threadIdx.x;
    for (int e = t; e < 8192; e += 256) {
        float wt = W[e], wbo = W[8192 + e];
        wd[e] = wt - wbo; wb[e] = wbo;
    }
    __syncthreads();
    const int pl = t >> 7, c = t & 127;
    const float b1v = b1[c];
    for (int p0 = blockIdx.x*2; p0 < BN_; p0 += gridDim.x*2) {
        const int p = p0 + pl;
        float Pv = b1v, Qv = 0.f;
        const float* xrow = x1 + p*64;
        #pragma unroll 8
        for (int k = 0; k < 64; ++k) {
            float xv = xrow[k];
            Pv += xv * wd[k*128 + c];
            Qv += xv * wb[k*128 + c];
        }
        P[p*128 + c] = Pv;
        Q[p*128 + c] = Qv;
    }
}

// ---------------------------------------------------------------- layer-1 BN stats (fp64 per-block partials)
template<int HO>
__global__ __launch_bounds__(256) void stats_l1_kernel(const float* __restrict__ P, const float* __restrict__ Q,
                                                       const int* __restrict__ idx, double* __restrict__ partOut)
{
    constexpr int G = 256/HO;
    __shared__ double red[256], red2[256];
    const int t = threadIdx.x, c = t % HO, g = t / HO;
    double s = 0., s2 = 0.;
    for (int p = blockIdx.x; p < BN_; p += gridDim.x) {
        const float Pv = P[p*HO + c];
        const int bbase = p & ~(N_-1);
        for (int j = g; j < K_; j += G) {
            int m = idx[p*K_ + j];
            float z = Pv + Q[(bbase + m)*HO + c];
            double zd = (double)z;
            s += zd; s2 += zd*zd;
        }
    }
    red[t] = s; red2[t] = s2;
    __syncthreads();
    if (t < HO) {
        double a = red[t], a2 = red2[t];
        #pragma unroll
        for (int q = 1; q < G; ++q) { a += red[q*HO + t]; a2 += red2[q*HO + t]; }
        partOut[(size_t)blockIdx.x*(2*HO) + t] = a;
        partOut[(size_t)blockIdx.x*(2*HO) + HO + t] = a2;
    }
}

// ---------------------------------------------------------------- EdgeConv layer-2, exact fp32 (conv1:
// its output feeds kNN2, which is flip-sensitive to ~1e-4 feature perturbation).
// R11: BN applied in the reference's elementwise op order (((z-m)*rstd)*g+be,
// separately rounded) — the folded z*ac+bc form differed by 1-2 ULP on x1 features.
template<int HO>
__global__ __launch_bounds__(256) void conv_l2_kernel(
    const float* __restrict__ P, const float* __restrict__ Q, const int* __restrict__ idx,
    const float* __restrict__ st1, const float* __restrict__ g1, const float* __restrict__ be1,
    const float* __restrict__ w2, const float* __restrict__ b2,
    float* __restrict__ zmax, float* __restrict__ zmin, double* __restrict__ partOut)
{
    __shared__ float w2s[HO*64];
    __shared__ float h1s[K_*HO];
    __shared__ float redA[256], redB[256];
    __shared__ double redD[256], redD2[256];
    const int t = threadIdx.x;
    const int cy = blockIdx.y;
    for (int e = t; e < HO*64; e += 256) {
        int c = e >> 6, cl = e & 63;
        w2s[e] = w2[c*HO + cy*64 + cl];
    }
    const int cA = t % HO;
    const float mA = st1[2*HO + cA], rA = st1[3*HO + cA];
    const float gA = g1[cA], beA = be1[cA];
    const int c2l = t & 63, jh = t >> 6;
    const float b2v = b2[cy*64 + c2l];
    double ssum = 0., ssq = 0.;
    for (int p = blockIdx.x; p < BN_; p += gridDim.x) {
        __syncthreads();
        const int bbase = p & ~(N_-1);
        const float Pv = P[p*HO + cA];
        for (int e = t; e < K_*HO; e += 256) {
            int j = e / HO;
            int m = idx[p*K_ + j];
            float z = Pv + Q[(bbase + m)*HO + cA];
            float bn = __fadd_rn(__fmul_rn(__fmul_rn(__fsub_rn(z, mA), rA), gA), beA);
            h1s[e] = fmaxf(bn, 0.f);
        }
        __syncthreads();
        float acc[5];
        #pragma unroll
        for (int q = 0; q < 5; ++q) acc[q] = b2v;
        for (int c = 0; c < HO; ++c) {
            float wv = w2s[c*64 + c2l];
            #pragma unroll
            for (int q = 0; q < 5; ++q)
                acc[q] += h1s[(jh + q*4)*HO + c] * wv;
        }
        float mx = acc[0], mn = acc[0];
        #pragma unroll
        for (int q = 0; q < 5; ++q) {
            mx = fmaxf(mx, acc[q]); mn = fminf(mn, acc[q]);
            double ad = (double)acc[q];
            ssum += ad; ssq += ad*ad;
        }
        redA[t] = mx; redB[t] = mn;
        __syncthreads();
        if (t < 64) {
            float M = redA[t], Mn = redB[t];
            #pragma unroll
            for (int g = 1; g < 4; ++g) { M = fmaxf(M, redA[g*64 + t]); Mn = fminf(Mn, redB[g*64 + t]); }
            zmax[p*HO + cy*64 + t] = M;
            zmin[p*HO + cy*64 + t] = Mn;
        }
    }
    __syncthreads();
    redD[t] = ssum; redD2[t] = ssq;
    __syncthreads();
    if (t < 64) {
        double s = redD[t], s2 = redD2[t];
        #pragma unroll
        for (int g = 1; g < 4; ++g) { s += redD[g*64 + t]; s2 += redD2[g*64 + t]; }
        partOut[(size_t)blockIdx.x*(2*HO) + cy*64 + t] = s;
        partOut[(size_t)blockIdx.x*(2*HO) + HO + cy*64 + t] = s2;
    }
}

// ---------------------------------------------------------------- W2^T split-bf16 prep
__global__ __launch_bounds__(256) void prep_w2t_kernel(const float* __restrict__ W,
                                                       unsigned short* __restrict__ wh,
                                                       unsigned short* __restrict__ wl, int HO)
{
    const int e = blockIdx.x*256 + threadIdx.x;   // e = k*HO + c
    const int k = e / HO, c = e % HO;
    const float v = W[e];
    unsigned short h = f2bf(v);
    float hf = __uint_as_float((unsigned)h << 16);
    wh[c*HO + k] = h;
    wl[c*HO + k] = f2bf(v - hf);
}

// ---------------------------------------------------------------- EdgeConv layer-2 via MFMA (split-bf16)
// conv2 only: output feeds the classifier (value-continuous), bf16-split safe.
template<int HO>
__global__ __launch_bounds__(256) void conv_l2_mfma_kernel(
    const float* __restrict__ P, const float* __restrict__ Q, const int* __restrict__ idx,
    const float* __restrict__ st1, const float* __restrict__ g1, const float* __restrict__ be1,
    const unsigned short* __restrict__ w2h, const unsigned short* __restrict__ w2l,
    const float* __restrict__ b2,
    float* __restrict__ zmax, float* __restrict__ zmin, double* __restrict__ partOut)
{
    constexpr int HOP = HO + 8;
    constexpr int CDP = HO + 1;
    constexpr int CTW = HO / 64;
    constexpr int KSn = HO / 32;
    constexpr int HSH = (HO == 128) ? 7 : 6;
    __shared__ __align__(16) short hs[2*80*HOP];
    __shared__ int sidx[80];
    float* cd = (float*)hs;

    const int t = threadIdx.x, w = t >> 6, L = t & 63;
    const int m16 = L & 15, q4 = L >> 4;

    const int kT = t & (HO - 1);
    const float ac = st1[3*HO + kT] * g1[kT];
    const float bc = be1[kT] - st1[2*HO + kT] * ac;

    bf16x8 Bh[CTW][KSn], Bl[CTW][KSn];
    #pragma unroll
    for (int ctl = 0; ctl < CTW; ++ctl)
        #pragma unroll
        for (int ks = 0; ks < KSn; ++ks) {
            const int c  = w*16*CTW + ctl*16 + m16;
            const int k0 = ks*32 + q4*8;
            Bh[ctl][ks] = *(const bf16x8*)(w2h + c*HO + k0);
            Bl[ctl][ks] = *(const bf16x8*)(w2l + c*HO + k0);
        }

    const float b2c = (t < HO) ? b2[t] : 0.f;
    double ssum = 0., ssq = 0.;

    for (int p0 = blockIdx.x*4; p0 < BN_; p0 += gridDim.x*4) {
        const int bbase = p0 & ~(N_-1);
        __syncthreads();
        if (t < 80) sidx[t] = idx[p0*K_ + t];
        __syncthreads();
        for (int e = t; e < 80*HO; e += 256) {
            const int r  = e >> HSH;
            const int pl = (r*3277) >> 16;     // r/20 for r<80
            const int mI = sidx[r];
            float z = P[(size_t)(p0+pl)*HO + kT] + Q[(size_t)(bbase+mI)*HO + kT];
            float h = fmaxf(z*ac + bc, 0.f);
            unsigned short hh = f2bf(h);
            float hf = __uint_as_float((unsigned)hh << 16);
            unsigned short hl = f2bf(h - hf);
            hs[r*HOP + kT] = (short)hh;
            hs[80*HOP + r*HOP + kT] = (short)hl;
        }
        __syncthreads();
        f32x4 acc[5][CTW];
        #pragma unroll
        for (int rt = 0; rt < 5; ++rt)
            #pragma unroll
            for (int ctl = 0; ctl < CTW; ++ctl)
                acc[rt][ctl] = (f32x4){0.f, 0.f, 0.f, 0.f};
        #pragma unroll
        for (int rt = 0; rt < 5; ++rt)
            #pragma unroll
            for (int ks = 0; ks < KSn; ++ks) {
                const short* ap = hs + (rt*16 + m16)*HOP + ks*32 + q4*8;
                bf16x8 Ah = *(const bf16x8*)ap;
                bf16x8 Al = *(const bf16x8*)(ap + 80*HOP);
                #pragma unroll
                for (int ctl = 0; ctl < CTW; ++ctl) {
                    acc[rt][ctl] = __builtin_amdgcn_mfma_f32_16x16x32_bf16(Ah, Bh[ctl][ks], acc[rt][ctl], 0, 0, 0);
                    acc[rt][ctl] = __builtin_amdgcn_mfma_f32_16x16x32_bf16(Al, Bh[ctl][ks], acc[rt][ctl], 0, 0, 0);
                    acc[rt][ctl] = __builtin_amdgcn_mfma_f32_16x16x32_bf16(Ah, Bl[ctl][ks], acc[rt][ctl], 0, 0, 0);
                }
            }
        __syncthreads();
        #pragma unroll
        for (int rt = 0; rt < 5; ++rt)
            #pragma unroll
            for (int ctl = 0; ctl < CTW; ++ctl) {
                const int col = w*16*CTW + ctl*16 + m16;
                #pragma unroll
                for (int ri = 0; ri < 4; ++ri) {
                    const int row = rt*16 + q4*4 + ri;
                    cd[row*CDP + col] = acc[rt][ctl][ri];
                }
            }
        __syncthreads();
        if (t < HO) {
            #pragma unroll
            for (int pl = 0; pl < 4; ++pl) {
                float mx = -3.4e38f, mn = 3.4e38f;
                #pragma unroll
                for (int j = 0; j < K_; ++j) {
                    float v = cd[(pl*20 + j)*CDP + t] + b2c;
                    mx = fmaxf(mx, v); mn = fminf(mn, v);
                    double vd = (double)v;
                    ssum += vd; ssq += vd*vd;
                }
                zmax[(size_t)(p0+pl)*HO + t] = mx;
                zmin[(size_t)(p0+pl)*HO + t] = mn;
            }
        }
    }
    if (t < HO) {
        partOut[(size_t)blockIdx.x*(2*HO) + t] = ssum;
        partOut[(size_t)blockIdx.x*(2*HO) + HO + t] = ssq;
    }
}

// max_j relu(BN(z)) = relu(BN(max_j z)) for gamma>=0, min for gamma<0.
// R11: reference elementwise op order for the x1b-producing instance.
template<int HO>
__global__ __launch_bounds__(256) void conv_fin_kernel(
    const float* __restrict__ zmax, const float* __restrict__ zmin,
    const float* __restrict__ st2, const float* __restrict__ g2, const float* __restrict__ be2,
    float* __restrict__ out)
{
    int e = blockIdx.x*256 + threadIdx.x;
    int c = e & (HO-1);
    float g = g2[c];
    float sel = (g >= 0.f) ? zmax[e] : zmin[e];
    float bn = __fadd_rn(__fmul_rn(__fmul_rn(__fsub_rn(sel, st2[2*HO + c]), st2[3*HO + c]), g), be2[c]);
    out[e] = fmaxf(bn, 0.f);
}

// ---------------------------------------------------------------- classifier
__global__ __launch_bounds__(256) void cls1_kernel(
    const float* __restrict__ x1, const float* __restrict__ x2f,
    const float* __restrict__ W, const float* __restrict__ b1,
    float* __restrict__ z, double* __restrict__ partOut)
{
    __shared__ float ws[192*64];
    __shared__ float xr[4*192];
    __shared__ double red[256], red2[256];
    const int t = threadIdx.x, cy = blockIdx.y;
    for (int e = t; e < 192*64; e += 256) {
        int c = e >> 6, cl = e & 63;
        ws[e] = W[c*128 + cy*64 + cl];
    }
    const int pl = t >> 6, c2l = t & 63;
    const float b1v = b1[cy*64 + c2l];
    double ssum = 0., ssq = 0.;
    for (int p0 = blockIdx.x*4; p0 < BN_; p0 += gridDim.x*4) {
        __syncthreads();
        for (int l = t; l < 4*192; l += 256) {
            int pp = l / 192, cc = l % 192;
            xr[l] = (cc < 64) ? x1[(p0+pp)*64 + cc] : x2f[(p0+pp)*128 + cc - 64];
        }
        __syncthreads();
        float acc = b1v;
        const float* xx = xr + pl*192;
        #pragma unroll 8
        for (int c = 0; c < 192; ++c) acc += xx[c] * ws[c*64 + c2l];
        z[(p0+pl)*128 + cy*64 + c2l] = acc;
        double ad = (double)acc;
        ssum += ad; ssq += ad*ad;
    }
    __syncthreads();
    red[t] = ssum; red2[t] = ssq;
    __syncthreads();
    if (t < 64) {
        double s = red[t], s2 = red2[t];
        #pragma unroll
        for (int g = 1; g < 4; ++g) { s += red[g*64 + t]; s2 += red2[g*64 + t]; }
        // partial row layout [512][256]: (sum ch0..127, sumsq ch0..127); the two
        // cy-planes of the same blockIdx.x fill disjoint 64-ch ranges.
        partOut[(size_t)blockIdx.x*256 + cy*64 + t] = s;
        partOut[(size_t)blockIdx.x*256 + 128 + cy*64 + t] = s2;
    }
}

__global__ __launch_bounds__(256) void cls_fin_kernel(
    const float* __restrict__ z, const float* __restrict__ st,
    const float* __restrict__ g, const float* __restrict__ be,
    const float* __restrict__ w2, const float* __restrict__ b2,
    float* __restrict__ out)
{
    const int t = threadIdx.x, w = t >> 6, L = t & 63;
    const int p = blockIdx.x*4 + w;
    float s = 0.f;
    #pragma unroll
    for (int h = 0; h < 2; ++h) {
        int c = L + h*64;
        float v = (z[p*128 + c] - st[256 + c]) * st[384 + c] * g[c] + be[c];
        s += fmaxf(v, 0.f) * w2[c];
    }
    #pragma unroll
    for (int off = 32; off; off >>= 1) s += __shfl_xor(s, off);
    if (L == 0) out[p] = s + b2[0];
}

// ---------------------------------------------------------------- launch
extern "C" void kernel_launch(void* const* d_in, const int* in_sizes, int n_in,
                              void* d_out, int out_size, void* d_ws, size_t ws_size,
                              hipStream_t stream)
{
    const float* x      = (const float*)d_in[0];
    const float* c1_w1  = (const float*)d_in[1];
    const float* c1_b1  = (const float*)d_in[2];
    const float* c1_g1  = (const float*)d_in[3];
    const float* c1_be1 = (const float*)d_in[4];
    const float* c1_w2  = (const float*)d_in[5];
    const float* c1_b2  = (const float*)d_in[6];
    const float* c1_g2  = (const float*)d_in[7];
    const float* c1_be2 = (const float*)d_in[8];
    const float* c2_w1  = (const float*)d_in[9];
    const float* c2_b1  = (const float*)d_in[10];
    const float* c2_g1  = (const float*)d_in[11];
    const float* c2_be1 = (const float*)d_in[12];
    const float* c2_w2  = (const float*)d_in[13];
    const float* c2_b2  = (const float*)d_in[14];
    const float* c2_g2  = (const float*)d_in[15];
    const float* c2_be2 = (const float*)d_in[16];
    const float* cls_w1 = (const float*)d_in[17];
    const float* cls_b1 = (const float*)d_in[18];
    const float* cls_g1 = (const float*)d_in[19];
    const float* cls_be1= (const float*)d_in[20];
    const float* cls_w2 = (const float*)d_in[21];
    const float* cls_b2 = (const float*)d_in[22];
    (void)in_sizes; (void)n_in; (void)out_size; (void)ws_size;

    char* ws = (char*)d_ws;
    size_t off = 0;
    auto alloc = [&](size_t bytes) { char* p = ws + off; off += (bytes + 255) & ~255ull; return p; };
    float* A    = (float*)alloc((size_t)16<<20);   // P1 -> P2 -> zcls
    float* Bq   = (float*)alloc((size_t)16<<20);   // Q1 -> Q2 -> cls partials
    float* zmax = (float*)alloc((size_t)16<<20);   // also hosts Xh/Xl between conv1 and conv2
    float* zmin = (float*)alloc((size_t)16<<20);
    float* x1b  = (float*)alloc((size_t)8<<20);
    float* x2b  = (float*)alloc((size_t)16<<20);   // also hosts idx24 + stats partials (dead windows)
    int*   idx  = (int*)  alloc((size_t)BN_*K_*4); // idx1 -> idx2
    float* nrm  = (float*)alloc((size_t)BN_*4);
    float* st   = (float*)alloc((size_t)5*512*4);
    unsigned short* w2th = (unsigned short*)alloc((size_t)128*128*2);  // W2^T hi
    unsigned short* w2tl = (unsigned short*)alloc((size_t)128*128*2);  // W2^T lo
    float *st0 = st, *st1 = st+512, *st2 = st+1024, *st3 = st+1536, *st4 = st+2048;

    unsigned short* Xh = (unsigned short*)zmax;                       // 4 MB
    unsigned short* Xl = (unsigned short*)((char*)zmax + (4<<20));    // 4 MB
    int* idx24 = (int*)x2b;
    double* part  = (double*)x2b;  // fp64 stats partials (max 4 MB): free during both conv phases
    double* partC = (double*)Bq;   // cls stats partials (1 MB): Q2 dead after conv_l2_mfma

    // ---- EdgeConv 1 (exact fp32 conv: x1b feeds flip-sensitive kNN2)
    knn4_kernel<<<dim3(N_/4, B_), 256, 0, stream>>>(x, idx);
    pq1_kernel<<<BN_/4, 256, 0, stream>>>(x, c1_w1, c1_b1, A, Bq);
    stats_l1_kernel<64><<<2048, 256, 0, stream>>>(A, Bq, idx, part);
    finalize_parts_kernel<<<64, 256, 0, stream>>>(part, 2048, 64, 1.0/655360.0, st0);
    conv_l2_kernel<64><<<dim3(2048,1), 256, 0, stream>>>(A, Bq, idx, st0, c1_g1, c1_be1, c1_w2, c1_b2, zmax, zmin, part);
    finalize_parts_kernel<<<64, 256, 0, stream>>>(part, 2048, 64, 1.0/655360.0, st1);
    conv_fin_kernel<64><<<BN_*64/256, 256, 0, stream>>>(zmax, zmin, st1, c1_g2, c1_be2, x1b);

    // ---- EdgeConv 2 (MFMA conv: x2b only feeds classifier)
    prep64_kernel<<<BN_/4, 256, 0, stream>>>(x1b, Xh, Xl, nrm);
    knn64v4_kernel<<<dim3(N_/16, B_), 1024, 0, stream>>>(Xh, Xl, nrm, idx24);
    rescore_kernel<<<BN_/4, 256, 0, stream>>>(x1b, nrm, idx24, idx);
    pq2_kernel<<<1024, 256, 0, stream>>>(x1b, c2_w1, c2_b1, A, Bq);
    stats_l1_kernel<128><<<2048, 256, 0, stream>>>(A, Bq, idx, part);
    finalize_parts_kernel<<<128, 256, 0, stream>>>(part, 2048, 128, 1.0/655360.0, st2);
    prep_w2t_kernel<<<128*128/256, 256, 0, stream>>>(c2_w2, w2th, w2tl, 128);
    conv_l2_mfma_kernel<128><<<2048, 256, 0, stream>>>(A, Bq, idx, st2, c2_g1, c2_be1, w2th, w2tl, c2_b2, zmax, zmin, part);
    finalize_parts_kernel<<<128, 256, 0, stream>>>(part, 2048, 128, 1.0/655360.0, st3);
    conv_fin_kernel<128><<<BN_*128/256, 256, 0, stream>>>(zmax, zmin, st3, c2_g2, c2_be2, x2b);

    // ---- classifier
    cls1_kernel<<<dim3(512,2), 256, 0, stream>>>(x1b, x2b, cls_w1, cls_b1, A, partC);
    finalize_parts_kernel<<<128, 256, 0, stream>>>(partC, 512, 128, 1.0/32768.0, st4);
    cls_fin_kernel<<<BN_/4, 256, 0, stream>>>(A, st4, cls_g1, cls_be1, cls_w2, cls_b2, (float*)d_out);
}

// Round 6
// 1414.384 us; speedup vs baseline: 1.0837x; 1.0837x over previous
//
#include <hip/hip_runtime.h>
#include <math.h>

#define B_ 8
#define N_ 4096
#define K_ 20
#define KS_ 24          // approx-select width; exact rescore trims to K_ (R3-validated margin)
#define BN_ (B_*N_)

typedef __attribute__((ext_vector_type(8))) short bf16x8;
typedef __attribute__((ext_vector_type(4))) float f32x4;

// ---------------------------------------------------------------- BN stats finalize (deterministic, fp64)
// R10: float atomicAdd stats were order-nondeterministic across graph replays ->
// kNN2 boundary flip -> post-timing divergence.  R11: the deterministic fp32
// order landed on the WRONG side of a ~1-ULP distance tie (absmax 0.1177).
// All stats now accumulate in DOUBLE (partials + reduce + mean/var/rstd), so our
// stats are ~exact; the x1b-feeding BN applies the reference's elementwise op
// order; rescore uses the reference's full d formula.  DO NOT reintroduce
// atomicAdd or fold these back into fp32/FMA on the conv1 path.
// part layout: [nb][2*H] doubles (sum(H), sumsq(H) per block row).
__global__ __launch_bounds__(256) void finalize_parts_kernel(
    const double* __restrict__ part, int nb, int H, double invCount, float* __restrict__ st)
{
    __shared__ double red[256], red2[256];
    const int c = blockIdx.x, t = threadIdx.x;
    double s = 0., s2 = 0.;
    for (int b = t; b < nb; b += 256) {
        s  += part[(size_t)b*2*H + c];
        s2 += part[(size_t)b*2*H + H + c];
    }
    red[t] = s; red2[t] = s2;
    __syncthreads();
    #pragma unroll
    for (int off = 128; off; off >>= 1) {
        if (t < off) { red[t] += red[t+off]; red2[t] += red2[t+off]; }
        __syncthreads();
    }
    if (t == 0) {
        double mean = red[0] * invCount;
        double var  = fmax(red2[0] * invCount - mean * mean, 0.);
        st[2*H + c] = (float)mean;
        st[3*H + c] = (float)(1.0 / sqrt(var + 1e-5));
    }
}

// ---------------------------------------------------------------- kNN, C=4
// R7-validated (value, candidate-index) lexicographic argmin — matches jax
// top_k tie-break; reference-defining (no rescore guard) -> selection EXACT.
// R15: two structurally different versions (R3 1024-thr, R5 256-thr+regs) both
// ~350us -> shared bottleneck = L1I thrash from ~2300 fully-unrolled instrs
// (init scan + 2 rescan copies over d[64]).  d[64] ELIMINATED: rolled 64-iter
// loop fuses dist-compute (from xt) + the IDENTICAL top-3 insert chain; rescans
// RECOMPUTE dists (deterministic -> bit-identical -> exact semantics fully
// preserved).  Code ~2KB, ~30 VGPR, 1024-thr for full occupancy.
__global__ __launch_bounds__(1024, 8) void knn4_kernel(const float* __restrict__ x, int* __restrict__ idxout)
{
    __shared__ float4 xt[N_];   // 64 KB
    const int b = blockIdx.y;
    const int t = threadIdx.x;
    const float4* xg = (const float4*)x + b*N_;
    for (int e = t; e < N_; e += 1024) xt[e] = xg[e];
    __syncthreads();
    const int w = t >> 6, L = t & 63;
    const int n = blockIdx.x*16 + w;
    const float4 q = xt[n];
    const float MX = 3.4e38f;
    float m1 = MX, m2 = MX, m3 = MX; int i1 = 0, i2 = 0, i3 = 0;
    #pragma unroll 1
    for (int j = 0; j < 64; ++j) {
        float4 vv = xt[(j<<6) | L];
        float nn = vv.x*vv.x + vv.y*vv.y + vv.z*vv.z + vv.w*vv.w;
        float dp = q.x*vv.x + q.y*vv.y + q.z*vv.z + q.w*vv.w;
        float v = nn - 2.f*dp;   // |xn|^2 dropped: rank-equivalent
        bool c1 = v < m1, c2 = v < m2, c3 = v < m3;
        m3 = c2 ? m2 : (c3 ? v : m3);
        i3 = c2 ? i2 : (c3 ? j : i3);
        m2 = c1 ? m1 : (c2 ? v : m2);
        i2 = c1 ? i1 : (c2 ? j : i2);
        m1 = c1 ? v : m1;
        i1 = c1 ? j : i1;
    }
    unsigned long long used = 0;
    int mywin = 0;
    #pragma unroll 1
    for (int r = 0; r < K_; ++r) {
        float bv = m1; int bg = (i1<<6) | L;
        #pragma unroll
        for (int off = 32; off; off >>= 1) {
            float ov = __shfl_xor(bv, off);
            int   og = __shfl_xor(bg, off);
            bool tk = (ov < bv) || (ov == bv && og < bg);
            bv = tk ? ov : bv; bg = tk ? og : bg;
        }
        if (L == r) mywin = bg;
        if (L == (bg & 63)) {
            used |= 1ull << i1;
            m1 = m2; i1 = i2; m2 = m3; i2 = i3; m3 = MX;
            if (m1 == MX) {
                m2 = MX; m3 = MX; i1 = 0; i2 = 0; i3 = 0;
                #pragma unroll 1
                for (int j = 0; j < 64; ++j) {
                    float4 vv = xt[(j<<6) | L];
                    float nn = vv.x*vv.x + vv.y*vv.y + vv.z*vv.z + vv.w*vv.w;
                    float dp = q.x*vv.x + q.y*vv.y + q.z*vv.z + q.w*vv.w;
                    float dj = nn - 2.f*dp;
                    float v = ((used >> j) & 1ull) ? MX : dj;
                    bool c1 = v < m1, c2 = v < m2, c3 = v < m3;
                    m3 = c2 ? m2 : (c3 ? v : m3);
                    i3 = c2 ? i2 : (c3 ? j : i3);
                    m2 = c1 ? m1 : (c2 ? v : m2);
                    i2 = c1 ? i1 : (c2 ? j : i2);
                    m1 = c1 ? v : m1;
                    i1 = c1 ? j : i1;
                }
            }
        }
    }
    if (L < K_) idxout[(b*N_ + n)*K_ + L] = mywin;
}

// ---------------------------------------------------------------- fp32 -> bf16 RNE
static __device__ inline unsigned short f2bf(float f)
{
    unsigned u = __float_as_uint(f);
    unsigned r = (u + 0x7fffu + ((u >> 16) & 1u)) >> 16;   // RNE
    return (unsigned short)r;
}

__global__ __launch_bounds__(256) void prep64_kernel(const float* __restrict__ x,
                                                     unsigned short* __restrict__ Xh,
                                                     unsigned short* __restrict__ Xl,
                                                     float* __restrict__ nrm)
{
    const int t = threadIdx.x, L = t & 63;
    const int row = blockIdx.x*4 + (t >> 6);
    const float v = x[row*64 + L];
    unsigned short h = f2bf(v);
    float hf = __uint_as_float((unsigned)h << 16);
    unsigned short l = f2bf(v - hf);
    Xh[row*64 + L] = h;
    Xl[row*64 + L] = l;
    float s = v * v;
    #pragma unroll
    for (int off = 32; off; off >>= 1) s += __shfl_xor(s, off);
    if (L == 0) nrm[row] = s;
}

// ---------------------------------------------------------------- kNN, C=64 via MFMA (split-bf16 Gram, approx)
// v8 (R15): ALL long loops rolled (#pragma unroll 1) — the fully-unrolled
// ck*tt staging/MFMA + scan body was ~25-35KB of code, thrashing the 32KB L1I
// (VALUBusy 31%, all pipes idle, ~110K cyc/block unexplained by data-side
// models).  Selection semantics unchanged from R5 (per-lane sorted top-8
// value-only keys w/ slot in low 6 mantissa bits [R12], 2-winner butterfly
// w/ readlane fix [R13], XOR-swizzled dist [R12], top-8 dropout P~5e-9/query).
__global__ __launch_bounds__(1024, 4) void knn64v4_kernel(
    const unsigned short* __restrict__ Xh, const unsigned short* __restrict__ Xl,
    const float* __restrict__ nrm, int* __restrict__ idx24)
{
    __shared__ float dist[16*1024];   // exactly 64 KB
    const int b = blockIdx.y, t = threadIdx.x;
    const int w = t >> 6, L = t & 63;
    const int q0 = blockIdx.x * 16;
    const int m = L & 15, q4 = L >> 4, kq = q4 * 8;
    const size_t rowbase = (size_t)b * N_ * 64;
    const int swzW = q4 << 4;         // write-side column XOR (qrow>>2 == q4)
    const int swzR = (w >> 2) << 4;   // read-side column XOR (query row w)

    const unsigned short* aph = Xh + rowbase + (size_t)(q0 + m)*64 + kq;
    const unsigned short* apl = Xl + rowbase + (size_t)(q0 + m)*64 + kq;
    const bf16x8 a_h0 = *(const bf16x8*)(aph);
    const bf16x8 a_h1 = *(const bf16x8*)(aph + 32);
    const bf16x8 a_l0 = *(const bf16x8*)(apl);
    const bf16x8 a_l1 = *(const bf16x8*)(apl + 32);

    const float MX = 3.4e38f;
    float sm[8];
    #pragma unroll
    for (int l = 0; l < 8; ++l) sm[l] = MX;

    #pragma unroll 1
    for (int ck = 0; ck < 4; ++ck) {
        const int cq = ck * 1024;
        const unsigned slotW = (unsigned)(ck*16 + w);   // global slot of this wave's candidates
        __syncthreads();
        #pragma unroll 1
        for (int tt = 0; tt < 4; ++tt) {
            const int cbase = w*64 + tt*16;
            const unsigned short* bph = Xh + rowbase + (size_t)(cq + cbase + m)*64 + kq;
            const unsigned short* bpl = Xl + rowbase + (size_t)(cq + cbase + m)*64 + kq;
            bf16x8 b_h0 = *(const bf16x8*)(bph);
            bf16x8 b_h1 = *(const bf16x8*)(bph + 32);
            bf16x8 b_l0 = *(const bf16x8*)(bpl);
            bf16x8 b_l1 = *(const bf16x8*)(bpl + 32);
            f32x4 acc = {0.f, 0.f, 0.f, 0.f};
            acc = __builtin_amdgcn_mfma_f32_16x16x32_bf16(a_h0, b_h0, acc, 0, 0, 0);
            acc = __builtin_amdgcn_mfma_f32_16x16x32_bf16(a_h1, b_h1, acc, 0, 0, 0);
            acc = __builtin_amdgcn_mfma_f32_16x16x32_bf16(a_l0, b_h0, acc, 0, 0, 0);
            acc = __builtin_amdgcn_mfma_f32_16x16x32_bf16(a_l1, b_h1, acc, 0, 0, 0);
            acc = __builtin_amdgcn_mfma_f32_16x16x32_bf16(a_h0, b_l0, acc, 0, 0, 0);
            acc = __builtin_amdgcn_mfma_f32_16x16x32_bf16(a_h1, b_l1, acc, 0, 0, 0);
            const float nv = nrm[b*N_ + cq + cbase + m];
            const int colW = (cbase + m) ^ swzW;
            #pragma unroll
            for (int r = 0; r < 4; ++r) {
                float dv = nv - 2.f*acc[r];
                unsigned key = (__float_as_uint(dv) & ~63u) | slotW;
                dist[(q4*4 + r)*1024 + colW] = __uint_as_float(key);
            }
        }
        __syncthreads();
        // scan this ck's 16 values straight from LDS into the sorted top-8
        #pragma unroll 1
        for (int s = 0; s < 16; ++s) {
            float v = dist[w*1024 + (((s<<6) + L) ^ swzR)];
            #pragma unroll
            for (int l = 0; l < 8; ++l) {
                float lo = fminf(sm[l], v);
                v = fmaxf(sm[l], v);
                sm[l] = lo;
            }
        }
    }

    int mywin = 0;
    #pragma unroll 1
    for (int r = 0; r < KS_/2; ++r) {
        float a1 = sm[0], a2 = sm[1];
        #pragma unroll
        for (int off = 32; off; off >>= 1) {
            float b1 = __shfl_xor(a1, off);
            float b2 = __shfl_xor(a2, off);
            float lo = fminf(a1, b1);
            float hi = fmaxf(a1, b1);
            a2 = fminf(hi, fminf(a2, b2));
            a1 = lo;
        }
        const unsigned long long t1 = __ballot(sm[0] == a1);
        const int wl1 = (int)__ffsll((unsigned long long)t1) - 1;
        if (L == 2*r) mywin = (int)(((__float_as_uint(a1) & 63u) << 6) | (unsigned)wl1);
        if (L == wl1) {
            #pragma unroll
            for (int l = 0; l < 7; ++l) sm[l] = sm[l+1];
            sm[7] = MX;
        }
        // winner2 = min(butterfly 2nd, wl1's current min)  [uniform readlane]
        const float w1m = __shfl(sm[0], wl1);
        const float gv2 = fminf(a2, w1m);
        const unsigned long long t2 = __ballot(sm[0] == gv2);
        const int wl2 = (int)__ffsll((unsigned long long)t2) - 1;
        if (L == 2*r+1) mywin = (int)(((__float_as_uint(gv2) & 63u) << 6) | (unsigned)wl2);
        if (L == wl2) {
            #pragma unroll
            for (int l = 0; l < 7; ++l) sm[l] = sm[l+1];
            sm[7] = MX;
        }
    }
    if (L < KS_) idx24[((size_t)b*N_ + q0 + w)*KS_ + L] = mywin;
}

// ---------------------------------------------------------------- exact fp32 rescore of the KS_ candidates
// R11: d matches the reference formula exactly.  R13: two winners per round
// (10 rounds).  Exact without a readlane fix: every lane holds ONE always-valid
// candidate, so the butterfly's top-2 over (dv,MX) pairs is the true top-2;
// candidate indices are unique (extraction marks used), so pops are unambiguous.
// R15: round loop rolled (code size).
__global__ __launch_bounds__(256) void rescore_kernel(const float* __restrict__ x1, const float* __restrict__ nrm,
                                                      const int* __restrict__ idx24, int* __restrict__ idxout)
{
    const int t = threadIdx.x, w = t >> 6, L = t & 63;
    const int p = blockIdx.x*4 + w;
    const int bbase = p & ~(N_-1);
    const float MX = 3.4e38f;
    float dv = MX; int di = 0x7fffffff;
    if (L < KS_) {
        const int ci = idx24[(size_t)p*KS_ + L];
        const float4* qr = (const float4*)(x1 + (size_t)p*64);
        const float4* cr = (const float4*)(x1 + (size_t)(bbase + ci)*64);
        float dot = 0.f;
        #pragma unroll
        for (int i = 0; i < 16; ++i) {
            float4 a = qr[i], bx = cr[i];
            dot += a.x*bx.x + a.y*bx.y + a.z*bx.z + a.w*bx.w;
        }
        dv = __fsub_rn(__fadd_rn(nrm[p], nrm[bbase + ci]), 2.f*dot);
        di = ci;
    }
    int myfin = 0;
    #pragma unroll 1
    for (int r = 0; r < K_/2; ++r) {
        float v1 = dv; int g1 = di;
        float v2 = MX; int g2 = 0x7fffffff;
        #pragma unroll
        for (int off = 32; off; off >>= 1) {
            float ov1 = __shfl_xor(v1, off); int og1 = __shfl_xor(g1, off);
            float ov2 = __shfl_xor(v2, off); int og2 = __shfl_xor(g2, off);
            bool c1 = (ov1 < v1) || (ov1 == v1 && og1 < g1);
            float hv = c1 ? v1 : ov1; int hg = c1 ? g1 : og1;
            v1 = c1 ? ov1 : v1;       g1 = c1 ? og1 : g1;
            bool c2 = (ov2 < v2) || (ov2 == v2 && og2 < g2);
            float l2v = c2 ? ov2 : v2; int l2g = c2 ? og2 : g2;
            bool c3 = (l2v < hv) || (l2v == hv && l2g < hg);
            v2 = c3 ? l2v : hv;  g2 = c3 ? l2g : hg;
        }
        if (L == 2*r)   myfin = g1;
        if (L == 2*r+1) myfin = g2;
        if (di == g1 || di == g2) dv = MX;
    }
    if (L < K_) idxout[(size_t)p*K_ + L] = myfin;
}

// ---------------------------------------------------------------- P/Q precompute
__global__ __launch_bounds__(256) void pq1_kernel(const float* __restrict__ x, const float* __restrict__ W,
                                                  const float* __restrict__ b1,
                                                  float* __restrict__ P, float* __restrict__ Q)
{
    __shared__ float wd[256], wb[256];
    const int t = threadIdx.x;
    wd[t] = W[t] - W[256 + t];
    wb[t] = W[256 + t];
    __syncthreads();
    const int p = blockIdx.x*4 + (t >> 6), c = t & 63;
    const float4 xv = ((const float4*)x)[p];
    float Pv = b1[c] + xv.x*wd[c] + xv.y*wd[64+c] + xv.z*wd[128+c] + xv.w*wd[192+c];
    float Qv =         xv.x*wb[c] + xv.y*wb[64+c] + xv.z*wb[128+c] + xv.w*wb[192+c];
    P[p*64 + c] = Pv;
    Q[p*64 + c] = Qv;
}

__global__ __launch_bounds__(256) void pq2_kernel(const float* __restrict__ x1, const float* __restrict__ W,
                                                  const float* __restrict__ b1,
                                                  float* __restrict__ P, float* __restrict__ Q)
{
    __shared__ float wd[64*128], wb[64*128];
    const int t = threadIdx.x;
    for (int e = t; e < 8192; e += 256) {
        float wt = W[e], wbo = W[8192 + e];
        wd[e] = wt - wbo; wb[e] = wbo;
    }
    __syncthreads();
    const int pl = t >> 7, c = t & 127;
    const float b1v = b1[c];
    for (int p0 = blockIdx.x*2; p0 < BN_; p0 += gridDim.x*2) {
        const int p = p0 + pl;
        float Pv = b1v, Qv = 0.f;
        const float* xrow = x1 + p*64;
        #pragma unroll 8
        for (int k = 0; k < 64; ++k) {
            float xv = xrow[k];
            Pv += xv * wd[k*128 + c];
            Qv += xv * wb[k*128 + c];
        }
        P[p*128 + c] = Pv;
        Q[p*128 + c] = Qv;
    }
}

// ---------------------------------------------------------------- layer-1 BN stats (fp64 per-block partials)
template<int HO>
__global__ __launch_bounds__(256) void stats_l1_kernel(const float* __restrict__ P, const float* __restrict__ Q,
                                                       const int* __restrict__ idx, double* __restrict__ partOut)
{
    constexpr int G = 256/HO;
    __shared__ double red[256], red2[256];
    const int t = threadIdx.x, c = t % HO, g = t / HO;
    double s = 0., s2 = 0.;
    for (int p = blockIdx.x; p < BN_; p += gridDim.x) {
        const float Pv = P[p*HO + c];
        const int bbase = p & ~(N_-1);
        for (int j = g; j < K_; j += G) {
            int m = idx[p*K_ + j];
            float z = Pv + Q[(bbase + m)*HO + c];
            double zd = (double)z;
            s += zd; s2 += zd*zd;
        }
    }
    red[t] = s; red2[t] = s2;
    __syncthreads();
    if (t < HO) {
        double a = red[t], a2 = red2[t];
        #pragma unroll
        for (int q = 1; q < G; ++q) { a += red[q*HO + t]; a2 += red2[q*HO + t]; }
        partOut[(size_t)blockIdx.x*(2*HO) + t] = a;
        partOut[(size_t)blockIdx.x*(2*HO) + HO + t] = a2;
    }
}

// ---------------------------------------------------------------- EdgeConv layer-2, exact fp32 (conv1:
// its output feeds kNN2, which is flip-sensitive to ~1e-4 feature perturbation).
// R11: BN applied in the reference's elementwise op order (((z-m)*rstd)*g+be,
// separately rounded) — the folded z*ac+bc form differed by 1-2 ULP on x1 features.
template<int HO>
__global__ __launch_bounds__(256) void conv_l2_kernel(
    const float* __restrict__ P, const float* __restrict__ Q, const int* __restrict__ idx,
    const float* __restrict__ st1, const float* __restrict__ g1, const float* __restrict__ be1,
    const float* __restrict__ w2, const float* __restrict__ b2,
    float* __restrict__ zmax, float* __restrict__ zmin, double* __restrict__ partOut)
{
    __shared__ float w2s[HO*64];
    __shared__ float h1s[K_*HO];
    __shared__ float redA[256], redB[256];
    __shared__ double redD[256], redD2[256];
    const int t = threadIdx.x;
    const int cy = blockIdx.y;
    for (int e = t; e < HO*64; e += 256) {
        int c = e >> 6, cl = e & 63;
        w2s[e] = w2[c*HO + cy*64 + cl];
    }
    const int cA = t % HO;
    const float mA = st1[2*HO + cA], rA = st1[3*HO + cA];
    const float gA = g1[cA], beA = be1[cA];
    const int c2l = t & 63, jh = t >> 6;
    const float b2v = b2[cy*64 + c2l];
    double ssum = 0., ssq = 0.;
    for (int p = blockIdx.x; p < BN_; p += gridDim.x) {
        __syncthreads();
        const int bbase = p & ~(N_-1);
        const float Pv = P[p*HO + cA];
        for (int e = t; e < K_*HO; e += 256) {
            int j = e / HO;
            int m = idx[p*K_ + j];
            float z = Pv + Q[(bbase + m)*HO + cA];
            float bn = __fadd_rn(__fmul_rn(__fmul_rn(__fsub_rn(z, mA), rA), gA), beA);
            h1s[e] = fmaxf(bn, 0.f);
        }
        __syncthreads();
        float acc[5];
        #pragma unroll
        for (int q = 0; q < 5; ++q) acc[q] = b2v;
        for (int c = 0; c < HO; ++c) {
            float wv = w2s[c*64 + c2l];
            #pragma unroll
            for (int q = 0; q < 5; ++q)
                acc[q] += h1s[(jh + q*4)*HO + c] * wv;
        }
        float mx = acc[0], mn = acc[0];
        #pragma unroll
        for (int q = 0; q < 5; ++q) {
            mx = fmaxf(mx, acc[q]); mn = fminf(mn, acc[q]);
            double ad = (double)acc[q];
            ssum += ad; ssq += ad*ad;
        }
        redA[t] = mx; redB[t] = mn;
        __syncthreads();
        if (t < 64) {
            float M = redA[t], Mn = redB[t];
            #pragma unroll
            for (int g = 1; g < 4; ++g) { M = fmaxf(M, redA[g*64 + t]); Mn = fminf(Mn, redB[g*64 + t]); }
            zmax[p*HO + cy*64 + t] = M;
            zmin[p*HO + cy*64 + t] = Mn;
        }
    }
    __syncthreads();
    redD[t] = ssum; redD2[t] = ssq;
    __syncthreads();
    if (t < 64) {
        double s = redD[t], s2 = redD2[t];
        #pragma unroll
        for (int g = 1; g < 4; ++g) { s += redD[g*64 + t]; s2 += redD2[g*64 + t]; }
        partOut[(size_t)blockIdx.x*(2*HO) + cy*64 + t] = s;
        partOut[(size_t)blockIdx.x*(2*HO) + HO + cy*64 + t] = s2;
    }
}

// ---------------------------------------------------------------- W2^T split-bf16 prep
__global__ __launch_bounds__(256) void prep_w2t_kernel(const float* __restrict__ W,
                                                       unsigned short* __restrict__ wh,
                                                       unsigned short* __restrict__ wl, int HO)
{
    const int e = blockIdx.x*256 + threadIdx.x;   // e = k*HO + c
    const int k = e / HO, c = e % HO;
    const float v = W[e];
    unsigned short h = f2bf(v);
    float hf = __uint_as_float((unsigned)h << 16);
    wh[c*HO + k] = h;
    wl[c*HO + k] = f2bf(v - hf);
}

// ---------------------------------------------------------------- EdgeConv layer-2 via MFMA (split-bf16)
// conv2 only: output feeds the classifier (value-continuous), bf16-split safe.
template<int HO>
__global__ __launch_bounds__(256) void conv_l2_mfma_kernel(
    const float* __restrict__ P, const float* __restrict__ Q, const int* __restrict__ idx,
    const float* __restrict__ st1, const float* __restrict__ g1, const float* __restrict__ be1,
    const unsigned short* __restrict__ w2h, const unsigned short* __restrict__ w2l,
    const float* __restrict__ b2,
    float* __restrict__ zmax, float* __restrict__ zmin, double* __restrict__ partOut)
{
    constexpr int HOP = HO + 8;
    constexpr int CDP = HO + 1;
    constexpr int CTW = HO / 64;
    constexpr int KSn = HO / 32;
    constexpr int HSH = (HO == 128) ? 7 : 6;
    __shared__ __align__(16) short hs[2*80*HOP];
    __shared__ int sidx[80];
    float* cd = (float*)hs;

    const int t = threadIdx.x, w = t >> 6, L = t & 63;
    const int m16 = L & 15, q4 = L >> 4;

    const int kT = t & (HO - 1);
    const float ac = st1[3*HO + kT] * g1[kT];
    const float bc = be1[kT] - st1[2*HO + kT] * ac;

    bf16x8 Bh[CTW][KSn], Bl[CTW][KSn];
    #pragma unroll
    for (int ctl = 0; ctl < CTW; ++ctl)
        #pragma unroll
        for (int ks = 0; ks < KSn; ++ks) {
            const int c  = w*16*CTW + ctl*16 + m16;
            const int k0 = ks*32 + q4*8;
            Bh[ctl][ks] = *(const bf16x8*)(w2h + c*HO + k0);
            Bl[ctl][ks] = *(const bf16x8*)(w2l + c*HO + k0);
        }

    const float b2c = (t < HO) ? b2[t] : 0.f;
    double ssum = 0., ssq = 0.;

    for (int p0 = blockIdx.x*4; p0 < BN_; p0 += gridDim.x*4) {
        const int bbase = p0 & ~(N_-1);
        __syncthreads();
        if (t < 80) sidx[t] = idx[p0*K_ + t];
        __syncthreads();
        for (int e = t; e < 80*HO; e += 256) {
            const int r  = e >> HSH;
            const int pl = (r*3277) >> 16;     // r/20 for r<80
            const int mI = sidx[r];
            float z = P[(size_t)(p0+pl)*HO + kT] + Q[(size_t)(bbase+mI)*HO + kT];
            float h = fmaxf(z*ac + bc, 0.f);
            unsigned short hh = f2bf(h);
            float hf = __uint_as_float((unsigned)hh << 16);
            unsigned short hl = f2bf(h - hf);
            hs[r*HOP + kT] = (short)hh;
            hs[80*HOP + r*HOP + kT] = (short)hl;
        }
        __syncthreads();
        f32x4 acc[5][CTW];
        #pragma unroll
        for (int rt = 0; rt < 5; ++rt)
            #pragma unroll
            for (int ctl = 0; ctl < CTW; ++ctl)
                acc[rt][ctl] = (f32x4){0.f, 0.f, 0.f, 0.f};
        #pragma unroll
        for (int rt = 0; rt < 5; ++rt)
            #pragma unroll
            for (int ks = 0; ks < KSn; ++ks) {
                const short* ap = hs + (rt*16 + m16)*HOP + ks*32 + q4*8;
                bf16x8 Ah = *(const bf16x8*)ap;
                bf16x8 Al = *(const bf16x8*)(ap + 80*HOP);
                #pragma unroll
                for (int ctl = 0; ctl < CTW; ++ctl) {
                    acc[rt][ctl] = __builtin_amdgcn_mfma_f32_16x16x32_bf16(Ah, Bh[ctl][ks], acc[rt][ctl], 0, 0, 0);
                    acc[rt][ctl] = __builtin_amdgcn_mfma_f32_16x16x32_bf16(Al, Bh[ctl][ks], acc[rt][ctl], 0, 0, 0);
                    acc[rt][ctl] = __builtin_amdgcn_mfma_f32_16x16x32_bf16(Ah, Bl[ctl][ks], acc[rt][ctl], 0, 0, 0);
                }
            }
        __syncthreads();
        #pragma unroll
        for (int rt = 0; rt < 5; ++rt)
            #pragma unroll
            for (int ctl = 0; ctl < CTW; ++ctl) {
                const int col = w*16*CTW + ctl*16 + m16;
                #pragma unroll
                for (int ri = 0; ri < 4; ++ri) {
                    const int row = rt*16 + q4*4 + ri;
                    cd[row*CDP + col] = acc[rt][ctl][ri];
                }
            }
        __syncthreads();
        if (t < HO) {
            #pragma unroll
            for (int pl = 0; pl < 4; ++pl) {
                float mx = -3.4e38f, mn = 3.4e38f;
                #pragma unroll
                for (int j = 0; j < K_; ++j) {
                    float v = cd[(pl*20 + j)*CDP + t] + b2c;
                    mx = fmaxf(mx, v); mn = fminf(mn, v);
                    double vd = (double)v;
                    ssum += vd; ssq += vd*vd;
                }
                zmax[(size_t)(p0+pl)*HO + t] = mx;
                zmin[(size_t)(p0+pl)*HO + t] = mn;
            }
        }
    }
    if (t < HO) {
        partOut[(size_t)blockIdx.x*(2*HO) + t] = ssum;
        partOut[(size_t)blockIdx.x*(2*HO) + HO + t] = ssq;
    }
}

// max_j relu(BN(z)) = relu(BN(max_j z)) for gamma>=0, min for gamma<0.
// R11: reference elementwise op order for the x1b-producing instance.
template<int HO>
__global__ __launch_bounds__(256) void conv_fin_kernel(
    const float* __restrict__ zmax, const float* __restrict__ zmin,
    const float* __restrict__ st2, const float* __restrict__ g2, const float* __restrict__ be2,
    float* __restrict__ out)
{
    int e = blockIdx.x*256 + threadIdx.x;
    int c = e & (HO-1);
    float g = g2[c];
    float sel = (g >= 0.f) ? zmax[e] : zmin[e];
    float bn = __fadd_rn(__fmul_rn(__fmul_rn(__fsub_rn(sel, st2[2*HO + c]), st2[3*HO + c]), g), be2[c]);
    out[e] = fmaxf(bn, 0.f);
}

// ---------------------------------------------------------------- classifier
__global__ __launch_bounds__(256) void cls1_kernel(
    const float* __restrict__ x1, const float* __restrict__ x2f,
    const float* __restrict__ W, const float* __restrict__ b1,
    float* __restrict__ z, double* __restrict__ partOut)
{
    __shared__ float ws[192*64];
    __shared__ float xr[4*192];
    __shared__ double red[256], red2[256];
    const int t = threadIdx.x, cy = blockIdx.y;
    for (int e = t; e < 192*64; e += 256) {
        int c = e >> 6, cl = e & 63;
        ws[e] = W[c*128 + cy*64 + cl];
    }
    const int pl = t >> 6, c2l = t & 63;
    const float b1v = b1[cy*64 + c2l];
    double ssum = 0., ssq = 0.;
    for (int p0 = blockIdx.x*4; p0 < BN_; p0 += gridDim.x*4) {
        __syncthreads();
        for (int l = t; l < 4*192; l += 256) {
            int pp = l / 192, cc = l % 192;
            xr[l] = (cc < 64) ? x1[(p0+pp)*64 + cc] : x2f[(p0+pp)*128 + cc - 64];
        }
        __syncthreads();
        float acc = b1v;
        const float* xx = xr + pl*192;
        #pragma unroll 8
        for (int c = 0; c < 192; ++c) acc += xx[c] * ws[c*64 + c2l];
        z[(p0+pl)*128 + cy*64 + c2l] = acc;
        double ad = (double)acc;
        ssum += ad; ssq += ad*ad;
    }
    __syncthreads();
    red[t] = ssum; red2[t] = ssq;
    __syncthreads();
    if (t < 64) {
        double s = red[t], s2 = red2[t];
        #pragma unroll
        for (int g = 1; g < 4; ++g) { s += red[g*64 + t]; s2 += red2[g*64 + t]; }
        // partial row layout [512][256]: (sum ch0..127, sumsq ch0..127); the two
        // cy-planes of the same blockIdx.x fill disjoint 64-ch ranges.
        partOut[(size_t)blockIdx.x*256 + cy*64 + t] = s;
        partOut[(size_t)blockIdx.x*256 + 128 + cy*64 + t] = s2;
    }
}

__global__ __launch_bounds__(256) void cls_fin_kernel(
    const float* __restrict__ z, const float* __restrict__ st,
    const float* __restrict__ g, const float* __restrict__ be,
    const float* __restrict__ w2, const float* __restrict__ b2,
    float* __restrict__ out)
{
    const int t = threadIdx.x, w = t >> 6, L = t & 63;
    const int p = blockIdx.x*4 + w;
    float s = 0.f;
    #pragma unroll
    for (int h = 0; h < 2; ++h) {
        int c = L + h*64;
        float v = (z[p*128 + c] - st[256 + c]) * st[384 + c] * g[c] + be[c];
        s += fmaxf(v, 0.f) * w2[c];
    }
    #pragma unroll
    for (int off = 32; off; off >>= 1) s += __shfl_xor(s, off);
    if (L == 0) out[p] = s + b2[0];
}

// ---------------------------------------------------------------- launch
extern "C" void kernel_launch(void* const* d_in, const int* in_sizes, int n_in,
                              void* d_out, int out_size, void* d_ws, size_t ws_size,
                              hipStream_t stream)
{
    const float* x      = (const float*)d_in[0];
    const float* c1_w1  = (const float*)d_in[1];
    const float* c1_b1  = (const float*)d_in[2];
    const float* c1_g1  = (const float*)d_in[3];
    const float* c1_be1 = (const float*)d_in[4];
    const float* c1_w2  = (const float*)d_in[5];
    const float* c1_b2  = (const float*)d_in[6];
    const float* c1_g2  = (const float*)d_in[7];
    const float* c1_be2 = (const float*)d_in[8];
    const float* c2_w1  = (const float*)d_in[9];
    const float* c2_b1  = (const float*)d_in[10];
    const float* c2_g1  = (const float*)d_in[11];
    const float* c2_be1 = (const float*)d_in[12];
    const float* c2_w2  = (const float*)d_in[13];
    const float* c2_b2  = (const float*)d_in[14];
    const float* c2_g2  = (const float*)d_in[15];
    const float* c2_be2 = (const float*)d_in[16];
    const float* cls_w1 = (const float*)d_in[17];
    const float* cls_b1 = (const float*)d_in[18];
    const float* cls_g1 = (const float*)d_in[19];
    const float* cls_be1= (const float*)d_in[20];
    const float* cls_w2 = (const float*)d_in[21];
    const float* cls_b2 = (const float*)d_in[22];
    (void)in_sizes; (void)n_in; (void)out_size; (void)ws_size;

    char* ws = (char*)d_ws;
    size_t off = 0;
    auto alloc = [&](size_t bytes) { char* p = ws + off; off += (bytes + 255) & ~255ull; return p; };
    float* A    = (float*)alloc((size_t)16<<20);   // P1 -> P2 -> zcls
    float* Bq   = (float*)alloc((size_t)16<<20);   // Q1 -> Q2 -> cls partials
    float* zmax = (float*)alloc((size_t)16<<20);   // also hosts Xh/Xl between conv1 and conv2
    float* zmin = (float*)alloc((size_t)16<<20);
    float* x1b  = (float*)alloc((size_t)8<<20);
    float* x2b  = (float*)alloc((size_t)16<<20);   // also hosts idx24 + stats partials (dead windows)
    int*   idx  = (int*)  alloc((size_t)BN_*K_*4); // idx1 -> idx2
    float* nrm  = (float*)alloc((size_t)BN_*4);
    float* st   = (float*)alloc((size_t)5*512*4);
    unsigned short* w2th = (unsigned short*)alloc((size_t)128*128*2);  // W2^T hi
    unsigned short* w2tl = (unsigned short*)alloc((size_t)128*128*2);  // W2^T lo
    float *st0 = st, *st1 = st+512, *st2 = st+1024, *st3 = st+1536, *st4 = st+2048;

    unsigned short* Xh = (unsigned short*)zmax;                       // 4 MB
    unsigned short* Xl = (unsigned short*)((char*)zmax + (4<<20));    // 4 MB
    int* idx24 = (int*)x2b;
    double* part  = (double*)x2b;  // fp64 stats partials (max 4 MB): free during both conv phases
    double* partC = (double*)Bq;   // cls stats partials (1 MB): Q2 dead after conv_l2_mfma

    // ---- EdgeConv 1 (exact fp32 conv: x1b feeds flip-sensitive kNN2)
    knn4_kernel<<<dim3(N_/16, B_), 1024, 0, stream>>>(x, idx);
    pq1_kernel<<<BN_/4, 256, 0, stream>>>(x, c1_w1, c1_b1, A, Bq);
    stats_l1_kernel<64><<<2048, 256, 0, stream>>>(A, Bq, idx, part);
    finalize_parts_kernel<<<64, 256, 0, stream>>>(part, 2048, 64, 1.0/655360.0, st0);
    conv_l2_kernel<64><<<dim3(2048,1), 256, 0, stream>>>(A, Bq, idx, st0, c1_g1, c1_be1, c1_w2, c1_b2, zmax, zmin, part);
    finalize_parts_kernel<<<64, 256, 0, stream>>>(part, 2048, 64, 1.0/655360.0, st1);
    conv_fin_kernel<64><<<BN_*64/256, 256, 0, stream>>>(zmax, zmin, st1, c1_g2, c1_be2, x1b);

    // ---- EdgeConv 2 (MFMA conv: x2b only feeds classifier)
    prep64_kernel<<<BN_/4, 256, 0, stream>>>(x1b, Xh, Xl, nrm);
    knn64v4_kernel<<<dim3(N_/16, B_), 1024, 0, stream>>>(Xh, Xl, nrm, idx24);
    rescore_kernel<<<BN_/4, 256, 0, stream>>>(x1b, nrm, idx24, idx);
    pq2_kernel<<<1024, 256, 0, stream>>>(x1b, c2_w1, c2_b1, A, Bq);
    stats_l1_kernel<128><<<2048, 256, 0, stream>>>(A, Bq, idx, part);
    finalize_parts_kernel<<<128, 256, 0, stream>>>(part, 2048, 128, 1.0/655360.0, st2);
    prep_w2t_kernel<<<128*128/256, 256, 0, stream>>>(c2_w2, w2th, w2tl, 128);
    conv_l2_mfma_kernel<128><<<2048, 256, 0, stream>>>(A, Bq, idx, st2, c2_g1, c2_be1, w2th, w2tl, c2_b2, zmax, zmin, part);
    finalize_parts_kernel<<<128, 256, 0, stream>>>(part, 2048, 128, 1.0/655360.0, st3);
    conv_fin_kernel<128><<<BN_*128/256, 256, 0, stream>>>(zmax, zmin, st3, c2_g2, c2_be2, x2b);

    // ---- classifier
    cls1_kernel<<<dim3(512,2), 256, 0, stream>>>(x1b, x2b, cls_w1, cls_b1, A, partC);
    finalize_parts_kernel<<<128, 256, 0, stream>>>(partC, 512, 128, 1.0/32768.0, st4);
    cls_fin_kernel<<<BN_/4, 256, 0, stream>>>(A, st4, cls_g1, cls_be1, cls_w2, cls_b2, (float*)d_out);
}

// Round 7
// 1414.226 us; speedup vs baseline: 1.0838x; 1.0001x over previous
//
#include <hip/hip_runtime.h>
#include <math.h>

#define B_ 8
#define N_ 4096
#define K_ 20
#define KS_ 24          // approx-select width; exact rescore trims to K_ (R3-validated margin)
#define BN_ (B_*N_)

typedef __attribute__((ext_vector_type(8))) short bf16x8;
typedef __attribute__((ext_vector_type(4))) float f32x4;

// ---------------------------------------------------------------- BN stats finalize (deterministic, fp64)
// R10: float atomicAdd stats were order-nondeterministic across graph replays ->
// kNN2 boundary flip -> post-timing divergence.  R11: the deterministic fp32
// order landed on the WRONG side of a ~1-ULP distance tie (absmax 0.1177).
// All stats now accumulate in DOUBLE (partials + reduce + mean/var/rstd), so our
// stats are ~exact; the x1b-feeding BN applies the reference's elementwise op
// order; rescore uses the reference's full d formula.  DO NOT reintroduce
// atomicAdd or fold these back into fp32/FMA on the conv1 path.
// part layout: [nb][2*H] doubles (sum(H), sumsq(H) per block row).
__global__ __launch_bounds__(256) void finalize_parts_kernel(
    const double* __restrict__ part, int nb, int H, double invCount, float* __restrict__ st)
{
    __shared__ double red[256], red2[256];
    const int c = blockIdx.x, t = threadIdx.x;
    double s = 0., s2 = 0.;
    for (int b = t; b < nb; b += 256) {
        s  += part[(size_t)b*2*H + c];
        s2 += part[(size_t)b*2*H + H + c];
    }
    red[t] = s; red2[t] = s2;
    __syncthreads();
    #pragma unroll
    for (int off = 128; off; off >>= 1) {
        if (t < off) { red[t] += red[t+off]; red2[t] += red2[t+off]; }
        __syncthreads();
    }
    if (t == 0) {
        double mean = red[0] * invCount;
        double var  = fmax(red2[0] * invCount - mean * mean, 0.);
        st[2*H + c] = (float)mean;
        st[3*H + c] = (float)(1.0 / sqrt(var + 1e-5));
    }
}

// ---------------------------------------------------------------- kNN, C=4
// R7-validated (value, candidate-index) lexicographic argmin — matches jax
// top_k tie-break; reference-defining (no rescore guard) -> selection EXACT.
// R15: rolled loops (L1I); d[64] eliminated via fused compute+insert; rescans
// recompute dists (bit-identical).  DO NOT replace with DPP (R9).
__global__ __launch_bounds__(1024, 8) void knn4_kernel(const float* __restrict__ x, int* __restrict__ idxout)
{
    __shared__ float4 xt[N_];   // 64 KB
    const int b = blockIdx.y;
    const int t = threadIdx.x;
    const float4* xg = (const float4*)x + b*N_;
    for (int e = t; e < N_; e += 1024) xt[e] = xg[e];
    __syncthreads();
    const int w = t >> 6, L = t & 63;
    const int n = blockIdx.x*16 + w;
    const float4 q = xt[n];
    const float MX = 3.4e38f;
    float m1 = MX, m2 = MX, m3 = MX; int i1 = 0, i2 = 0, i3 = 0;
    #pragma unroll 1
    for (int j = 0; j < 64; ++j) {
        float4 vv = xt[(j<<6) | L];
        float nn = vv.x*vv.x + vv.y*vv.y + vv.z*vv.z + vv.w*vv.w;
        float dp = q.x*vv.x + q.y*vv.y + q.z*vv.z + q.w*vv.w;
        float v = nn - 2.f*dp;   // |xn|^2 dropped: rank-equivalent
        bool c1 = v < m1, c2 = v < m2, c3 = v < m3;
        m3 = c2 ? m2 : (c3 ? v : m3);
        i3 = c2 ? i2 : (c3 ? j : i3);
        m2 = c1 ? m1 : (c2 ? v : m2);
        i2 = c1 ? i1 : (c2 ? j : i2);
        m1 = c1 ? v : m1;
        i1 = c1 ? j : i1;
    }
    unsigned long long used = 0;
    int mywin = 0;
    #pragma unroll 1
    for (int r = 0; r < K_; ++r) {
        float bv = m1; int bg = (i1<<6) | L;
        #pragma unroll
        for (int off = 32; off; off >>= 1) {
            float ov = __shfl_xor(bv, off);
            int   og = __shfl_xor(bg, off);
            bool tk = (ov < bv) || (ov == bv && og < bg);
            bv = tk ? ov : bv; bg = tk ? og : bg;
        }
        if (L == r) mywin = bg;
        if (L == (bg & 63)) {
            used |= 1ull << i1;
            m1 = m2; i1 = i2; m2 = m3; i2 = i3; m3 = MX;
            if (m1 == MX) {
                m2 = MX; m3 = MX; i1 = 0; i2 = 0; i3 = 0;
                #pragma unroll 1
                for (int j = 0; j < 64; ++j) {
                    float4 vv = xt[(j<<6) | L];
                    float nn = vv.x*vv.x + vv.y*vv.y + vv.z*vv.z + vv.w*vv.w;
                    float dp = q.x*vv.x + q.y*vv.y + q.z*vv.z + q.w*vv.w;
                    float dj = nn - 2.f*dp;
                    float v = ((used >> j) & 1ull) ? MX : dj;
                    bool c1 = v < m1, c2 = v < m2, c3 = v < m3;
                    m3 = c2 ? m2 : (c3 ? v : m3);
                    i3 = c2 ? i2 : (c3 ? j : i3);
                    m2 = c1 ? m1 : (c2 ? v : m2);
                    i2 = c1 ? i1 : (c2 ? j : i2);
                    m1 = c1 ? v : m1;
                    i1 = c1 ? j : i1;
                }
            }
        }
    }
    if (L < K_) idxout[(b*N_ + n)*K_ + L] = mywin;
}

// ---------------------------------------------------------------- fp32 -> bf16 RNE
static __device__ inline unsigned short f2bf(float f)
{
    unsigned u = __float_as_uint(f);
    unsigned r = (u + 0x7fffu + ((u >> 16) & 1u)) >> 16;   // RNE
    return (unsigned short)r;
}

__global__ __launch_bounds__(256) void prep64_kernel(const float* __restrict__ x,
                                                     unsigned short* __restrict__ Xh,
                                                     unsigned short* __restrict__ Xl,
                                                     float* __restrict__ nrm)
{
    const int t = threadIdx.x, L = t & 63;
    const int row = blockIdx.x*4 + (t >> 6);
    const float v = x[row*64 + L];
    unsigned short h = f2bf(v);
    float hf = __uint_as_float((unsigned)h << 16);
    unsigned short l = f2bf(v - hf);
    Xh[row*64 + L] = h;
    Xl[row*64 + L] = l;
    float s = v * v;
    #pragma unroll
    for (int off = 32; off; off >>= 1) s += __shfl_xor(s, off);
    if (L == 0) nrm[row] = s;
}

// ---------------------------------------------------------------- kNN, C=64 via MFMA (split-bf16 Gram, approx)
// v9 (R16): selection latency attacked.  KEY INSIGHT: idx24 is an unordered
// SET (rescore re-orders), so ordered 2-winner extraction is overkill.
// New: 3 super-rounds; each does ONE 6-step butterfly all-reduce with the
// associative op "sorted lowest-8 of union" (bitonic min-merge c[i]=
// min(a[i],b[7-i]) + 12-CE cleanup), yielding the exact global top-8 of the
// snapshot at every lane, then 8 sequential ballot+pops.  Butterfly sub-cubes
// are disjoint -> no double counting; a lane winning k<=8 times is fully
// visible (R13 readlane fix obsolete).  Serial chain ~2200 cyc vs ~4000.
// Scan gains an `if (v < sm7)` filter — provably identical (v>=sm7 makes the
// insert chain a no-op).  Keys/slot-embed (R12), XOR-swizzle (R12), rolled
// staging (R15), top-8 dropout P~5e-9 (R14) all unchanged.
__global__ __launch_bounds__(1024, 4) void knn64v4_kernel(
    const unsigned short* __restrict__ Xh, const unsigned short* __restrict__ Xl,
    const float* __restrict__ nrm, int* __restrict__ idx24)
{
    __shared__ float dist[16*1024];   // exactly 64 KB
    const int b = blockIdx.y, t = threadIdx.x;
    const int w = t >> 6, L = t & 63;
    const int q0 = blockIdx.x * 16;
    const int m = L & 15, q4 = L >> 4, kq = q4 * 8;
    const size_t rowbase = (size_t)b * N_ * 64;
    const int swzW = q4 << 4;         // write-side column XOR (qrow>>2 == q4)
    const int swzR = (w >> 2) << 4;   // read-side column XOR (query row w)

    const unsigned short* aph = Xh + rowbase + (size_t)(q0 + m)*64 + kq;
    const unsigned short* apl = Xl + rowbase + (size_t)(q0 + m)*64 + kq;
    const bf16x8 a_h0 = *(const bf16x8*)(aph);
    const bf16x8 a_h1 = *(const bf16x8*)(aph + 32);
    const bf16x8 a_l0 = *(const bf16x8*)(apl);
    const bf16x8 a_l1 = *(const bf16x8*)(apl + 32);

    const float MX = 3.4e38f;
    float sm0 = MX, sm1 = MX, sm2 = MX, sm3 = MX, sm4 = MX, sm5 = MX, sm6 = MX, sm7 = MX;

    #pragma unroll 1
    for (int ck = 0; ck < 4; ++ck) {
        const int cq = ck * 1024;
        const unsigned slotW = (unsigned)(ck*16 + w);   // global slot of this wave's candidates
        __syncthreads();
        #pragma unroll 1
        for (int tt = 0; tt < 4; ++tt) {
            const int cbase = w*64 + tt*16;
            const unsigned short* bph = Xh + rowbase + (size_t)(cq + cbase + m)*64 + kq;
            const unsigned short* bpl = Xl + rowbase + (size_t)(cq + cbase + m)*64 + kq;
            bf16x8 b_h0 = *(const bf16x8*)(bph);
            bf16x8 b_h1 = *(const bf16x8*)(bph + 32);
            bf16x8 b_l0 = *(const bf16x8*)(bpl);
            bf16x8 b_l1 = *(const bf16x8*)(bpl + 32);
            f32x4 acc = {0.f, 0.f, 0.f, 0.f};
            acc = __builtin_amdgcn_mfma_f32_16x16x32_bf16(a_h0, b_h0, acc, 0, 0, 0);
            acc = __builtin_amdgcn_mfma_f32_16x16x32_bf16(a_h1, b_h1, acc, 0, 0, 0);
            acc = __builtin_amdgcn_mfma_f32_16x16x32_bf16(a_l0, b_h0, acc, 0, 0, 0);
            acc = __builtin_amdgcn_mfma_f32_16x16x32_bf16(a_l1, b_h1, acc, 0, 0, 0);
            acc = __builtin_amdgcn_mfma_f32_16x16x32_bf16(a_h0, b_l0, acc, 0, 0, 0);
            acc = __builtin_amdgcn_mfma_f32_16x16x32_bf16(a_h1, b_l1, acc, 0, 0, 0);
            const float nv = nrm[b*N_ + cq + cbase + m];
            const int colW = (cbase + m) ^ swzW;
            #pragma unroll
            for (int r = 0; r < 4; ++r) {
                float dv = nv - 2.f*acc[r];
                unsigned key = (__float_as_uint(dv) & ~63u) | slotW;
                dist[(q4*4 + r)*1024 + colW] = __uint_as_float(key);
            }
        }
        __syncthreads();
        // scan this ck's 16 values straight from LDS into the sorted top-8
        #pragma unroll 1
        for (int s = 0; s < 16; ++s) {
            float v = dist[w*1024 + (((s<<6) + L) ^ swzR)];
            if (v < sm7) {
                float tt2;
                tt2 = fminf(sm0, v); v = fmaxf(sm0, v); sm0 = tt2;
                tt2 = fminf(sm1, v); v = fmaxf(sm1, v); sm1 = tt2;
                tt2 = fminf(sm2, v); v = fmaxf(sm2, v); sm2 = tt2;
                tt2 = fminf(sm3, v); v = fmaxf(sm3, v); sm3 = tt2;
                tt2 = fminf(sm4, v); v = fmaxf(sm4, v); sm4 = tt2;
                tt2 = fminf(sm5, v); v = fmaxf(sm5, v); sm5 = tt2;
                tt2 = fminf(sm6, v); v = fmaxf(sm6, v); sm6 = tt2;
                sm7 = fminf(sm7, v);
            }
        }
    }

    int mywin = 0;
    #pragma unroll 1
    for (int sr = 0; sr < 3; ++sr) {
        // butterfly all-reduce: global sorted top-8 of the union of all lanes' lists
        float a0 = sm0, a1 = sm1, a2 = sm2, a3 = sm3, a4 = sm4, a5 = sm5, a6 = sm6, a7 = sm7;
        #pragma unroll
        for (int off = 32; off; off >>= 1) {
            float b0 = __shfl_xor(a0, off), b1 = __shfl_xor(a1, off);
            float b2 = __shfl_xor(a2, off), b3 = __shfl_xor(a3, off);
            float b4 = __shfl_xor(a4, off), b5 = __shfl_xor(a5, off);
            float b6 = __shfl_xor(a6, off), b7 = __shfl_xor(a7, off);
            // lowest-8 of two sorted-8 lists (bitonic min-merge)
            float c0 = fminf(a0, b7), c1 = fminf(a1, b6), c2 = fminf(a2, b5), c3 = fminf(a3, b4);
            float c4 = fminf(a4, b3), c5 = fminf(a5, b2), c6 = fminf(a6, b1), c7 = fminf(a7, b0);
            // bitonic cleanup: distances 4, 2, 1
            float u;
            u = fminf(c0, c4); c4 = fmaxf(c0, c4); c0 = u;
            u = fminf(c1, c5); c5 = fmaxf(c1, c5); c1 = u;
            u = fminf(c2, c6); c6 = fmaxf(c2, c6); c2 = u;
            u = fminf(c3, c7); c7 = fmaxf(c3, c7); c3 = u;
            u = fminf(c0, c2); c2 = fmaxf(c0, c2); c0 = u;
            u = fminf(c1, c3); c3 = fmaxf(c1, c3); c1 = u;
            u = fminf(c4, c6); c6 = fmaxf(c4, c6); c4 = u;
            u = fminf(c5, c7); c7 = fmaxf(c5, c7); c5 = u;
            u = fminf(c0, c1); c1 = fmaxf(c0, c1); c0 = u;
            u = fminf(c2, c3); c3 = fmaxf(c2, c3); c2 = u;
            u = fminf(c4, c5); c5 = fmaxf(c4, c5); c4 = u;
            u = fminf(c6, c7); c7 = fmaxf(c6, c7); c6 = u;
            a0 = c0; a1 = c1; a2 = c2; a3 = c3; a4 = c4; a5 = c5; a6 = c6; a7 = c7;
        }
        // extract the 8 winners in ascending order (set semantics; min-lane on ties)
        #define POPW(AW, WIDX)                                                              \
        {                                                                                   \
            const unsigned long long bal = __ballot(sm0 == (AW));                           \
            const int owner = (int)__ffsll(bal) - 1;                                        \
            if (L == sr*8 + (WIDX))                                                         \
                mywin = (int)(((__float_as_uint(AW) & 63u) << 6) | (unsigned)owner);        \
            if (L == owner) {                                                               \
                sm0 = sm1; sm1 = sm2; sm2 = sm3; sm3 = sm4;                                 \
                sm4 = sm5; sm5 = sm6; sm6 = sm7; sm7 = MX;                                  \
            }                                                                               \
        }
        POPW(a0, 0) POPW(a1, 1) POPW(a2, 2) POPW(a3, 3)
        POPW(a4, 4) POPW(a5, 5) POPW(a6, 6) POPW(a7, 7)
        #undef POPW
    }
    if (L < KS_) idx24[((size_t)b*N_ + q0 + w)*KS_ + L] = mywin;
}

// ---------------------------------------------------------------- exact fp32 rescore of the KS_ candidates
// R11: d matches the reference formula exactly.  R13: two winners per round
// (10 rounds).  Exact without a readlane fix: every lane holds ONE always-valid
// candidate, so the butterfly's top-2 over (dv,MX) pairs is the true top-2;
// candidate indices are unique (extraction marks used), so pops are unambiguous.
// R15: round loop rolled (code size).
__global__ __launch_bounds__(256) void rescore_kernel(const float* __restrict__ x1, const float* __restrict__ nrm,
                                                      const int* __restrict__ idx24, int* __restrict__ idxout)
{
    const int t = threadIdx.x, w = t >> 6, L = t & 63;
    const int p = blockIdx.x*4 + w;
    const int bbase = p & ~(N_-1);
    const float MX = 3.4e38f;
    float dv = MX; int di = 0x7fffffff;
    if (L < KS_) {
        const int ci = idx24[(size_t)p*KS_ + L];
        const float4* qr = (const float4*)(x1 + (size_t)p*64);
        const float4* cr = (const float4*)(x1 + (size_t)(bbase + ci)*64);
        float dot = 0.f;
        #pragma unroll
        for (int i = 0; i < 16; ++i) {
            float4 a = qr[i], bx = cr[i];
            dot += a.x*bx.x + a.y*bx.y + a.z*bx.z + a.w*bx.w;
        }
        dv = __fsub_rn(__fadd_rn(nrm[p], nrm[bbase + ci]), 2.f*dot);
        di = ci;
    }
    int myfin = 0;
    #pragma unroll 1
    for (int r = 0; r < K_/2; ++r) {
        float v1 = dv; int g1 = di;
        float v2 = MX; int g2 = 0x7fffffff;
        #pragma unroll
        for (int off = 32; off; off >>= 1) {
            float ov1 = __shfl_xor(v1, off); int og1 = __shfl_xor(g1, off);
            float ov2 = __shfl_xor(v2, off); int og2 = __shfl_xor(g2, off);
            bool c1 = (ov1 < v1) || (ov1 == v1 && og1 < g1);
            float hv = c1 ? v1 : ov1; int hg = c1 ? g1 : og1;
            v1 = c1 ? ov1 : v1;       g1 = c1 ? og1 : g1;
            bool c2 = (ov2 < v2) || (ov2 == v2 && og2 < g2);
            float l2v = c2 ? ov2 : v2; int l2g = c2 ? og2 : g2;
            bool c3 = (l2v < hv) || (l2v == hv && l2g < hg);
            v2 = c3 ? l2v : hv;  g2 = c3 ? l2g : hg;
        }
        if (L == 2*r)   myfin = g1;
        if (L == 2*r+1) myfin = g2;
        if (di == g1 || di == g2) dv = MX;
    }
    if (L < K_) idxout[(size_t)p*K_ + L] = myfin;
}

// ---------------------------------------------------------------- P/Q precompute
__global__ __launch_bounds__(256) void pq1_kernel(const float* __restrict__ x, const float* __restrict__ W,
                                                  const float* __restrict__ b1,
                                                  float* __restrict__ P, float* __restrict__ Q)
{
    __shared__ float wd[256], wb[256];
    const int t = threadIdx.x;
    wd[t] = W[t] - W[256 + t];
    wb[t] = W[256 + t];
    __syncthreads();
    const int p = blockIdx.x*4 + (t >> 6), c = t & 63;
    const float4 xv = ((const float4*)x)[p];
    float Pv = b1[c] + xv.x*wd[c] + xv.y*wd[64+c] + xv.z*wd[128+c] + xv.w*wd[192+c];
    float Qv =         xv.x*wb[c] + xv.y*wb[64+c] + xv.z*wb[128+c] + xv.w*wb[192+c];
    P[p*64 + c] = Pv;
    Q[p*64 + c] = Qv;
}

__global__ __launch_bounds__(256) void pq2_kernel(const float* __restrict__ x1, const float* __restrict__ W,
                                                  const float* __restrict__ b1,
                                                  float* __restrict__ P, float* __restrict__ Q)
{
    __shared__ float wd[64*128], wb[64*128];
    const int t = threadIdx.x;
    for (int e = t; e < 8192; e += 256) {
        float wt = W[e], wbo = W[8192 + e];
        wd[e] = wt - wbo; wb[e] = wbo;
    }
    __syncthreads();
    const int pl = t >> 7, c = t & 127;
    const float b1v = b1[c];
    for (int p0 = blockIdx.x*2; p0 < BN_; p0 += gridDim.x*2) {
        const int p = p0 + pl;
        float Pv = b1v, Qv = 0.f;
        const float* xrow = x1 + p*64;
        #pragma unroll 8
        for (int k = 0; k < 64; ++k) {
            float xv = xrow[k];
            Pv += xv * wd[k*128 + c];
            Qv += xv * wb[k*128 + c];
        }
        P[p*128 + c] = Pv;
        Q[p*128 + c] = Qv;
    }
}

// ---------------------------------------------------------------- layer-1 BN stats (fp64 per-block partials)
template<int HO>
__global__ __launch_bounds__(256) void stats_l1_kernel(const float* __restrict__ P, const float* __restrict__ Q,
                                                       const int* __restrict__ idx, double* __restrict__ partOut)
{
    constexpr int G = 256/HO;
    __shared__ double red[256], red2[256];
    const int t = threadIdx.x, c = t % HO, g = t / HO;
    double s = 0., s2 = 0.;
    for (int p = blockIdx.x; p < BN_; p += gridDim.x) {
        const float Pv = P[p*HO + c];
        const int bbase = p & ~(N_-1);
        for (int j = g; j < K_; j += G) {
            int m = idx[p*K_ + j];
            float z = Pv + Q[(bbase + m)*HO + c];
            double zd = (double)z;
            s += zd; s2 += zd*zd;
        }
    }
    red[t] = s; red2[t] = s2;
    __syncthreads();
    if (t < HO) {
        double a = red[t], a2 = red2[t];
        #pragma unroll
        for (int q = 1; q < G; ++q) { a += red[q*HO + t]; a2 += red2[q*HO + t]; }
        partOut[(size_t)blockIdx.x*(2*HO) + t] = a;
        partOut[(size_t)blockIdx.x*(2*HO) + HO + t] = a2;
    }
}

// ---------------------------------------------------------------- EdgeConv layer-2, exact fp32 (conv1:
// its output feeds kNN2, which is flip-sensitive to ~1e-4 feature perturbation).
// R11: BN applied in the reference's elementwise op order (((z-m)*rstd)*g+be,
// separately rounded) — the folded z*ac+bc form differed by 1-2 ULP on x1 features.
template<int HO>
__global__ __launch_bounds__(256) void conv_l2_kernel(
    const float* __restrict__ P, const float* __restrict__ Q, const int* __restrict__ idx,
    const float* __restrict__ st1, const float* __restrict__ g1, const float* __restrict__ be1,
    const float* __restrict__ w2, const float* __restrict__ b2,
    float* __restrict__ zmax, float* __restrict__ zmin, double* __restrict__ partOut)
{
    __shared__ float w2s[HO*64];
    __shared__ float h1s[K_*HO];
    __shared__ float redA[256], redB[256];
    __shared__ double redD[256], redD2[256];
    const int t = threadIdx.x;
    const int cy = blockIdx.y;
    for (int e = t; e < HO*64; e += 256) {
        int c = e >> 6, cl = e & 63;
        w2s[e] = w2[c*HO + cy*64 + cl];
    }
    const int cA = t % HO;
    const float mA = st1[2*HO + cA], rA = st1[3*HO + cA];
    const float gA = g1[cA], beA = be1[cA];
    const int c2l = t & 63, jh = t >> 6;
    const float b2v = b2[cy*64 + c2l];
    double ssum = 0., ssq = 0.;
    for (int p = blockIdx.x; p < BN_; p += gridDim.x) {
        __syncthreads();
        const int bbase = p & ~(N_-1);
        const float Pv = P[p*HO + cA];
        for (int e = t; e < K_*HO; e += 256) {
            int j = e / HO;
            int m = idx[p*K_ + j];
            float z = Pv + Q[(bbase + m)*HO + cA];
            float bn = __fadd_rn(__fmul_rn(__fmul_rn(__fsub_rn(z, mA), rA), gA), beA);
            h1s[e] = fmaxf(bn, 0.f);
        }
        __syncthreads();
        float acc[5];
        #pragma unroll
        for (int q = 0; q < 5; ++q) acc[q] = b2v;
        for (int c = 0; c < HO; ++c) {
            float wv = w2s[c*64 + c2l];
            #pragma unroll
            for (int q = 0; q < 5; ++q)
                acc[q] += h1s[(jh + q*4)*HO + c] * wv;
        }
        float mx = acc[0], mn = acc[0];
        #pragma unroll
        for (int q = 0; q < 5; ++q) {
            mx = fmaxf(mx, acc[q]); mn = fminf(mn, acc[q]);
            double ad = (double)acc[q];
            ssum += ad; ssq += ad*ad;
        }
        redA[t] = mx; redB[t] = mn;
        __syncthreads();
        if (t < 64) {
            float M = redA[t], Mn = redB[t];
            #pragma unroll
            for (int g = 1; g < 4; ++g) { M = fmaxf(M, redA[g*64 + t]); Mn = fminf(Mn, redB[g*64 + t]); }
            zmax[p*HO + cy*64 + t] = M;
            zmin[p*HO + cy*64 + t] = Mn;
        }
    }
    __syncthreads();
    redD[t] = ssum; redD2[t] = ssq;
    __syncthreads();
    if (t < 64) {
        double s = redD[t], s2 = redD2[t];
        #pragma unroll
        for (int g = 1; g < 4; ++g) { s += redD[g*64 + t]; s2 += redD2[g*64 + t]; }
        partOut[(size_t)blockIdx.x*(2*HO) + cy*64 + t] = s;
        partOut[(size_t)blockIdx.x*(2*HO) + HO + cy*64 + t] = s2;
    }
}

// ---------------------------------------------------------------- W2^T split-bf16 prep
__global__ __launch_bounds__(256) void prep_w2t_kernel(const float* __restrict__ W,
                                                       unsigned short* __restrict__ wh,
                                                       unsigned short* __restrict__ wl, int HO)
{
    const int e = blockIdx.x*256 + threadIdx.x;   // e = k*HO + c
    const int k = e / HO, c = e % HO;
    const float v = W[e];
    unsigned short h = f2bf(v);
    float hf = __uint_as_float((unsigned)h << 16);
    wh[c*HO + k] = h;
    wl[c*HO + k] = f2bf(v - hf);
}

// ---------------------------------------------------------------- EdgeConv layer-2 via MFMA (split-bf16)
// conv2 only: output feeds the classifier (value-continuous), bf16-split safe.
template<int HO>
__global__ __launch_bounds__(256) void conv_l2_mfma_kernel(
    const float* __restrict__ P, const float* __restrict__ Q, const int* __restrict__ idx,
    const float* __restrict__ st1, const float* __restrict__ g1, const float* __restrict__ be1,
    const unsigned short* __restrict__ w2h, const unsigned short* __restrict__ w2l,
    const float* __restrict__ b2,
    float* __restrict__ zmax, float* __restrict__ zmin, double* __restrict__ partOut)
{
    constexpr int HOP = HO + 8;
    constexpr int CDP = HO + 1;
    constexpr int CTW = HO / 64;
    constexpr int KSn = HO / 32;
    constexpr int HSH = (HO == 128) ? 7 : 6;
    __shared__ __align__(16) short hs[2*80*HOP];
    __shared__ int sidx[80];
    float* cd = (float*)hs;

    const int t = threadIdx.x, w = t >> 6, L = t & 63;
    const int m16 = L & 15, q4 = L >> 4;

    const int kT = t & (HO - 1);
    const float ac = st1[3*HO + kT] * g1[kT];
    const float bc = be1[kT] - st1[2*HO + kT] * ac;

    bf16x8 Bh[CTW][KSn], Bl[CTW][KSn];
    #pragma unroll
    for (int ctl = 0; ctl < CTW; ++ctl)
        #pragma unroll
        for (int ks = 0; ks < KSn; ++ks) {
            const int c  = w*16*CTW + ctl*16 + m16;
            const int k0 = ks*32 + q4*8;
            Bh[ctl][ks] = *(const bf16x8*)(w2h + c*HO + k0);
            Bl[ctl][ks] = *(const bf16x8*)(w2l + c*HO + k0);
        }

    const float b2c = (t < HO) ? b2[t] : 0.f;
    double ssum = 0., ssq = 0.;

    for (int p0 = blockIdx.x*4; p0 < BN_; p0 += gridDim.x*4) {
        const int bbase = p0 & ~(N_-1);
        __syncthreads();
        if (t < 80) sidx[t] = idx[p0*K_ + t];
        __syncthreads();
        for (int e = t; e < 80*HO; e += 256) {
            const int r  = e >> HSH;
            const int pl = (r*3277) >> 16;     // r/20 for r<80
            const int mI = sidx[r];
            float z = P[(size_t)(p0+pl)*HO + kT] + Q[(size_t)(bbase+mI)*HO + kT];
            float h = fmaxf(z*ac + bc, 0.f);
            unsigned short hh = f2bf(h);
            float hf = __uint_as_float((unsigned)hh << 16);
            unsigned short hl = f2bf(h - hf);
            hs[r*HOP + kT] = (short)hh;
            hs[80*HOP + r*HOP + kT] = (short)hl;
        }
        __syncthreads();
        f32x4 acc[5][CTW];
        #pragma unroll
        for (int rt = 0; rt < 5; ++rt)
            #pragma unroll
            for (int ctl = 0; ctl < CTW; ++ctl)
                acc[rt][ctl] = (f32x4){0.f, 0.f, 0.f, 0.f};
        #pragma unroll
        for (int rt = 0; rt < 5; ++rt)
            #pragma unroll
            for (int ks = 0; ks < KSn; ++ks) {
                const short* ap = hs + (rt*16 + m16)*HOP + ks*32 + q4*8;
                bf16x8 Ah = *(const bf16x8*)ap;
                bf16x8 Al = *(const bf16x8*)(ap + 80*HOP);
                #pragma unroll
                for (int ctl = 0; ctl < CTW; ++ctl) {
                    acc[rt][ctl] = __builtin_amdgcn_mfma_f32_16x16x32_bf16(Ah, Bh[ctl][ks], acc[rt][ctl], 0, 0, 0);
                    acc[rt][ctl] = __builtin_amdgcn_mfma_f32_16x16x32_bf16(Al, Bh[ctl][ks], acc[rt][ctl], 0, 0, 0);
                    acc[rt][ctl] = __builtin_amdgcn_mfma_f32_16x16x32_bf16(Ah, Bl[ctl][ks], acc[rt][ctl], 0, 0, 0);
                }
            }
        __syncthreads();
        #pragma unroll
        for (int rt = 0; rt < 5; ++rt)
            #pragma unroll
            for (int ctl = 0; ctl < CTW; ++ctl) {
                const int col = w*16*CTW + ctl*16 + m16;
                #pragma unroll
                for (int ri = 0; ri < 4; ++ri) {
                    const int row = rt*16 + q4*4 + ri;
                    cd[row*CDP + col] = acc[rt][ctl][ri];
                }
            }
        __syncthreads();
        if (t < HO) {
            #pragma unroll
            for (int pl = 0; pl < 4; ++pl) {
                float mx = -3.4e38f, mn = 3.4e38f;
                #pragma unroll
                for (int j = 0; j < K_; ++j) {
                    float v = cd[(pl*20 + j)*CDP + t] + b2c;
                    mx = fmaxf(mx, v); mn = fminf(mn, v);
                    double vd = (double)v;
                    ssum += vd; ssq += vd*vd;
                }
                zmax[(size_t)(p0+pl)*HO + t] = mx;
                zmin[(size_t)(p0+pl)*HO + t] = mn;
            }
        }
    }
    if (t < HO) {
        partOut[(size_t)blockIdx.x*(2*HO) + t] = ssum;
        partOut[(size_t)blockIdx.x*(2*HO) + HO + t] = ssq;
    }
}

// max_j relu(BN(z)) = relu(BN(max_j z)) for gamma>=0, min for gamma<0.
// R11: reference elementwise op order for the x1b-producing instance.
template<int HO>
__global__ __launch_bounds__(256) void conv_fin_kernel(
    const float* __restrict__ zmax, const float* __restrict__ zmin,
    const float* __restrict__ st2, const float* __restrict__ g2, const float* __restrict__ be2,
    float* __restrict__ out)
{
    int e = blockIdx.x*256 + threadIdx.x;
    int c = e & (HO-1);
    float g = g2[c];
    float sel = (g >= 0.f) ? zmax[e] : zmin[e];
    float bn = __fadd_rn(__fmul_rn(__fmul_rn(__fsub_rn(sel, st2[2*HO + c]), st2[3*HO + c]), g), be2[c]);
    out[e] = fmaxf(bn, 0.f);
}

// ---------------------------------------------------------------- classifier
__global__ __launch_bounds__(256) void cls1_kernel(
    const float* __restrict__ x1, const float* __restrict__ x2f,
    const float* __restrict__ W, const float* __restrict__ b1,
    float* __restrict__ z, double* __restrict__ partOut)
{
    __shared__ float ws[192*64];
    __shared__ float xr[4*192];
    __shared__ double red[256], red2[256];
    const int t = threadIdx.x, cy = blockIdx.y;
    for (int e = t; e < 192*64; e += 256) {
        int c = e >> 6, cl = e & 63;
        ws[e] = W[c*128 + cy*64 + cl];
    }
    const int pl = t >> 6, c2l = t & 63;
    const float b1v = b1[cy*64 + c2l];
    double ssum = 0., ssq = 0.;
    for (int p0 = blockIdx.x*4; p0 < BN_; p0 += gridDim.x*4) {
        __syncthreads();
        for (int l = t; l < 4*192; l += 256) {
            int pp = l / 192, cc = l % 192;
            xr[l] = (cc < 64) ? x1[(p0+pp)*64 + cc] : x2f[(p0+pp)*128 + cc - 64];
        }
        __syncthreads();
        float acc = b1v;
        const float* xx = xr + pl*192;
        #pragma unroll 8
        for (int c = 0; c < 192; ++c) acc += xx[c] * ws[c*64 + c2l];
        z[(p0+pl)*128 + cy*64 + c2l] = acc;
        double ad = (double)acc;
        ssum += ad; ssq += ad*ad;
    }
    __syncthreads();
    red[t] = ssum; red2[t] = ssq;
    __syncthreads();
    if (t < 64) {
        double s = red[t], s2 = red2[t];
        #pragma unroll
        for (int g = 1; g < 4; ++g) { s += red[g*64 + t]; s2 += red2[g*64 + t]; }
        // partial row layout [512][256]: (sum ch0..127, sumsq ch0..127); the two
        // cy-planes of the same blockIdx.x fill disjoint 64-ch ranges.
        partOut[(size_t)blockIdx.x*256 + cy*64 + t] = s;
        partOut[(size_t)blockIdx.x*256 + 128 + cy*64 + t] = s2;
    }
}

__global__ __launch_bounds__(256) void cls_fin_kernel(
    const float* __restrict__ z, const float* __restrict__ st,
    const float* __restrict__ g, const float* __restrict__ be,
    const float* __restrict__ w2, const float* __restrict__ b2,
    float* __restrict__ out)
{
    const int t = threadIdx.x, w = t >> 6, L = t & 63;
    const int p = blockIdx.x*4 + w;
    float s = 0.f;
    #pragma unroll
    for (int h = 0; h < 2; ++h) {
        int c = L + h*64;
        float v = (z[p*128 + c] - st[256 + c]) * st[384 + c] * g[c] + be[c];
        s += fmaxf(v, 0.f) * w2[c];
    }
    #pragma unroll
    for (int off = 32; off; off >>= 1) s += __shfl_xor(s, off);
    if (L == 0) out[p] = s + b2[0];
}

// ---------------------------------------------------------------- launch
extern "C" void kernel_launch(void* const* d_in, const int* in_sizes, int n_in,
                              void* d_out, int out_size, void* d_ws, size_t ws_size,
                              hipStream_t stream)
{
    const float* x      = (const float*)d_in[0];
    const float* c1_w1  = (const float*)d_in[1];
    const float* c1_b1  = (const float*)d_in[2];
    const float* c1_g1  = (const float*)d_in[3];
    const float* c1_be1 = (const float*)d_in[4];
    const float* c1_w2  = (const float*)d_in[5];
    const float* c1_b2  = (const float*)d_in[6];
    const float* c1_g2  = (const float*)d_in[7];
    const float* c1_be2 = (const float*)d_in[8];
    const float* c2_w1  = (const float*)d_in[9];
    const float* c2_b1  = (const float*)d_in[10];
    const float* c2_g1  = (const float*)d_in[11];
    const float* c2_be1 = (const float*)d_in[12];
    const float* c2_w2  = (const float*)d_in[13];
    const float* c2_b2  = (const float*)d_in[14];
    const float* c2_g2  = (const float*)d_in[15];
    const float* c2_be2 = (const float*)d_in[16];
    const float* cls_w1 = (const float*)d_in[17];
    const float* cls_b1 = (const float*)d_in[18];
    const float* cls_g1 = (const float*)d_in[19];
    const float* cls_be1= (const float*)d_in[20];
    const float* cls_w2 = (const float*)d_in[21];
    const float* cls_b2 = (const float*)d_in[22];
    (void)in_sizes; (void)n_in; (void)out_size; (void)ws_size;

    char* ws = (char*)d_ws;
    size_t off = 0;
    auto alloc = [&](size_t bytes) { char* p = ws + off; off += (bytes + 255) & ~255ull; return p; };
    float* A    = (float*)alloc((size_t)16<<20);   // P1 -> P2 -> zcls
    float* Bq   = (float*)alloc((size_t)16<<20);   // Q1 -> Q2 -> cls partials
    float* zmax = (float*)alloc((size_t)16<<20);   // also hosts Xh/Xl between conv1 and conv2
    float* zmin = (float*)alloc((size_t)16<<20);
    float* x1b  = (float*)alloc((size_t)8<<20);
    float* x2b  = (float*)alloc((size_t)16<<20);   // also hosts idx24 + stats partials (dead windows)
    int*   idx  = (int*)  alloc((size_t)BN_*K_*4); // idx1 -> idx2
    float* nrm  = (float*)alloc((size_t)BN_*4);
    float* st   = (float*)alloc((size_t)5*512*4);
    unsigned short* w2th = (unsigned short*)alloc((size_t)128*128*2);  // W2^T hi
    unsigned short* w2tl = (unsigned short*)alloc((size_t)128*128*2);  // W2^T lo
    float *st0 = st, *st1 = st+512, *st2 = st+1024, *st3 = st+1536, *st4 = st+2048;

    unsigned short* Xh = (unsigned short*)zmax;                       // 4 MB
    unsigned short* Xl = (unsigned short*)((char*)zmax + (4<<20));    // 4 MB
    int* idx24 = (int*)x2b;
    double* part  = (double*)x2b;  // fp64 stats partials (max 4 MB): free during both conv phases
    double* partC = (double*)Bq;   // cls stats partials (1 MB): Q2 dead after conv_l2_mfma

    // ---- EdgeConv 1 (exact fp32 conv: x1b feeds flip-sensitive kNN2)
    knn4_kernel<<<dim3(N_/16, B_), 1024, 0, stream>>>(x, idx);
    pq1_kernel<<<BN_/4, 256, 0, stream>>>(x, c1_w1, c1_b1, A, Bq);
    stats_l1_kernel<64><<<2048, 256, 0, stream>>>(A, Bq, idx, part);
    finalize_parts_kernel<<<64, 256, 0, stream>>>(part, 2048, 64, 1.0/655360.0, st0);
    conv_l2_kernel<64><<<dim3(2048,1), 256, 0, stream>>>(A, Bq, idx, st0, c1_g1, c1_be1, c1_w2, c1_b2, zmax, zmin, part);
    finalize_parts_kernel<<<64, 256, 0, stream>>>(part, 2048, 64, 1.0/655360.0, st1);
    conv_fin_kernel<64><<<BN_*64/256, 256, 0, stream>>>(zmax, zmin, st1, c1_g2, c1_be2, x1b);

    // ---- EdgeConv 2 (MFMA conv: x2b only feeds classifier)
    prep64_kernel<<<BN_/4, 256, 0, stream>>>(x1b, Xh, Xl, nrm);
    knn64v4_kernel<<<dim3(N_/16, B_), 1024, 0, stream>>>(Xh, Xl, nrm, idx24);
    rescore_kernel<<<BN_/4, 256, 0, stream>>>(x1b, nrm, idx24, idx);
    pq2_kernel<<<1024, 256, 0, stream>>>(x1b, c2_w1, c2_b1, A, Bq);
    stats_l1_kernel<128><<<2048, 256, 0, stream>>>(A, Bq, idx, part);
    finalize_parts_kernel<<<128, 256, 0, stream>>>(part, 2048, 128, 1.0/655360.0, st2);
    prep_w2t_kernel<<<128*128/256, 256, 0, stream>>>(c2_w2, w2th, w2tl, 128);
    conv_l2_mfma_kernel<128><<<2048, 256, 0, stream>>>(A, Bq, idx, st2, c2_g1, c2_be1, w2th, w2tl, c2_b2, zmax, zmin, part);
    finalize_parts_kernel<<<128, 256, 0, stream>>>(part, 2048, 128, 1.0/655360.0, st3);
    conv_fin_kernel<128><<<BN_*128/256, 256, 0, stream>>>(zmax, zmin, st3, c2_g2, c2_be2, x2b);

    // ---- classifier
    cls1_kernel<<<dim3(512,2), 256, 0, stream>>>(x1b, x2b, cls_w1, cls_b1, A, partC);
    finalize_parts_kernel<<<128, 256, 0, stream>>>(partC, 512, 128, 1.0/32768.0, st4);
    cls_fin_kernel<<<BN_/4, 256, 0, stream>>>(A, st4, cls_g1, cls_be1, cls_w2, cls_b2, (float*)d_out);
}

// Round 8
// 1295.189 us; speedup vs baseline: 1.1835x; 1.0919x over previous
//
#include <hip/hip_runtime.h>
#include <math.h>

#define B_ 8
#define N_ 4096
#define K_ 20
#define KS_ 24          // approx-select width; exact rescore trims to K_ (R3-validated margin)
#define BN_ (B_*N_)

typedef __attribute__((ext_vector_type(8))) short bf16x8;
typedef __attribute__((ext_vector_type(4))) float f32x4;

// ---------------------------------------------------------------- BN stats finalize (deterministic, fp64)
// R10: float atomicAdd stats were order-nondeterministic across graph replays ->
// kNN2 boundary flip -> post-timing divergence.  R11: the deterministic fp32
// order landed on the WRONG side of a ~1-ULP distance tie (absmax 0.1177).
// All stats now accumulate in DOUBLE (partials + reduce + mean/var/rstd), so our
// stats are ~exact; the x1b-feeding BN applies the reference's elementwise op
// order; rescore uses the reference's full d formula.  DO NOT reintroduce
// atomicAdd or fold these back into fp32/FMA on the conv1 path.
// part layout: [nb][2*H] doubles (sum(H), sumsq(H) per block row).
__global__ __launch_bounds__(256) void finalize_parts_kernel(
    const double* __restrict__ part, int nb, int H, double invCount, float* __restrict__ st)
{
    __shared__ double red[256], red2[256];
    const int c = blockIdx.x, t = threadIdx.x;
    double s = 0., s2 = 0.;
    for (int b = t; b < nb; b += 256) {
        s  += part[(size_t)b*2*H + c];
        s2 += part[(size_t)b*2*H + H + c];
    }
    red[t] = s; red2[t] = s2;
    __syncthreads();
    #pragma unroll
    for (int off = 128; off; off >>= 1) {
        if (t < off) { red[t] += red[t+off]; red2[t] += red2[t+off]; }
        __syncthreads();
    }
    if (t == 0) {
        double mean = red[0] * invCount;
        double var  = fmax(red2[0] * invCount - mean * mean, 0.);
        st[2*H + c] = (float)mean;
        st[3*H + c] = (float)(1.0 / sqrt(var + 1e-5));
    }
}

// ---------------------------------------------------------------- kNN, C=4
// R7-validated (value, candidate-index) lexicographic argmin — matches jax
// top_k tie-break; reference-defining (no rescore guard) -> selection EXACT.
// R15: rolled loops (L1I); d[64] eliminated via fused compute+insert; rescans
// recompute dists (bit-identical).  DO NOT replace with DPP (R9).
__global__ __launch_bounds__(1024, 8) void knn4_kernel(const float* __restrict__ x, int* __restrict__ idxout)
{
    __shared__ float4 xt[N_];   // 64 KB
    const int b = blockIdx.y;
    const int t = threadIdx.x;
    const float4* xg = (const float4*)x + b*N_;
    for (int e = t; e < N_; e += 1024) xt[e] = xg[e];
    __syncthreads();
    const int w = t >> 6, L = t & 63;
    const int n = blockIdx.x*16 + w;
    const float4 q = xt[n];
    const float MX = 3.4e38f;
    float m1 = MX, m2 = MX, m3 = MX; int i1 = 0, i2 = 0, i3 = 0;
    #pragma unroll 1
    for (int j = 0; j < 64; ++j) {
        float4 vv = xt[(j<<6) | L];
        float nn = vv.x*vv.x + vv.y*vv.y + vv.z*vv.z + vv.w*vv.w;
        float dp = q.x*vv.x + q.y*vv.y + q.z*vv.z + q.w*vv.w;
        float v = nn - 2.f*dp;   // |xn|^2 dropped: rank-equivalent
        bool c1 = v < m1, c2 = v < m2, c3 = v < m3;
        m3 = c2 ? m2 : (c3 ? v : m3);
        i3 = c2 ? i2 : (c3 ? j : i3);
        m2 = c1 ? m1 : (c2 ? v : m2);
        i2 = c1 ? i1 : (c2 ? j : i2);
        m1 = c1 ? v : m1;
        i1 = c1 ? j : i1;
    }
    unsigned long long used = 0;
    int mywin = 0;
    #pragma unroll 1
    for (int r = 0; r < K_; ++r) {
        float bv = m1; int bg = (i1<<6) | L;
        #pragma unroll
        for (int off = 32; off; off >>= 1) {
            float ov = __shfl_xor(bv, off);
            int   og = __shfl_xor(bg, off);
            bool tk = (ov < bv) || (ov == bv && og < bg);
            bv = tk ? ov : bv; bg = tk ? og : bg;
        }
        if (L == r) mywin = bg;
        if (L == (bg & 63)) {
            used |= 1ull << i1;
            m1 = m2; i1 = i2; m2 = m3; i2 = i3; m3 = MX;
            if (m1 == MX) {
                m2 = MX; m3 = MX; i1 = 0; i2 = 0; i3 = 0;
                #pragma unroll 1
                for (int j = 0; j < 64; ++j) {
                    float4 vv = xt[(j<<6) | L];
                    float nn = vv.x*vv.x + vv.y*vv.y + vv.z*vv.z + vv.w*vv.w;
                    float dp = q.x*vv.x + q.y*vv.y + q.z*vv.z + q.w*vv.w;
                    float dj = nn - 2.f*dp;
                    float v = ((used >> j) & 1ull) ? MX : dj;
                    bool c1 = v < m1, c2 = v < m2, c3 = v < m3;
                    m3 = c2 ? m2 : (c3 ? v : m3);
                    i3 = c2 ? i2 : (c3 ? j : i3);
                    m2 = c1 ? m1 : (c2 ? v : m2);
                    i2 = c1 ? i1 : (c2 ? j : i2);
                    m1 = c1 ? v : m1;
                    i1 = c1 ? j : i1;
                }
            }
        }
    }
    if (L < K_) idxout[(b*N_ + n)*K_ + L] = mywin;
}

// ---------------------------------------------------------------- fp32 -> bf16 RNE
static __device__ inline unsigned short f2bf(float f)
{
    unsigned u = __float_as_uint(f);
    unsigned r = (u + 0x7fffu + ((u >> 16) & 1u)) >> 16;   // RNE
    return (unsigned short)r;
}

// ---------------------------------------------------------------- x1 norms (bit-identical to the R2-validated reduce)
// nrm feeds the flip-sensitive exact rescore (R11): the 64-lane butterfly sum
// order must NOT change.  Kept as its own kernel when the split-bf16 prep moved
// to the tiled layout (R17).
__global__ __launch_bounds__(256) void nrm64_kernel(const float* __restrict__ x, float* __restrict__ nrm)
{
    const int t = threadIdx.x, L = t & 63;
    const int row = blockIdx.x*4 + (t >> 6);
    const float v = x[row*64 + L];
    float s = v * v;
    #pragma unroll
    for (int off = 32; off; off >>= 1) s += __shfl_xor(s, off);
    if (L == 0) nrm[row] = s;
}

// ---------------------------------------------------------------- split-bf16 prep, TILED layout (R17)
// R17: knn64v4's fragment gathers (lane->addr transposed, 16 half-used lines
// per 16B x 64-lane load) saturated the VMEM pipe (~65K cyc/block — matches the
// 222K-cyc/block mystery that VALU/LDS/serial models missed by 4-10x).
// Global layout retiled so fragment loads are PERFECTLY coalesced:
//   tile T = row>>4 (16 rows), chunk j = ch>>3 (8 shorts):
//   addr(shorts) = T*1024 + j*128 + (row&15)*8 + (ch&7)
// Fragment read lane(m,q4): chunks q4 (and q4+4 at +512) -> consecutive m-lanes
// read consecutive 16B.  Producer+consumer both updated (rule #21).
__global__ __launch_bounds__(256) void prep64t_kernel(const float* __restrict__ x,
                                                      unsigned short* __restrict__ Xh,
                                                      unsigned short* __restrict__ Xl)
{
    const int t = threadIdx.x;
    const int j = t >> 5, rl = t & 31;          // chunk 0..7, local row 0..31
    const int row = blockIdx.x*32 + rl;
    const float4* xp = (const float4*)(x + (size_t)row*64 + j*8);
    const float4 a = xp[0], c = xp[1];
    float v[8] = {a.x, a.y, a.z, a.w, c.x, c.y, c.z, c.w};
    bf16x8 hv, lv;
    #pragma unroll
    for (int s = 0; s < 8; ++s) {
        unsigned short h = f2bf(v[s]);
        float hf = __uint_as_float((unsigned)h << 16);
        hv[s] = (short)h;
        lv[s] = (short)f2bf(v[s] - hf);
    }
    const size_t base = (size_t)(row >> 4)*1024 + (size_t)j*128 + (size_t)(row & 15)*8;
    *(bf16x8*)(Xh + base) = hv;
    *(bf16x8*)(Xl + base) = lv;
}

// ---------------------------------------------------------------- kNN, C=64 via MFMA (split-bf16 Gram, approx)
// v10 (R17): A/B fragment loads now read the TILED Xh/Xl layout (see
// prep64t_kernel) — coalesced 16B/lane, monotone lane order, 8 fully-used
// lines per load (was: transposed 128B-stride gather, ~16 half-used lines).
// Selection (R16 bitonic 8-merge butterfly + ballot pops), keys w/ slot in low
// 6 mantissa bits (R12), XOR-swizzled dist (R12), rolled staging (R15), top-8
// dropout P~5e-9 (R14) all unchanged.
__global__ __launch_bounds__(1024, 4) void knn64v4_kernel(
    const unsigned short* __restrict__ Xh, const unsigned short* __restrict__ Xl,
    const float* __restrict__ nrm, int* __restrict__ idx24)
{
    __shared__ float dist[16*1024];   // exactly 64 KB
    const int b = blockIdx.y, t = threadIdx.x;
    const int w = t >> 6, L = t & 63;
    const int q0 = blockIdx.x * 16;
    const int m = L & 15, q4 = L >> 4;
    const size_t rowbase = (size_t)b * N_ * 64;
    const int swzW = q4 << 4;         // write-side column XOR (qrow>>2 == q4)
    const int swzR = (w >> 2) << 4;   // read-side column XOR (query row w)

    // A fragments: tile q0>>4, chunk q4 (and q4+4), row m
    const unsigned short* aph = Xh + rowbase + (size_t)(q0 >> 4)*1024 + q4*128 + m*8;
    const unsigned short* apl = Xl + rowbase + (size_t)(q0 >> 4)*1024 + q4*128 + m*8;
    const bf16x8 a_h0 = *(const bf16x8*)(aph);
    const bf16x8 a_h1 = *(const bf16x8*)(aph + 512);
    const bf16x8 a_l0 = *(const bf16x8*)(apl);
    const bf16x8 a_l1 = *(const bf16x8*)(apl + 512);

    const float MX = 3.4e38f;
    float sm0 = MX, sm1 = MX, sm2 = MX, sm3 = MX, sm4 = MX, sm5 = MX, sm6 = MX, sm7 = MX;

    #pragma unroll 1
    for (int ck = 0; ck < 4; ++ck) {
        const int cq = ck * 1024;
        const unsigned slotW = (unsigned)(ck*16 + w);   // global slot of this wave's candidates
        __syncthreads();
        #pragma unroll 1
        for (int tt = 0; tt < 4; ++tt) {
            const int cbase = w*64 + tt*16;
            const size_t tile = (size_t)((cq + cbase) >> 4)*1024;
            const unsigned short* bph = Xh + rowbase + tile + q4*128 + m*8;
            const unsigned short* bpl = Xl + rowbase + tile + q4*128 + m*8;
            bf16x8 b_h0 = *(const bf16x8*)(bph);
            bf16x8 b_h1 = *(const bf16x8*)(bph + 512);
            bf16x8 b_l0 = *(const bf16x8*)(bpl);
            bf16x8 b_l1 = *(const bf16x8*)(bpl + 512);
            f32x4 acc = {0.f, 0.f, 0.f, 0.f};
            acc = __builtin_amdgcn_mfma_f32_16x16x32_bf16(a_h0, b_h0, acc, 0, 0, 0);
            acc = __builtin_amdgcn_mfma_f32_16x16x32_bf16(a_h1, b_h1, acc, 0, 0, 0);
            acc = __builtin_amdgcn_mfma_f32_16x16x32_bf16(a_l0, b_h0, acc, 0, 0, 0);
            acc = __builtin_amdgcn_mfma_f32_16x16x32_bf16(a_l1, b_h1, acc, 0, 0, 0);
            acc = __builtin_amdgcn_mfma_f32_16x16x32_bf16(a_h0, b_l0, acc, 0, 0, 0);
            acc = __builtin_amdgcn_mfma_f32_16x16x32_bf16(a_h1, b_l1, acc, 0, 0, 0);
            const float nv = nrm[b*N_ + cq + cbase + m];
            const int colW = (cbase + m) ^ swzW;
            #pragma unroll
            for (int r = 0; r < 4; ++r) {
                float dv = nv - 2.f*acc[r];
                unsigned key = (__float_as_uint(dv) & ~63u) | slotW;
                dist[(q4*4 + r)*1024 + colW] = __uint_as_float(key);
            }
        }
        __syncthreads();
        // scan this ck's 16 values straight from LDS into the sorted top-8
        #pragma unroll 1
        for (int s = 0; s < 16; ++s) {
            float v = dist[w*1024 + (((s<<6) + L) ^ swzR)];
            if (v < sm7) {
                float tt2;
                tt2 = fminf(sm0, v); v = fmaxf(sm0, v); sm0 = tt2;
                tt2 = fminf(sm1, v); v = fmaxf(sm1, v); sm1 = tt2;
                tt2 = fminf(sm2, v); v = fmaxf(sm2, v); sm2 = tt2;
                tt2 = fminf(sm3, v); v = fmaxf(sm3, v); sm3 = tt2;
                tt2 = fminf(sm4, v); v = fmaxf(sm4, v); sm4 = tt2;
                tt2 = fminf(sm5, v); v = fmaxf(sm5, v); sm5 = tt2;
                tt2 = fminf(sm6, v); v = fmaxf(sm6, v); sm6 = tt2;
                sm7 = fminf(sm7, v);
            }
        }
    }

    int mywin = 0;
    #pragma unroll 1
    for (int sr = 0; sr < 3; ++sr) {
        // butterfly all-reduce: global sorted top-8 of the union of all lanes' lists
        float a0 = sm0, a1 = sm1, a2 = sm2, a3 = sm3, a4 = sm4, a5 = sm5, a6 = sm6, a7 = sm7;
        #pragma unroll
        for (int off = 32; off; off >>= 1) {
            float b0 = __shfl_xor(a0, off), b1 = __shfl_xor(a1, off);
            float b2 = __shfl_xor(a2, off), b3 = __shfl_xor(a3, off);
            float b4 = __shfl_xor(a4, off), b5 = __shfl_xor(a5, off);
            float b6 = __shfl_xor(a6, off), b7 = __shfl_xor(a7, off);
            // lowest-8 of two sorted-8 lists (bitonic min-merge)
            float c0 = fminf(a0, b7), c1 = fminf(a1, b6), c2 = fminf(a2, b5), c3 = fminf(a3, b4);
            float c4 = fminf(a4, b3), c5 = fminf(a5, b2), c6 = fminf(a6, b1), c7 = fminf(a7, b0);
            // bitonic cleanup: distances 4, 2, 1
            float u;
            u = fminf(c0, c4); c4 = fmaxf(c0, c4); c0 = u;
            u = fminf(c1, c5); c5 = fmaxf(c1, c5); c1 = u;
            u = fminf(c2, c6); c6 = fmaxf(c2, c6); c2 = u;
            u = fminf(c3, c7); c7 = fmaxf(c3, c7); c3 = u;
            u = fminf(c0, c2); c2 = fmaxf(c0, c2); c0 = u;
            u = fminf(c1, c3); c3 = fmaxf(c1, c3); c1 = u;
            u = fminf(c4, c6); c6 = fmaxf(c4, c6); c4 = u;
            u = fminf(c5, c7); c7 = fmaxf(c5, c7); c5 = u;
            u = fminf(c0, c1); c1 = fmaxf(c0, c1); c0 = u;
            u = fminf(c2, c3); c3 = fmaxf(c2, c3); c2 = u;
            u = fminf(c4, c5); c5 = fmaxf(c4, c5); c4 = u;
            u = fminf(c6, c7); c7 = fmaxf(c6, c7); c6 = u;
            a0 = c0; a1 = c1; a2 = c2; a3 = c3; a4 = c4; a5 = c5; a6 = c6; a7 = c7;
        }
        // extract the 8 winners in ascending order (set semantics; min-lane on ties)
        #define POPW(AW, WIDX)                                                              \
        {                                                                                   \
            const unsigned long long bal = __ballot(sm0 == (AW));                           \
            const int owner = (int)__ffsll(bal) - 1;                                        \
            if (L == sr*8 + (WIDX))                                                         \
                mywin = (int)(((__float_as_uint(AW) & 63u) << 6) | (unsigned)owner);        \
            if (L == owner) {                                                               \
                sm0 = sm1; sm1 = sm2; sm2 = sm3; sm3 = sm4;                                 \
                sm4 = sm5; sm5 = sm6; sm6 = sm7; sm7 = MX;                                  \
            }                                                                               \
        }
        POPW(a0, 0) POPW(a1, 1) POPW(a2, 2) POPW(a3, 3)
        POPW(a4, 4) POPW(a5, 5) POPW(a6, 6) POPW(a7, 7)
        #undef POPW
    }
    if (L < KS_) idx24[((size_t)b*N_ + q0 + w)*KS_ + L] = mywin;
}

// ---------------------------------------------------------------- exact fp32 rescore of the KS_ candidates
// R11: d matches the reference formula exactly.  R13: two winners per round
// (10 rounds).  Exact without a readlane fix: every lane holds ONE always-valid
// candidate, so the butterfly's top-2 over (dv,MX) pairs is the true top-2;
// candidate indices are unique (extraction marks used), so pops are unambiguous.
// R15: round loop rolled (code size).
__global__ __launch_bounds__(256) void rescore_kernel(const float* __restrict__ x1, const float* __restrict__ nrm,
                                                      const int* __restrict__ idx24, int* __restrict__ idxout)
{
    const int t = threadIdx.x, w = t >> 6, L = t & 63;
    const int p = blockIdx.x*4 + w;
    const int bbase = p & ~(N_-1);
    const float MX = 3.4e38f;
    float dv = MX; int di = 0x7fffffff;
    if (L < KS_) {
        const int ci = idx24[(size_t)p*KS_ + L];
        const float4* qr = (const float4*)(x1 + (size_t)p*64);
        const float4* cr = (const float4*)(x1 + (size_t)(bbase + ci)*64);
        float dot = 0.f;
        #pragma unroll
        for (int i = 0; i < 16; ++i) {
            float4 a = qr[i], bx = cr[i];
            dot += a.x*bx.x + a.y*bx.y + a.z*bx.z + a.w*bx.w;
        }
        dv = __fsub_rn(__fadd_rn(nrm[p], nrm[bbase + ci]), 2.f*dot);
        di = ci;
    }
    int myfin = 0;
    #pragma unroll 1
    for (int r = 0; r < K_/2; ++r) {
        float v1 = dv; int g1 = di;
        float v2 = MX; int g2 = 0x7fffffff;
        #pragma unroll
        for (int off = 32; off; off >>= 1) {
            float ov1 = __shfl_xor(v1, off); int og1 = __shfl_xor(g1, off);
            float ov2 = __shfl_xor(v2, off); int og2 = __shfl_xor(g2, off);
            bool c1 = (ov1 < v1) || (ov1 == v1 && og1 < g1);
            float hv = c1 ? v1 : ov1; int hg = c1 ? g1 : og1;
            v1 = c1 ? ov1 : v1;       g1 = c1 ? og1 : g1;
            bool c2 = (ov2 < v2) || (ov2 == v2 && og2 < g2);
            float l2v = c2 ? ov2 : v2; int l2g = c2 ? og2 : g2;
            bool c3 = (l2v < hv) || (l2v == hv && l2g < hg);
            v2 = c3 ? l2v : hv;  g2 = c3 ? l2g : hg;
        }
        if (L == 2*r)   myfin = g1;
        if (L == 2*r+1) myfin = g2;
        if (di == g1 || di == g2) dv = MX;
    }
    if (L < K_) idxout[(size_t)p*K_ + L] = myfin;
}

// ---------------------------------------------------------------- P/Q precompute
__global__ __launch_bounds__(256) void pq1_kernel(const float* __restrict__ x, const float* __restrict__ W,
                                                  const float* __restrict__ b1,
                                                  float* __restrict__ P, float* __restrict__ Q)
{
    __shared__ float wd[256], wb[256];
    const int t = threadIdx.x;
    wd[t] = W[t] - W[256 + t];
    wb[t] = W[256 + t];
    __syncthreads();
    const int p = blockIdx.x*4 + (t >> 6), c = t & 63;
    const float4 xv = ((const float4*)x)[p];
    float Pv = b1[c] + xv.x*wd[c] + xv.y*wd[64+c] + xv.z*wd[128+c] + xv.w*wd[192+c];
    float Qv =         xv.x*wb[c] + xv.y*wb[64+c] + xv.z*wb[128+c] + xv.w*wb[192+c];
    P[p*64 + c] = Pv;
    Q[p*64 + c] = Qv;
}

__global__ __launch_bounds__(256) void pq2_kernel(const float* __restrict__ x1, const float* __restrict__ W,
                                                  const float* __restrict__ b1,
                                                  float* __restrict__ P, float* __restrict__ Q)
{
    __shared__ float wd[64*128], wb[64*128];
    const int t = threadIdx.x;
    for (int e = t; e < 8192; e += 256) {
        float wt = W[e], wbo = W[8192 + e];
        wd[e] = wt - wbo; wb[e] = wbo;
    }
    __syncthreads();
    const int pl = t >> 7, c = t & 127;
    const float b1v = b1[c];
    for (int p0 = blockIdx.x*2; p0 < BN_; p0 += gridDim.x*2) {
        const int p = p0 + pl;
        float Pv = b1v, Qv = 0.f;
        const float* xrow = x1 + p*64;
        #pragma unroll 8
        for (int k = 0; k < 64; ++k) {
            float xv = xrow[k];
            Pv += xv * wd[k*128 + c];
            Qv += xv * wb[k*128 + c];
        }
        P[p*128 + c] = Pv;
        Q[p*128 + c] = Qv;
    }
}

// ---------------------------------------------------------------- layer-1 BN stats (fp64 per-block partials)
template<int HO>
__global__ __launch_bounds__(256) void stats_l1_kernel(const float* __restrict__ P, const float* __restrict__ Q,
                                                       const int* __restrict__ idx, double* __restrict__ partOut)
{
    constexpr int G = 256/HO;
    __shared__ double red[256], red2[256];
    const int t = threadIdx.x, c = t % HO, g = t / HO;
    double s = 0., s2 = 0.;
    for (int p = blockIdx.x; p < BN_; p += gridDim.x) {
        const float Pv = P[p*HO + c];
        const int bbase = p & ~(N_-1);
        for (int j = g; j < K_; j += G) {
            int m = idx[p*K_ + j];
            float z = Pv + Q[(bbase + m)*HO + c];
            double zd = (double)z;
            s += zd; s2 += zd*zd;
        }
    }
    red[t] = s; red2[t] = s2;
    __syncthreads();
    if (t < HO) {
        double a = red[t], a2 = red2[t];
        #pragma unroll
        for (int q = 1; q < G; ++q) { a += red[q*HO + t]; a2 += red2[q*HO + t]; }
        partOut[(size_t)blockIdx.x*(2*HO) + t] = a;
        partOut[(size_t)blockIdx.x*(2*HO) + HO + t] = a2;
    }
}

// ---------------------------------------------------------------- EdgeConv layer-2, exact fp32 (conv1:
// its output feeds kNN2, which is flip-sensitive to ~1e-4 feature perturbation).
// R11: BN applied in the reference's elementwise op order (((z-m)*rstd)*g+be,
// separately rounded) — the folded z*ac+bc form differed by 1-2 ULP on x1 features.
template<int HO>
__global__ __launch_bounds__(256) void conv_l2_kernel(
    const float* __restrict__ P, const float* __restrict__ Q, const int* __restrict__ idx,
    const float* __restrict__ st1, const float* __restrict__ g1, const float* __restrict__ be1,
    const float* __restrict__ w2, const float* __restrict__ b2,
    float* __restrict__ zmax, float* __restrict__ zmin, double* __restrict__ partOut)
{
    __shared__ float w2s[HO*64];
    __shared__ float h1s[K_*HO];
    __shared__ float redA[256], redB[256];
    __shared__ double redD[256], redD2[256];
    const int t = threadIdx.x;
    const int cy = blockIdx.y;
    for (int e = t; e < HO*64; e += 256) {
        int c = e >> 6, cl = e & 63;
        w2s[e] = w2[c*HO + cy*64 + cl];
    }
    const int cA = t % HO;
    const float mA = st1[2*HO + cA], rA = st1[3*HO + cA];
    const float gA = g1[cA], beA = be1[cA];
    const int c2l = t & 63, jh = t >> 6;
    const float b2v = b2[cy*64 + c2l];
    double ssum = 0., ssq = 0.;
    for (int p = blockIdx.x; p < BN_; p += gridDim.x) {
        __syncthreads();
        const int bbase = p & ~(N_-1);
        const float Pv = P[p*HO + cA];
        for (int e = t; e < K_*HO; e += 256) {
            int j = e / HO;
            int m = idx[p*K_ + j];
            float z = Pv + Q[(bbase + m)*HO + cA];
            float bn = __fadd_rn(__fmul_rn(__fmul_rn(__fsub_rn(z, mA), rA), gA), beA);
            h1s[e] = fmaxf(bn, 0.f);
        }
        __syncthreads();
        float acc[5];
        #pragma unroll
        for (int q = 0; q < 5; ++q) acc[q] = b2v;
        for (int c = 0; c < HO; ++c) {
            float wv = w2s[c*64 + c2l];
            #pragma unroll
            for (int q = 0; q < 5; ++q)
                acc[q] += h1s[(jh + q*4)*HO + c] * wv;
        }
        float mx = acc[0], mn = acc[0];
        #pragma unroll
        for (int q = 0; q < 5; ++q) {
            mx = fmaxf(mx, acc[q]); mn = fminf(mn, acc[q]);
            double ad = (double)acc[q];
            ssum += ad; ssq += ad*ad;
        }
        redA[t] = mx; redB[t] = mn;
        __syncthreads();
        if (t < 64) {
            float M = redA[t], Mn = redB[t];
            #pragma unroll
            for (int g = 1; g < 4; ++g) { M = fmaxf(M, redA[g*64 + t]); Mn = fminf(Mn, redB[g*64 + t]); }
            zmax[p*HO + cy*64 + t] = M;
            zmin[p*HO + cy*64 + t] = Mn;
        }
    }
    __syncthreads();
    redD[t] = ssum; redD2[t] = ssq;
    __syncthreads();
    if (t < 64) {
        double s = redD[t], s2 = redD2[t];
        #pragma unroll
        for (int g = 1; g < 4; ++g) { s += redD[g*64 + t]; s2 += redD2[g*64 + t]; }
        partOut[(size_t)blockIdx.x*(2*HO) + cy*64 + t] = s;
        partOut[(size_t)blockIdx.x*(2*HO) + HO + cy*64 + t] = s2;
    }
}

// ---------------------------------------------------------------- W2^T split-bf16 prep
__global__ __launch_bounds__(256) void prep_w2t_kernel(const float* __restrict__ W,
                                                       unsigned short* __restrict__ wh,
                                                       unsigned short* __restrict__ wl, int HO)
{
    const int e = blockIdx.x*256 + threadIdx.x;   // e = k*HO + c
    const int k = e / HO, c = e % HO;
    const float v = W[e];
    unsigned short h = f2bf(v);
    float hf = __uint_as_float((unsigned)h << 16);
    wh[c*HO + k] = h;
    wl[c*HO + k] = f2bf(v - hf);
}

// ---------------------------------------------------------------- EdgeConv layer-2 via MFMA (split-bf16)
// conv2 only: output feeds the classifier (value-continuous), bf16-split safe.
template<int HO>
__global__ __launch_bounds__(256) void conv_l2_mfma_kernel(
    const float* __restrict__ P, const float* __restrict__ Q, const int* __restrict__ idx,
    const float* __restrict__ st1, const float* __restrict__ g1, const float* __restrict__ be1,
    const unsigned short* __restrict__ w2h, const unsigned short* __restrict__ w2l,
    const float* __restrict__ b2,
    float* __restrict__ zmax, float* __restrict__ zmin, double* __restrict__ partOut)
{
    constexpr int HOP = HO + 8;
    constexpr int CDP = HO + 1;
    constexpr int CTW = HO / 64;
    constexpr int KSn = HO / 32;
    constexpr int HSH = (HO == 128) ? 7 : 6;
    __shared__ __align__(16) short hs[2*80*HOP];
    __shared__ int sidx[80];
    float* cd = (float*)hs;

    const int t = threadIdx.x, w = t >> 6, L = t & 63;
    const int m16 = L & 15, q4 = L >> 4;

    const int kT = t & (HO - 1);
    const float ac = st1[3*HO + kT] * g1[kT];
    const float bc = be1[kT] - st1[2*HO + kT] * ac;

    bf16x8 Bh[CTW][KSn], Bl[CTW][KSn];
    #pragma unroll
    for (int ctl = 0; ctl < CTW; ++ctl)
        #pragma unroll
        for (int ks = 0; ks < KSn; ++ks) {
            const int c  = w*16*CTW + ctl*16 + m16;
            const int k0 = ks*32 + q4*8;
            Bh[ctl][ks] = *(const bf16x8*)(w2h + c*HO + k0);
            Bl[ctl][ks] = *(const bf16x8*)(w2l + c*HO + k0);
        }

    const float b2c = (t < HO) ? b2[t] : 0.f;
    double ssum = 0., ssq = 0.;

    for (int p0 = blockIdx.x*4; p0 < BN_; p0 += gridDim.x*4) {
        const int bbase = p0 & ~(N_-1);
        __syncthreads();
        if (t < 80) sidx[t] = idx[p0*K_ + t];
        __syncthreads();
        for (int e = t; e < 80*HO; e += 256) {
            const int r  = e >> HSH;
            const int pl = (r*3277) >> 16;     // r/20 for r<80
            const int mI = sidx[r];
            float z = P[(size_t)(p0+pl)*HO + kT] + Q[(size_t)(bbase+mI)*HO + kT];
            float h = fmaxf(z*ac + bc, 0.f);
            unsigned short hh = f2bf(h);
            float hf = __uint_as_float((unsigned)hh << 16);
            unsigned short hl = f2bf(h - hf);
            hs[r*HOP + kT] = (short)hh;
            hs[80*HOP + r*HOP + kT] = (short)hl;
        }
        __syncthreads();
        f32x4 acc[5][CTW];
        #pragma unroll
        for (int rt = 0; rt < 5; ++rt)
            #pragma unroll
            for (int ctl = 0; ctl < CTW; ++ctl)
                acc[rt][ctl] = (f32x4){0.f, 0.f, 0.f, 0.f};
        #pragma unroll
        for (int rt = 0; rt < 5; ++rt)
            #pragma unroll
            for (int ks = 0; ks < KSn; ++ks) {
                const short* ap = hs + (rt*16 + m16)*HOP + ks*32 + q4*8;
                bf16x8 Ah = *(const bf16x8*)ap;
                bf16x8 Al = *(const bf16x8*)(ap + 80*HOP);
                #pragma unroll
                for (int ctl = 0; ctl < CTW; ++ctl) {
                    acc[rt][ctl] = __builtin_amdgcn_mfma_f32_16x16x32_bf16(Ah, Bh[ctl][ks], acc[rt][ctl], 0, 0, 0);
                    acc[rt][ctl] = __builtin_amdgcn_mfma_f32_16x16x32_bf16(Al, Bh[ctl][ks], acc[rt][ctl], 0, 0, 0);
                    acc[rt][ctl] = __builtin_amdgcn_mfma_f32_16x16x32_bf16(Ah, Bl[ctl][ks], acc[rt][ctl], 0, 0, 0);
                }
            }
        __syncthreads();
        #pragma unroll
        for (int rt = 0; rt < 5; ++rt)
            #pragma unroll
            for (int ctl = 0; ctl < CTW; ++ctl) {
                const int col = w*16*CTW + ctl*16 + m16;
                #pragma unroll
                for (int ri = 0; ri < 4; ++ri) {
                    const int row = rt*16 + q4*4 + ri;
                    cd[row*CDP + col] = acc[rt][ctl][ri];
                }
            }
        __syncthreads();
        if (t < HO) {
            #pragma unroll
            for (int pl = 0; pl < 4; ++pl) {
                float mx = -3.4e38f, mn = 3.4e38f;
                #pragma unroll
                for (int j = 0; j < K_; ++j) {
                    float v = cd[(pl*20 + j)*CDP + t] + b2c;
                    mx = fmaxf(mx, v); mn = fminf(mn, v);
                    double vd = (double)v;
                    ssum += vd; ssq += vd*vd;
                }
                zmax[(size_t)(p0+pl)*HO + t] = mx;
                zmin[(size_t)(p0+pl)*HO + t] = mn;
            }
        }
    }
    if (t < HO) {
        partOut[(size_t)blockIdx.x*(2*HO) + t] = ssum;
        partOut[(size_t)blockIdx.x*(2*HO) + HO + t] = ssq;
    }
}

// max_j relu(BN(z)) = relu(BN(max_j z)) for gamma>=0, min for gamma<0.
// R11: reference elementwise op order for the x1b-producing instance.
template<int HO>
__global__ __launch_bounds__(256) void conv_fin_kernel(
    const float* __restrict__ zmax, const float* __restrict__ zmin,
    const float* __restrict__ st2, const float* __restrict__ g2, const float* __restrict__ be2,
    float* __restrict__ out)
{
    int e = blockIdx.x*256 + threadIdx.x;
    int c = e & (HO-1);
    float g = g2[c];
    float sel = (g >= 0.f) ? zmax[e] : zmin[e];
    float bn = __fadd_rn(__fmul_rn(__fmul_rn(__fsub_rn(sel, st2[2*HO + c]), st2[3*HO + c]), g), be2[c]);
    out[e] = fmaxf(bn, 0.f);
}

// ---------------------------------------------------------------- classifier
__global__ __launch_bounds__(256) void cls1_kernel(
    const float* __restrict__ x1, const float* __restrict__ x2f,
    const float* __restrict__ W, const float* __restrict__ b1,
    float* __restrict__ z, double* __restrict__ partOut)
{
    __shared__ float ws[192*64];
    __shared__ float xr[4*192];
    __shared__ double red[256], red2[256];
    const int t = threadIdx.x, cy = blockIdx.y;
    for (int e = t; e < 192*64; e += 256) {
        int c = e >> 6, cl = e & 63;
        ws[e] = W[c*128 + cy*64 + cl];
    }
    const int pl = t >> 6, c2l = t & 63;
    const float b1v = b1[cy*64 + c2l];
    double ssum = 0., ssq = 0.;
    for (int p0 = blockIdx.x*4; p0 < BN_; p0 += gridDim.x*4) {
        __syncthreads();
        for (int l = t; l < 4*192; l += 256) {
            int pp = l / 192, cc = l % 192;
            xr[l] = (cc < 64) ? x1[(p0+pp)*64 + cc] : x2f[(p0+pp)*128 + cc - 64];
        }
        __syncthreads();
        float acc = b1v;
        const float* xx = xr + pl*192;
        #pragma unroll 8
        for (int c = 0; c < 192; ++c) acc += xx[c] * ws[c*64 + c2l];
        z[(p0+pl)*128 + cy*64 + c2l] = acc;
        double ad = (double)acc;
        ssum += ad; ssq += ad*ad;
    }
    __syncthreads();
    red[t] = ssum; red2[t] = ssq;
    __syncthreads();
    if (t < 64) {
        double s = red[t], s2 = red2[t];
        #pragma unroll
        for (int g = 1; g < 4; ++g) { s += red[g*64 + t]; s2 += red2[g*64 + t]; }
        // partial row layout [512][256]: (sum ch0..127, sumsq ch0..127); the two
        // cy-planes of the same blockIdx.x fill disjoint 64-ch ranges.
        partOut[(size_t)blockIdx.x*256 + cy*64 + t] = s;
        partOut[(size_t)blockIdx.x*256 + 128 + cy*64 + t] = s2;
    }
}

__global__ __launch_bounds__(256) void cls_fin_kernel(
    const float* __restrict__ z, const float* __restrict__ st,
    const float* __restrict__ g, const float* __restrict__ be,
    const float* __restrict__ w2, const float* __restrict__ b2,
    float* __restrict__ out)
{
    const int t = threadIdx.x, w = t >> 6, L = t & 63;
    const int p = blockIdx.x*4 + w;
    float s = 0.f;
    #pragma unroll
    for (int h = 0; h < 2; ++h) {
        int c = L + h*64;
        float v = (z[p*128 + c] - st[256 + c]) * st[384 + c] * g[c] + be[c];
        s += fmaxf(v, 0.f) * w2[c];
    }
    #pragma unroll
    for (int off = 32; off; off >>= 1) s += __shfl_xor(s, off);
    if (L == 0) out[p] = s + b2[0];
}

// ---------------------------------------------------------------- launch
extern "C" void kernel_launch(void* const* d_in, const int* in_sizes, int n_in,
                              void* d_out, int out_size, void* d_ws, size_t ws_size,
                              hipStream_t stream)
{
    const float* x      = (const float*)d_in[0];
    const float* c1_w1  = (const float*)d_in[1];
    const float* c1_b1  = (const float*)d_in[2];
    const float* c1_g1  = (const float*)d_in[3];
    const float* c1_be1 = (const float*)d_in[4];
    const float* c1_w2  = (const float*)d_in[5];
    const float* c1_b2  = (const float*)d_in[6];
    const float* c1_g2  = (const float*)d_in[7];
    const float* c1_be2 = (const float*)d_in[8];
    const float* c2_w1  = (const float*)d_in[9];
    const float* c2_b1  = (const float*)d_in[10];
    const float* c2_g1  = (const float*)d_in[11];
    const float* c2_be1 = (const float*)d_in[12];
    const float* c2_w2  = (const float*)d_in[13];
    const float* c2_b2  = (const float*)d_in[14];
    const float* c2_g2  = (const float*)d_in[15];
    const float* c2_be2 = (const float*)d_in[16];
    const float* cls_w1 = (const float*)d_in[17];
    const float* cls_b1 = (const float*)d_in[18];
    const float* cls_g1 = (const float*)d_in[19];
    const float* cls_be1= (const float*)d_in[20];
    const float* cls_w2 = (const float*)d_in[21];
    const float* cls_b2 = (const float*)d_in[22];
    (void)in_sizes; (void)n_in; (void)out_size; (void)ws_size;

    char* ws = (char*)d_ws;
    size_t off = 0;
    auto alloc = [&](size_t bytes) { char* p = ws + off; off += (bytes + 255) & ~255ull; return p; };
    float* A    = (float*)alloc((size_t)16<<20);   // P1 -> P2 -> zcls
    float* Bq   = (float*)alloc((size_t)16<<20);   // Q1 -> Q2 -> cls partials
    float* zmax = (float*)alloc((size_t)16<<20);   // also hosts Xh/Xl between conv1 and conv2
    float* zmin = (float*)alloc((size_t)16<<20);
    float* x1b  = (float*)alloc((size_t)8<<20);
    float* x2b  = (float*)alloc((size_t)16<<20);   // also hosts idx24 + stats partials (dead windows)
    int*   idx  = (int*)  alloc((size_t)BN_*K_*4); // idx1 -> idx2
    float* nrm  = (float*)alloc((size_t)BN_*4);
    float* st   = (float*)alloc((size_t)5*512*4);
    unsigned short* w2th = (unsigned short*)alloc((size_t)128*128*2);  // W2^T hi
    unsigned short* w2tl = (unsigned short*)alloc((size_t)128*128*2);  // W2^T lo
    float *st0 = st, *st1 = st+512, *st2 = st+1024, *st3 = st+1536, *st4 = st+2048;

    unsigned short* Xh = (unsigned short*)zmax;                       // 4 MB (tiled layout, R17)
    unsigned short* Xl = (unsigned short*)((char*)zmax + (4<<20));    // 4 MB
    int* idx24 = (int*)x2b;
    double* part  = (double*)x2b;  // fp64 stats partials (max 4 MB): free during both conv phases
    double* partC = (double*)Bq;   // cls stats partials (1 MB): Q2 dead after conv_l2_mfma

    // ---- EdgeConv 1 (exact fp32 conv: x1b feeds flip-sensitive kNN2)
    knn4_kernel<<<dim3(N_/16, B_), 1024, 0, stream>>>(x, idx);
    pq1_kernel<<<BN_/4, 256, 0, stream>>>(x, c1_w1, c1_b1, A, Bq);
    stats_l1_kernel<64><<<2048, 256, 0, stream>>>(A, Bq, idx, part);
    finalize_parts_kernel<<<64, 256, 0, stream>>>(part, 2048, 64, 1.0/655360.0, st0);
    conv_l2_kernel<64><<<dim3(2048,1), 256, 0, stream>>>(A, Bq, idx, st0, c1_g1, c1_be1, c1_w2, c1_b2, zmax, zmin, part);
    finalize_parts_kernel<<<64, 256, 0, stream>>>(part, 2048, 64, 1.0/655360.0, st1);
    conv_fin_kernel<64><<<BN_*64/256, 256, 0, stream>>>(zmax, zmin, st1, c1_g2, c1_be2, x1b);

    // ---- EdgeConv 2 (MFMA conv: x2b only feeds classifier)
    nrm64_kernel<<<BN_/4, 256, 0, stream>>>(x1b, nrm);
    prep64t_kernel<<<BN_/32, 256, 0, stream>>>(x1b, Xh, Xl);
    knn64v4_kernel<<<dim3(N_/16, B_), 1024, 0, stream>>>(Xh, Xl, nrm, idx24);
    rescore_kernel<<<BN_/4, 256, 0, stream>>>(x1b, nrm, idx24, idx);
    pq2_kernel<<<1024, 256, 0, stream>>>(x1b, c2_w1, c2_b1, A, Bq);
    stats_l1_kernel<128><<<2048, 256, 0, stream>>>(A, Bq, idx, part);
    finalize_parts_kernel<<<128, 256, 0, stream>>>(part, 2048, 128, 1.0/655360.0, st2);
    prep_w2t_kernel<<<128*128/256, 256, 0, stream>>>(c2_w2, w2th, w2tl, 128);
    conv_l2_mfma_kernel<128><<<2048, 256, 0, stream>>>(A, Bq, idx, st2, c2_g1, c2_be1, w2th, w2tl, c2_b2, zmax, zmin, part);
    finalize_parts_kernel<<<128, 256, 0, stream>>>(part, 2048, 128, 1.0/655360.0, st3);
    conv_fin_kernel<128><<<BN_*128/256, 256, 0, stream>>>(zmax, zmin, st3, c2_g2, c2_be2, x2b);

    // ---- classifier
    cls1_kernel<<<dim3(512,2), 256, 0, stream>>>(x1b, x2b, cls_w1, cls_b1, A, partC);
    finalize_parts_kernel<<<128, 256, 0, stream>>>(partC, 512, 128, 1.0/32768.0, st4);
    cls_fin_kernel<<<BN_/4, 256, 0, stream>>>(A, st4, cls_g1, cls_be1, cls_w2, cls_b2, (float*)d_out);
}

// Round 9
// 1247.772 us; speedup vs baseline: 1.2284x; 1.0380x over previous
//
#include <hip/hip_runtime.h>
#include <math.h>

#define B_ 8
#define N_ 4096
#define K_ 20
#define KS_ 24          // approx-select width; exact rescore trims to K_ (R3-validated margin)
#define BN_ (B_*N_)

typedef __attribute__((ext_vector_type(8))) short bf16x8;
typedef __attribute__((ext_vector_type(4))) float f32x4;

// ---------------------------------------------------------------- BN stats finalize (deterministic, fp64)
// R10: float atomicAdd stats were order-nondeterministic across graph replays ->
// kNN2 boundary flip -> post-timing divergence.  R11: the deterministic fp32
// order landed on the WRONG side of a ~1-ULP distance tie (absmax 0.1177).
// All stats now accumulate in DOUBLE (partials + reduce + mean/var/rstd), so our
// stats are ~exact; the x1b-feeding BN applies the reference's elementwise op
// order; rescore uses the reference's full d formula.  DO NOT reintroduce
// atomicAdd or fold these back into fp32/FMA on the conv1 path.
// part layout: [nb][2*H] doubles (sum(H), sumsq(H) per block row).
__global__ __launch_bounds__(256) void finalize_parts_kernel(
    const double* __restrict__ part, int nb, int H, double invCount, float* __restrict__ st)
{
    __shared__ double red[256], red2[256];
    const int c = blockIdx.x, t = threadIdx.x;
    double s = 0., s2 = 0.;
    for (int b = t; b < nb; b += 256) {
        s  += part[(size_t)b*2*H + c];
        s2 += part[(size_t)b*2*H + H + c];
    }
    red[t] = s; red2[t] = s2;
    __syncthreads();
    #pragma unroll
    for (int off = 128; off; off >>= 1) {
        if (t < off) { red[t] += red[t+off]; red2[t] += red2[t+off]; }
        __syncthreads();
    }
    if (t == 0) {
        double mean = red[0] * invCount;
        double var  = fmax(red2[0] * invCount - mean * mean, 0.);
        st[2*H + c] = (float)mean;
        st[3*H + c] = (float)(1.0 / sqrt(var + 1e-5));
    }
}

// ---------------------------------------------------------------- kNN, C=4
// R7-validated (value, candidate-index) lexicographic argmin — matches jax
// top_k tie-break; reference-defining (no rescore guard) -> selection EXACT.
// R15: rolled loops (L1I); d[64] eliminated via fused compute+insert; rescans
// recompute dists (bit-identical).  DO NOT replace with DPP (R9).
__global__ __launch_bounds__(1024, 8) void knn4_kernel(const float* __restrict__ x, int* __restrict__ idxout)
{
    __shared__ float4 xt[N_];   // 64 KB
    const int b = blockIdx.y;
    const int t = threadIdx.x;
    const float4* xg = (const float4*)x + b*N_;
    for (int e = t; e < N_; e += 1024) xt[e] = xg[e];
    __syncthreads();
    const int w = t >> 6, L = t & 63;
    const int n = blockIdx.x*16 + w;
    const float4 q = xt[n];
    const float MX = 3.4e38f;
    float m1 = MX, m2 = MX, m3 = MX; int i1 = 0, i2 = 0, i3 = 0;
    #pragma unroll 1
    for (int j = 0; j < 64; ++j) {
        float4 vv = xt[(j<<6) | L];
        float nn = vv.x*vv.x + vv.y*vv.y + vv.z*vv.z + vv.w*vv.w;
        float dp = q.x*vv.x + q.y*vv.y + q.z*vv.z + q.w*vv.w;
        float v = nn - 2.f*dp;   // |xn|^2 dropped: rank-equivalent
        bool c1 = v < m1, c2 = v < m2, c3 = v < m3;
        m3 = c2 ? m2 : (c3 ? v : m3);
        i3 = c2 ? i2 : (c3 ? j : i3);
        m2 = c1 ? m1 : (c2 ? v : m2);
        i2 = c1 ? i1 : (c2 ? j : i2);
        m1 = c1 ? v : m1;
        i1 = c1 ? j : i1;
    }
    unsigned long long used = 0;
    int mywin = 0;
    #pragma unroll 1
    for (int r = 0; r < K_; ++r) {
        float bv = m1; int bg = (i1<<6) | L;
        #pragma unroll
        for (int off = 32; off; off >>= 1) {
            float ov = __shfl_xor(bv, off);
            int   og = __shfl_xor(bg, off);
            bool tk = (ov < bv) || (ov == bv && og < bg);
            bv = tk ? ov : bv; bg = tk ? og : bg;
        }
        if (L == r) mywin = bg;
        if (L == (bg & 63)) {
            used |= 1ull << i1;
            m1 = m2; i1 = i2; m2 = m3; i2 = i3; m3 = MX;
            if (m1 == MX) {
                m2 = MX; m3 = MX; i1 = 0; i2 = 0; i3 = 0;
                #pragma unroll 1
                for (int j = 0; j < 64; ++j) {
                    float4 vv = xt[(j<<6) | L];
                    float nn = vv.x*vv.x + vv.y*vv.y + vv.z*vv.z + vv.w*vv.w;
                    float dp = q.x*vv.x + q.y*vv.y + q.z*vv.z + q.w*vv.w;
                    float dj = nn - 2.f*dp;
                    float v = ((used >> j) & 1ull) ? MX : dj;
                    bool c1 = v < m1, c2 = v < m2, c3 = v < m3;
                    m3 = c2 ? m2 : (c3 ? v : m3);
                    i3 = c2 ? i2 : (c3 ? j : i3);
                    m2 = c1 ? m1 : (c2 ? v : m2);
                    i2 = c1 ? i1 : (c2 ? j : i2);
                    m1 = c1 ? v : m1;
                    i1 = c1 ? j : i1;
                }
            }
        }
    }
    if (L < K_) idxout[(b*N_ + n)*K_ + L] = mywin;
}

// ---------------------------------------------------------------- fp32 -> bf16 RNE
static __device__ inline unsigned short f2bf(float f)
{
    unsigned u = __float_as_uint(f);
    unsigned r = (u + 0x7fffu + ((u >> 16) & 1u)) >> 16;   // RNE
    return (unsigned short)r;
}

// ---------------------------------------------------------------- x1 norms (bit-identical to the R2-validated reduce)
// nrm feeds the flip-sensitive exact rescore (R11): the 64-lane butterfly sum
// order must NOT change.
__global__ __launch_bounds__(256) void nrm64_kernel(const float* __restrict__ x, float* __restrict__ nrm)
{
    const int t = threadIdx.x, L = t & 63;
    const int row = blockIdx.x*4 + (t >> 6);
    const float v = x[row*64 + L];
    float s = v * v;
    #pragma unroll
    for (int off = 32; off; off >>= 1) s += __shfl_xor(s, off);
    if (L == 0) nrm[row] = s;
}

// ---------------------------------------------------------------- split-bf16 prep, TILED layout (R17)
// R17: fragment gathers saturated VMEM (transposed 128B-stride, half-used
// lines).  Tiled layout: addr(shorts) = (row>>4)*1024 + (ch>>3)*128 +
// (row&15)*8 + (ch&7) -> fragment loads perfectly coalesced.
__global__ __launch_bounds__(256) void prep64t_kernel(const float* __restrict__ x,
                                                      unsigned short* __restrict__ Xh,
                                                      unsigned short* __restrict__ Xl)
{
    const int t = threadIdx.x;
    const int j = t >> 5, rl = t & 31;          // chunk 0..7, local row 0..31
    const int row = blockIdx.x*32 + rl;
    const float4* xp = (const float4*)(x + (size_t)row*64 + j*8);
    const float4 a = xp[0], c = xp[1];
    float v[8] = {a.x, a.y, a.z, a.w, c.x, c.y, c.z, c.w};
    bf16x8 hv, lv;
    #pragma unroll
    for (int s = 0; s < 8; ++s) {
        unsigned short h = f2bf(v[s]);
        float hf = __uint_as_float((unsigned)h << 16);
        hv[s] = (short)h;
        lv[s] = (short)f2bf(v[s] - hf);
    }
    const size_t base = (size_t)(row >> 4)*1024 + (size_t)j*128 + (size_t)(row & 15)*8;
    *(bf16x8*)(Xh + base) = hv;
    *(bf16x8*)(Xl + base) = lv;
}

// comparator: (x,y) -> (min,max)
#define CE_(x,y) { float _t = fminf(x,y); y = fmaxf(x,y); x = _t; }
// Batcher odd-even sort-8 (19 CE)
#define SORT8_(g0,g1,g2,g3,g4,g5,g6,g7)                                   \
    CE_(g0,g1) CE_(g2,g3) CE_(g4,g5) CE_(g6,g7)                           \
    CE_(g0,g2) CE_(g1,g3) CE_(g4,g6) CE_(g5,g7)                           \
    CE_(g1,g2) CE_(g5,g6)                                                 \
    CE_(g0,g4) CE_(g1,g5) CE_(g2,g6) CE_(g3,g7)                           \
    CE_(g2,g4) CE_(g3,g5)                                                 \
    CE_(g1,g2) CE_(g3,g4) CE_(g5,g6)
// keep lowest-8 (sorted) of two sorted-asc 8-lists: sm = low8(sm, g)
#define MERGE8_(g0,g1,g2,g3,g4,g5,g6,g7)                                  \
    sm0 = fminf(sm0,g7); sm1 = fminf(sm1,g6); sm2 = fminf(sm2,g5);        \
    sm3 = fminf(sm3,g4); sm4 = fminf(sm4,g3); sm5 = fminf(sm5,g2);        \
    sm6 = fminf(sm6,g1); sm7 = fminf(sm7,g0);                             \
    CE_(sm0,sm4) CE_(sm1,sm5) CE_(sm2,sm6) CE_(sm3,sm7)                   \
    CE_(sm0,sm2) CE_(sm1,sm3) CE_(sm4,sm6) CE_(sm5,sm7)                   \
    CE_(sm0,sm1) CE_(sm2,sm3) CE_(sm4,sm5) CE_(sm6,sm7)

// ---------------------------------------------------------------- kNN, C=64 via MFMA (split-bf16 Gram, approx)
// v11 (R18): VALU-bound (R17 counters: VALUBusy 84%, all else idle) -> delete
// VALU.  (1) Scan: insert-chain (16 ops/val, always-taken under divergence)
// replaced by group-of-8 Batcher sort + bitonic keep-low-8 merge (~9 ops/val,
// identical resulting top-8 SET, deterministic; merge network == the R16
// butterfly's, already validated).  Read addr identity ((s<<6)+L)^swzR ==
// s*64 + (L^swzR) (swzR only bits 4-5) -> reads are base + immediate offsets,
// zero per-s addressing.  (2) Staging: tile pointers strength-reduced
// (+1024 shorts/tt), nrm idx +16, colW from running cm.  Selection (R16),
// keys (R12), tiled global layout (R17), top-8 dropout P~5e-9 (R14) unchanged.
__global__ __launch_bounds__(1024, 4) void knn64v4_kernel(
    const unsigned short* __restrict__ Xh, const unsigned short* __restrict__ Xl,
    const float* __restrict__ nrm, int* __restrict__ idx24)
{
    __shared__ float dist[16*1024];   // exactly 64 KB
    const int b = blockIdx.y, t = threadIdx.x;
    const int w = t >> 6, L = t & 63;
    const int q0 = blockIdx.x * 16;
    const int m = L & 15, q4 = L >> 4;
    const size_t rowbase = (size_t)b * N_ * 64;
    const int swzW = q4 << 4;         // write-side column XOR (qrow>>2 == q4)
    const int swzR = (w >> 2) << 4;   // read-side column XOR (query row w)
    const int fragoff = q4*128 + m*8; // within-tile fragment offset (shorts)

    // A fragments: tile q0>>4
    const unsigned short* aph = Xh + rowbase + (size_t)(q0 >> 4)*1024 + fragoff;
    const unsigned short* apl = Xl + rowbase + (size_t)(q0 >> 4)*1024 + fragoff;
    const bf16x8 a_h0 = *(const bf16x8*)(aph);
    const bf16x8 a_h1 = *(const bf16x8*)(aph + 512);
    const bf16x8 a_l0 = *(const bf16x8*)(apl);
    const bf16x8 a_l1 = *(const bf16x8*)(apl + 512);

    const float MX = 3.4e38f;
    float sm0 = MX, sm1 = MX, sm2 = MX, sm3 = MX, sm4 = MX, sm5 = MX, sm6 = MX, sm7 = MX;

    float* const wrow = dist + q4*4096;        // q4*4*1024
    float* const rrow = dist + w*1024 + (L ^ swzR);

    #pragma unroll 1
    for (int ck = 0; ck < 4; ++ck) {
        const unsigned slotW0 = (unsigned)(ck*16);
        // strength-reduced staging pointers for this ck
        const unsigned short* bp_h = Xh + rowbase + (size_t)(ck*64 + w*4)*1024 + fragoff;
        const unsigned short* bp_l = Xl + rowbase + (size_t)(ck*64 + w*4)*1024 + fragoff;
        const float* np = nrm + b*N_ + ck*1024 + w*64 + m;
        int cm = w*64 + m;
        __syncthreads();
        #pragma unroll 2
        for (int tt = 0; tt < 4; ++tt) {
            bf16x8 b_h0 = *(const bf16x8*)(bp_h);
            bf16x8 b_h1 = *(const bf16x8*)(bp_h + 512);
            bf16x8 b_l0 = *(const bf16x8*)(bp_l);
            bf16x8 b_l1 = *(const bf16x8*)(bp_l + 512);
            f32x4 acc = {0.f, 0.f, 0.f, 0.f};
            acc = __builtin_amdgcn_mfma_f32_16x16x32_bf16(a_h0, b_h0, acc, 0, 0, 0);
            acc = __builtin_amdgcn_mfma_f32_16x16x32_bf16(a_h1, b_h1, acc, 0, 0, 0);
            acc = __builtin_amdgcn_mfma_f32_16x16x32_bf16(a_l0, b_h0, acc, 0, 0, 0);
            acc = __builtin_amdgcn_mfma_f32_16x16x32_bf16(a_l1, b_h1, acc, 0, 0, 0);
            acc = __builtin_amdgcn_mfma_f32_16x16x32_bf16(a_h0, b_l0, acc, 0, 0, 0);
            acc = __builtin_amdgcn_mfma_f32_16x16x32_bf16(a_h1, b_l1, acc, 0, 0, 0);
            const float nv = *np;
            const int colW = cm ^ swzW;
            const unsigned slotW = slotW0 + (unsigned)w;
            float* wp = wrow + colW;
            #pragma unroll
            for (int r = 0; r < 4; ++r) {
                float dv = nv - 2.f*acc[r];
                unsigned key = (__float_as_uint(dv) & ~63u) | slotW;
                wp[r*1024] = __uint_as_float(key);
            }
            bp_h += 1024; bp_l += 1024; np += 16; cm += 16;
        }
        __syncthreads();
        // scan this ck's 16 values: two sorted groups of 8, merged into sm
        {
            float g0 = rrow[0*64],  g1 = rrow[1*64],  g2 = rrow[2*64],  g3 = rrow[3*64];
            float g4 = rrow[4*64],  g5 = rrow[5*64],  g6 = rrow[6*64],  g7 = rrow[7*64];
            SORT8_(g0,g1,g2,g3,g4,g5,g6,g7)
            MERGE8_(g0,g1,g2,g3,g4,g5,g6,g7)
            float h0 = rrow[8*64],  h1 = rrow[9*64],  h2 = rrow[10*64], h3 = rrow[11*64];
            float h4 = rrow[12*64], h5 = rrow[13*64], h6 = rrow[14*64], h7 = rrow[15*64];
            SORT8_(h0,h1,h2,h3,h4,h5,h6,h7)
            MERGE8_(h0,h1,h2,h3,h4,h5,h6,h7)
        }
    }

    int mywin = 0;
    #pragma unroll 1
    for (int sr = 0; sr < 3; ++sr) {
        // butterfly all-reduce: global sorted top-8 of the union of all lanes' lists
        float a0 = sm0, a1 = sm1, a2 = sm2, a3 = sm3, a4 = sm4, a5 = sm5, a6 = sm6, a7 = sm7;
        #pragma unroll
        for (int off = 32; off; off >>= 1) {
            float b0 = __shfl_xor(a0, off), b1 = __shfl_xor(a1, off);
            float b2 = __shfl_xor(a2, off), b3 = __shfl_xor(a3, off);
            float b4 = __shfl_xor(a4, off), b5 = __shfl_xor(a5, off);
            float b6 = __shfl_xor(a6, off), b7 = __shfl_xor(a7, off);
            float c0 = fminf(a0, b7), c1 = fminf(a1, b6), c2 = fminf(a2, b5), c3 = fminf(a3, b4);
            float c4 = fminf(a4, b3), c5 = fminf(a5, b2), c6 = fminf(a6, b1), c7 = fminf(a7, b0);
            float u;
            u = fminf(c0, c4); c4 = fmaxf(c0, c4); c0 = u;
            u = fminf(c1, c5); c5 = fmaxf(c1, c5); c1 = u;
            u = fminf(c2, c6); c6 = fmaxf(c2, c6); c2 = u;
            u = fminf(c3, c7); c7 = fmaxf(c3, c7); c3 = u;
            u = fminf(c0, c2); c2 = fmaxf(c0, c2); c0 = u;
            u = fminf(c1, c3); c3 = fmaxf(c1, c3); c1 = u;
            u = fminf(c4, c6); c6 = fmaxf(c4, c6); c4 = u;
            u = fminf(c5, c7); c7 = fmaxf(c5, c7); c5 = u;
            u = fminf(c0, c1); c1 = fmaxf(c0, c1); c0 = u;
            u = fminf(c2, c3); c3 = fmaxf(c2, c3); c2 = u;
            u = fminf(c4, c5); c5 = fmaxf(c4, c5); c4 = u;
            u = fminf(c6, c7); c7 = fmaxf(c6, c7); c6 = u;
            a0 = c0; a1 = c1; a2 = c2; a3 = c3; a4 = c4; a5 = c5; a6 = c6; a7 = c7;
        }
        // extract the 8 winners in ascending order (set semantics; min-lane on ties)
        #define POPW(AW, WIDX)                                                              \
        {                                                                                   \
            const unsigned long long bal = __ballot(sm0 == (AW));                           \
            const int owner = (int)__ffsll(bal) - 1;                                        \
            if (L == sr*8 + (WIDX))                                                         \
                mywin = (int)(((__float_as_uint(AW) & 63u) << 6) | (unsigned)owner);        \
            if (L == owner) {                                                               \
                sm0 = sm1; sm1 = sm2; sm2 = sm3; sm3 = sm4;                                 \
                sm4 = sm5; sm5 = sm6; sm6 = sm7; sm7 = MX;                                  \
            }                                                                               \
        }
        POPW(a0, 0) POPW(a1, 1) POPW(a2, 2) POPW(a3, 3)
        POPW(a4, 4) POPW(a5, 5) POPW(a6, 6) POPW(a7, 7)
        #undef POPW
    }
    if (L < KS_) idx24[((size_t)b*N_ + q0 + w)*KS_ + L] = mywin;
}

// ---------------------------------------------------------------- exact fp32 rescore of the KS_ candidates
// R11: d matches the reference formula exactly.  R13: two winners per round.
// Exact: every lane holds ONE always-valid candidate; indices unique.
__global__ __launch_bounds__(256) void rescore_kernel(const float* __restrict__ x1, const float* __restrict__ nrm,
                                                      const int* __restrict__ idx24, int* __restrict__ idxout)
{
    const int t = threadIdx.x, w = t >> 6, L = t & 63;
    const int p = blockIdx.x*4 + w;
    const int bbase = p & ~(N_-1);
    const float MX = 3.4e38f;
    float dv = MX; int di = 0x7fffffff;
    if (L < KS_) {
        const int ci = idx24[(size_t)p*KS_ + L];
        const float4* qr = (const float4*)(x1 + (size_t)p*64);
        const float4* cr = (const float4*)(x1 + (size_t)(bbase + ci)*64);
        float dot = 0.f;
        #pragma unroll
        for (int i = 0; i < 16; ++i) {
            float4 a = qr[i], bx = cr[i];
            dot += a.x*bx.x + a.y*bx.y + a.z*bx.z + a.w*bx.w;
        }
        dv = __fsub_rn(__fadd_rn(nrm[p], nrm[bbase + ci]), 2.f*dot);
        di = ci;
    }
    int myfin = 0;
    #pragma unroll 1
    for (int r = 0; r < K_/2; ++r) {
        float v1 = dv; int g1 = di;
        float v2 = MX; int g2 = 0x7fffffff;
        #pragma unroll
        for (int off = 32; off; off >>= 1) {
            float ov1 = __shfl_xor(v1, off); int og1 = __shfl_xor(g1, off);
            float ov2 = __shfl_xor(v2, off); int og2 = __shfl_xor(g2, off);
            bool c1 = (ov1 < v1) || (ov1 == v1 && og1 < g1);
            float hv = c1 ? v1 : ov1; int hg = c1 ? g1 : og1;
            v1 = c1 ? ov1 : v1;       g1 = c1 ? og1 : g1;
            bool c2 = (ov2 < v2) || (ov2 == v2 && og2 < g2);
            float l2v = c2 ? ov2 : v2; int l2g = c2 ? og2 : g2;
            bool c3 = (l2v < hv) || (l2v == hv && l2g < hg);
            v2 = c3 ? l2v : hv;  g2 = c3 ? l2g : hg;
        }
        if (L == 2*r)   myfin = g1;
        if (L == 2*r+1) myfin = g2;
        if (di == g1 || di == g2) dv = MX;
    }
    if (L < K_) idxout[(size_t)p*K_ + L] = myfin;
}

// ---------------------------------------------------------------- P/Q precompute
__global__ __launch_bounds__(256) void pq1_kernel(const float* __restrict__ x, const float* __restrict__ W,
                                                  const float* __restrict__ b1,
                                                  float* __restrict__ P, float* __restrict__ Q)
{
    __shared__ float wd[256], wb[256];
    const int t = threadIdx.x;
    wd[t] = W[t] - W[256 + t];
    wb[t] = W[256 + t];
    __syncthreads();
    const int p = blockIdx.x*4 + (t >> 6), c = t & 63;
    const float4 xv = ((const float4*)x)[p];
    float Pv = b1[c] + xv.x*wd[c] + xv.y*wd[64+c] + xv.z*wd[128+c] + xv.w*wd[192+c];
    float Qv =         xv.x*wb[c] + xv.y*wb[64+c] + xv.z*wb[128+c] + xv.w*wb[192+c];
    P[p*64 + c] = Pv;
    Q[p*64 + c] = Qv;
}

__global__ __launch_bounds__(256) void pq2_kernel(const float* __restrict__ x1, const float* __restrict__ W,
                                                  const float* __restrict__ b1,
                                                  float* __restrict__ P, float* __restrict__ Q)
{
    __shared__ float wd[64*128], wb[64*128];
    const int t = threadIdx.x;
    for (int e = t; e < 8192; e += 256) {
        float wt = W[e], wbo = W[8192 + e];
        wd[e] = wt - wbo; wb[e] = wbo;
    }
    __syncthreads();
    const int pl = t >> 7, c = t & 127;
    const float b1v = b1[c];
    for (int p0 = blockIdx.x*2; p0 < BN_; p0 += gridDim.x*2) {
        const int p = p0 + pl;
        float Pv = b1v, Qv = 0.f;
        const float* xrow = x1 + p*64;
        #pragma unroll 8
        for (int k = 0; k < 64; ++k) {
            float xv = xrow[k];
            Pv += xv * wd[k*128 + c];
            Qv += xv * wb[k*128 + c];
        }
        P[p*128 + c] = Pv;
        Q[p*128 + c] = Qv;
    }
}

// ---------------------------------------------------------------- layer-1 BN stats (fp64 per-block partials)
template<int HO>
__global__ __launch_bounds__(256) void stats_l1_kernel(const float* __restrict__ P, const float* __restrict__ Q,
                                                       const int* __restrict__ idx, double* __restrict__ partOut)
{
    constexpr int G = 256/HO;
    __shared__ double red[256], red2[256];
    const int t = threadIdx.x, c = t % HO, g = t / HO;
    double s = 0., s2 = 0.;
    for (int p = blockIdx.x; p < BN_; p += gridDim.x) {
        const float Pv = P[p*HO + c];
        const int bbase = p & ~(N_-1);
        for (int j = g; j < K_; j += G) {
            int m = idx[p*K_ + j];
            float z = Pv + Q[(bbase + m)*HO + c];
            double zd = (double)z;
            s += zd; s2 += zd*zd;
        }
    }
    red[t] = s; red2[t] = s2;
    __syncthreads();
    if (t < HO) {
        double a = red[t], a2 = red2[t];
        #pragma unroll
        for (int q = 1; q < G; ++q) { a += red[q*HO + t]; a2 += red2[q*HO + t]; }
        partOut[(size_t)blockIdx.x*(2*HO) + t] = a;
        partOut[(size_t)blockIdx.x*(2*HO) + HO + t] = a2;
    }
}

// ---------------------------------------------------------------- EdgeConv layer-2, exact fp32 (conv1:
// its output feeds kNN2, which is flip-sensitive to ~1e-4 feature perturbation).
// R11: BN applied in the reference's elementwise op order (((z-m)*rstd)*g+be,
// separately rounded) — the folded z*ac+bc form differed by 1-2 ULP on x1 features.
template<int HO>
__global__ __launch_bounds__(256) void conv_l2_kernel(
    const float* __restrict__ P, const float* __restrict__ Q, const int* __restrict__ idx,
    const float* __restrict__ st1, const float* __restrict__ g1, const float* __restrict__ be1,
    const float* __restrict__ w2, const float* __restrict__ b2,
    float* __restrict__ zmax, float* __restrict__ zmin, double* __restrict__ partOut)
{
    __shared__ float w2s[HO*64];
    __shared__ float h1s[K_*HO];
    __shared__ float redA[256], redB[256];
    __shared__ double redD[256], redD2[256];
    const int t = threadIdx.x;
    const int cy = blockIdx.y;
    for (int e = t; e < HO*64; e += 256) {
        int c = e >> 6, cl = e & 63;
        w2s[e] = w2[c*HO + cy*64 + cl];
    }
    const int cA = t % HO;
    const float mA = st1[2*HO + cA], rA = st1[3*HO + cA];
    const float gA = g1[cA], beA = be1[cA];
    const int c2l = t & 63, jh = t >> 6;
    const float b2v = b2[cy*64 + c2l];
    double ssum = 0., ssq = 0.;
    for (int p = blockIdx.x; p < BN_; p += gridDim.x) {
        __syncthreads();
        const int bbase = p & ~(N_-1);
        const float Pv = P[p*HO + cA];
        for (int e = t; e < K_*HO; e += 256) {
            int j = e / HO;
            int m = idx[p*K_ + j];
            float z = Pv + Q[(bbase + m)*HO + cA];
            float bn = __fadd_rn(__fmul_rn(__fmul_rn(__fsub_rn(z, mA), rA), gA), beA);
            h1s[e] = fmaxf(bn, 0.f);
        }
        __syncthreads();
        float acc[5];
        #pragma unroll
        for (int q = 0; q < 5; ++q) acc[q] = b2v;
        for (int c = 0; c < HO; ++c) {
            float wv = w2s[c*64 + c2l];
            #pragma unroll
            for (int q = 0; q < 5; ++q)
                acc[q] += h1s[(jh + q*4)*HO + c] * wv;
        }
        float mx = acc[0], mn = acc[0];
        #pragma unroll
        for (int q = 0; q < 5; ++q) {
            mx = fmaxf(mx, acc[q]); mn = fminf(mn, acc[q]);
            double ad = (double)acc[q];
            ssum += ad; ssq += ad*ad;
        }
        redA[t] = mx; redB[t] = mn;
        __syncthreads();
        if (t < 64) {
            float M = redA[t], Mn = redB[t];
            #pragma unroll
            for (int g = 1; g < 4; ++g) { M = fmaxf(M, redA[g*64 + t]); Mn = fminf(Mn, redB[g*64 + t]); }
            zmax[p*HO + cy*64 + t] = M;
            zmin[p*HO + cy*64 + t] = Mn;
        }
    }
    __syncthreads();
    redD[t] = ssum; redD2[t] = ssq;
    __syncthreads();
    if (t < 64) {
        double s = redD[t], s2 = redD2[t];
        #pragma unroll
        for (int g = 1; g < 4; ++g) { s += redD[g*64 + t]; s2 += redD2[g*64 + t]; }
        partOut[(size_t)blockIdx.x*(2*HO) + cy*64 + t] = s;
        partOut[(size_t)blockIdx.x*(2*HO) + HO + cy*64 + t] = s2;
    }
}

// ---------------------------------------------------------------- W2^T split-bf16 prep
__global__ __launch_bounds__(256) void prep_w2t_kernel(const float* __restrict__ W,
                                                       unsigned short* __restrict__ wh,
                                                       unsigned short* __restrict__ wl, int HO)
{
    const int e = blockIdx.x*256 + threadIdx.x;   // e = k*HO + c
    const int k = e / HO, c = e % HO;
    const float v = W[e];
    unsigned short h = f2bf(v);
    float hf = __uint_as_float((unsigned)h << 16);
    wh[c*HO + k] = h;
    wl[c*HO + k] = f2bf(v - hf);
}

// ---------------------------------------------------------------- EdgeConv layer-2 via MFMA (split-bf16)
// conv2 only: output feeds the classifier (value-continuous), bf16-split safe.
template<int HO>
__global__ __launch_bounds__(256) void conv_l2_mfma_kernel(
    const float* __restrict__ P, const float* __restrict__ Q, const int* __restrict__ idx,
    const float* __restrict__ st1, const float* __restrict__ g1, const float* __restrict__ be1,
    const unsigned short* __restrict__ w2h, const unsigned short* __restrict__ w2l,
    const float* __restrict__ b2,
    float* __restrict__ zmax, float* __restrict__ zmin, double* __restrict__ partOut)
{
    constexpr int HOP = HO + 8;
    constexpr int CDP = HO + 1;
    constexpr int CTW = HO / 64;
    constexpr int KSn = HO / 32;
    constexpr int HSH = (HO == 128) ? 7 : 6;
    __shared__ __align__(16) short hs[2*80*HOP];
    __shared__ int sidx[80];
    float* cd = (float*)hs;

    const int t = threadIdx.x, w = t >> 6, L = t & 63;
    const int m16 = L & 15, q4 = L >> 4;

    const int kT = t & (HO - 1);
    const float ac = st1[3*HO + kT] * g1[kT];
    const float bc = be1[kT] - st1[2*HO + kT] * ac;

    bf16x8 Bh[CTW][KSn], Bl[CTW][KSn];
    #pragma unroll
    for (int ctl = 0; ctl < CTW; ++ctl)
        #pragma unroll
        for (int ks = 0; ks < KSn; ++ks) {
            const int c  = w*16*CTW + ctl*16 + m16;
            const int k0 = ks*32 + q4*8;
            Bh[ctl][ks] = *(const bf16x8*)(w2h + c*HO + k0);
            Bl[ctl][ks] = *(const bf16x8*)(w2l + c*HO + k0);
        }

    const float b2c = (t < HO) ? b2[t] : 0.f;
    double ssum = 0., ssq = 0.;

    for (int p0 = blockIdx.x*4; p0 < BN_; p0 += gridDim.x*4) {
        const int bbase = p0 & ~(N_-1);
        __syncthreads();
        if (t < 80) sidx[t] = idx[p0*K_ + t];
        __syncthreads();
        for (int e = t; e < 80*HO; e += 256) {
            const int r  = e >> HSH;
            const int pl = (r*3277) >> 16;     // r/20 for r<80
            const int mI = sidx[r];
            float z = P[(size_t)(p0+pl)*HO + kT] + Q[(size_t)(bbase+mI)*HO + kT];
            float h = fmaxf(z*ac + bc, 0.f);
            unsigned short hh = f2bf(h);
            float hf = __uint_as_float((unsigned)hh << 16);
            unsigned short hl = f2bf(h - hf);
            hs[r*HOP + kT] = (short)hh;
            hs[80*HOP + r*HOP + kT] = (short)hl;
        }
        __syncthreads();
        f32x4 acc[5][CTW];
        #pragma unroll
        for (int rt = 0; rt < 5; ++rt)
            #pragma unroll
            for (int ctl = 0; ctl < CTW; ++ctl)
                acc[rt][ctl] = (f32x4){0.f, 0.f, 0.f, 0.f};
        #pragma unroll
        for (int rt = 0; rt < 5; ++rt)
            #pragma unroll
            for (int ks = 0; ks < KSn; ++ks) {
                const short* ap = hs + (rt*16 + m16)*HOP + ks*32 + q4*8;
                bf16x8 Ah = *(const bf16x8*)ap;
                bf16x8 Al = *(const bf16x8*)(ap + 80*HOP);
                #pragma unroll
                for (int ctl = 0; ctl < CTW; ++ctl) {
                    acc[rt][ctl] = __builtin_amdgcn_mfma_f32_16x16x32_bf16(Ah, Bh[ctl][ks], acc[rt][ctl], 0, 0, 0);
                    acc[rt][ctl] = __builtin_amdgcn_mfma_f32_16x16x32_bf16(Al, Bh[ctl][ks], acc[rt][ctl], 0, 0, 0);
                    acc[rt][ctl] = __builtin_amdgcn_mfma_f32_16x16x32_bf16(Ah, Bl[ctl][ks], acc[rt][ctl], 0, 0, 0);
                }
            }
        __syncthreads();
        #pragma unroll
        for (int rt = 0; rt < 5; ++rt)
            #pragma unroll
            for (int ctl = 0; ctl < CTW; ++ctl) {
                const int col = w*16*CTW + ctl*16 + m16;
                #pragma unroll
                for (int ri = 0; ri < 4; ++ri) {
                    const int row = rt*16 + q4*4 + ri;
                    cd[row*CDP + col] = acc[rt][ctl][ri];
                }
            }
        __syncthreads();
        if (t < HO) {
            #pragma unroll
            for (int pl = 0; pl < 4; ++pl) {
                float mx = -3.4e38f, mn = 3.4e38f;
                #pragma unroll
                for (int j = 0; j < K_; ++j) {
                    float v = cd[(pl*20 + j)*CDP + t] + b2c;
                    mx = fmaxf(mx, v); mn = fminf(mn, v);
                    double vd = (double)v;
                    ssum += vd; ssq += vd*vd;
                }
                zmax[(size_t)(p0+pl)*HO + t] = mx;
                zmin[(size_t)(p0+pl)*HO + t] = mn;
            }
        }
    }
    if (t < HO) {
        partOut[(size_t)blockIdx.x*(2*HO) + t] = ssum;
        partOut[(size_t)blockIdx.x*(2*HO) + HO + t] = ssq;
    }
}

// max_j relu(BN(z)) = relu(BN(max_j z)) for gamma>=0, min for gamma<0.
// R11: reference elementwise op order for the x1b-producing instance.
template<int HO>
__global__ __launch_bounds__(256) void conv_fin_kernel(
    const float* __restrict__ zmax, const float* __restrict__ zmin,
    const float* __restrict__ st2, const float* __restrict__ g2, const float* __restrict__ be2,
    float* __restrict__ out)
{
    int e = blockIdx.x*256 + threadIdx.x;
    int c = e & (HO-1);
    float g = g2[c];
    float sel = (g >= 0.f) ? zmax[e] : zmin[e];
    float bn = __fadd_rn(__fmul_rn(__fmul_rn(__fsub_rn(sel, st2[2*HO + c]), st2[3*HO + c]), g), be2[c]);
    out[e] = fmaxf(bn, 0.f);
}

// ---------------------------------------------------------------- classifier
__global__ __launch_bounds__(256) void cls1_kernel(
    const float* __restrict__ x1, const float* __restrict__ x2f,
    const float* __restrict__ W, const float* __restrict__ b1,
    float* __restrict__ z, double* __restrict__ partOut)
{
    __shared__ float ws[192*64];
    __shared__ float xr[4*192];
    __shared__ double red[256], red2[256];
    const int t = threadIdx.x, cy = blockIdx.y;
    for (int e = t; e < 192*64; e += 256) {
        int c = e >> 6, cl = e & 63;
        ws[e] = W[c*128 + cy*64 + cl];
    }
    const int pl = t >> 6, c2l = t & 63;
    const float b1v = b1[cy*64 + c2l];
    double ssum = 0., ssq = 0.;
    for (int p0 = blockIdx.x*4; p0 < BN_; p0 += gridDim.x*4) {
        __syncthreads();
        for (int l = t; l < 4*192; l += 256) {
            int pp = l / 192, cc = l % 192;
            xr[l] = (cc < 64) ? x1[(p0+pp)*64 + cc] : x2f[(p0+pp)*128 + cc - 64];
        }
        __syncthreads();
        float acc = b1v;
        const float* xx = xr + pl*192;
        #pragma unroll 8
        for (int c = 0; c < 192; ++c) acc += xx[c] * ws[c*64 + c2l];
        z[(p0+pl)*128 + cy*64 + c2l] = acc;
        double ad = (double)acc;
        ssum += ad; ssq += ad*ad;
    }
    __syncthreads();
    red[t] = ssum; red2[t] = ssq;
    __syncthreads();
    if (t < 64) {
        double s = red[t], s2 = red2[t];
        #pragma unroll
        for (int g = 1; g < 4; ++g) { s += red[g*64 + t]; s2 += red2[g*64 + t]; }
        // partial row layout [512][256]: (sum ch0..127, sumsq ch0..127); the two
        // cy-planes of the same blockIdx.x fill disjoint 64-ch ranges.
        partOut[(size_t)blockIdx.x*256 + cy*64 + t] = s;
        partOut[(size_t)blockIdx.x*256 + 128 + cy*64 + t] = s2;
    }
}

__global__ __launch_bounds__(256) void cls_fin_kernel(
    const float* __restrict__ z, const float* __restrict__ st,
    const float* __restrict__ g, const float* __restrict__ be,
    const float* __restrict__ w2, const float* __restrict__ b2,
    float* __restrict__ out)
{
    const int t = threadIdx.x, w = t >> 6, L = t & 63;
    const int p = blockIdx.x*4 + w;
    float s = 0.f;
    #pragma unroll
    for (int h = 0; h < 2; ++h) {
        int c = L + h*64;
        float v = (z[p*128 + c] - st[256 + c]) * st[384 + c] * g[c] + be[c];
        s += fmaxf(v, 0.f) * w2[c];
    }
    #pragma unroll
    for (int off = 32; off; off >>= 1) s += __shfl_xor(s, off);
    if (L == 0) out[p] = s + b2[0];
}

// ---------------------------------------------------------------- launch
extern "C" void kernel_launch(void* const* d_in, const int* in_sizes, int n_in,
                              void* d_out, int out_size, void* d_ws, size_t ws_size,
                              hipStream_t stream)
{
    const float* x      = (const float*)d_in[0];
    const float* c1_w1  = (const float*)d_in[1];
    const float* c1_b1  = (const float*)d_in[2];
    const float* c1_g1  = (const float*)d_in[3];
    const float* c1_be1 = (const float*)d_in[4];
    const float* c1_w2  = (const float*)d_in[5];
    const float* c1_b2  = (const float*)d_in[6];
    const float* c1_g2  = (const float*)d_in[7];
    const float* c1_be2 = (const float*)d_in[8];
    const float* c2_w1  = (const float*)d_in[9];
    const float* c2_b1  = (const float*)d_in[10];
    const float* c2_g1  = (const float*)d_in[11];
    const float* c2_be1 = (const float*)d_in[12];
    const float* c2_w2  = (const float*)d_in[13];
    const float* c2_b2  = (const float*)d_in[14];
    const float* c2_g2  = (const float*)d_in[15];
    const float* c2_be2 = (const float*)d_in[16];
    const float* cls_w1 = (const float*)d_in[17];
    const float* cls_b1 = (const float*)d_in[18];
    const float* cls_g1 = (const float*)d_in[19];
    const float* cls_be1= (const float*)d_in[20];
    const float* cls_w2 = (const float*)d_in[21];
    const float* cls_b2 = (const float*)d_in[22];
    (void)in_sizes; (void)n_in; (void)out_size; (void)ws_size;

    char* ws = (char*)d_ws;
    size_t off = 0;
    auto alloc = [&](size_t bytes) { char* p = ws + off; off += (bytes + 255) & ~255ull; return p; };
    float* A    = (float*)alloc((size_t)16<<20);   // P1 -> P2 -> zcls
    float* Bq   = (float*)alloc((size_t)16<<20);   // Q1 -> Q2 -> cls partials
    float* zmax = (float*)alloc((size_t)16<<20);   // also hosts Xh/Xl between conv1 and conv2
    float* zmin = (float*)alloc((size_t)16<<20);
    float* x1b  = (float*)alloc((size_t)8<<20);
    float* x2b  = (float*)alloc((size_t)16<<20);   // also hosts idx24 + stats partials (dead windows)
    int*   idx  = (int*)  alloc((size_t)BN_*K_*4); // idx1 -> idx2
    float* nrm  = (float*)alloc((size_t)BN_*4);
    float* st   = (float*)alloc((size_t)5*512*4);
    unsigned short* w2th = (unsigned short*)alloc((size_t)128*128*2);  // W2^T hi
    unsigned short* w2tl = (unsigned short*)alloc((size_t)128*128*2);  // W2^T lo
    float *st0 = st, *st1 = st+512, *st2 = st+1024, *st3 = st+1536, *st4 = st+2048;

    unsigned short* Xh = (unsigned short*)zmax;                       // 4 MB (tiled layout, R17)
    unsigned short* Xl = (unsigned short*)((char*)zmax + (4<<20));    // 4 MB
    int* idx24 = (int*)x2b;
    double* part  = (double*)x2b;  // fp64 stats partials (max 4 MB): free during both conv phases
    double* partC = (double*)Bq;   // cls stats partials (1 MB): Q2 dead after conv_l2_mfma

    // ---- EdgeConv 1 (exact fp32 conv: x1b feeds flip-sensitive kNN2)
    knn4_kernel<<<dim3(N_/16, B_), 1024, 0, stream>>>(x, idx);
    pq1_kernel<<<BN_/4, 256, 0, stream>>>(x, c1_w1, c1_b1, A, Bq);
    stats_l1_kernel<64><<<2048, 256, 0, stream>>>(A, Bq, idx, part);
    finalize_parts_kernel<<<64, 256, 0, stream>>>(part, 2048, 64, 1.0/655360.0, st0);
    conv_l2_kernel<64><<<dim3(2048,1), 256, 0, stream>>>(A, Bq, idx, st0, c1_g1, c1_be1, c1_w2, c1_b2, zmax, zmin, part);
    finalize_parts_kernel<<<64, 256, 0, stream>>>(part, 2048, 64, 1.0/655360.0, st1);
    conv_fin_kernel<64><<<BN_*64/256, 256, 0, stream>>>(zmax, zmin, st1, c1_g2, c1_be2, x1b);

    // ---- EdgeConv 2 (MFMA conv: x2b only feeds classifier)
    nrm64_kernel<<<BN_/4, 256, 0, stream>>>(x1b, nrm);
    prep64t_kernel<<<BN_/32, 256, 0, stream>>>(x1b, Xh, Xl);
    knn64v4_kernel<<<dim3(N_/16, B_), 1024, 0, stream>>>(Xh, Xl, nrm, idx24);
    rescore_kernel<<<BN_/4, 256, 0, stream>>>(x1b, nrm, idx24, idx);
    pq2_kernel<<<1024, 256, 0, stream>>>(x1b, c2_w1, c2_b1, A, Bq);
    stats_l1_kernel<128><<<2048, 256, 0, stream>>>(A, Bq, idx, part);
    finalize_parts_kernel<<<128, 256, 0, stream>>>(part, 2048, 128, 1.0/655360.0, st2);
    prep_w2t_kernel<<<128*128/256, 256, 0, stream>>>(c2_w2, w2th, w2tl, 128);
    conv_l2_mfma_kernel<128><<<2048, 256, 0, stream>>>(A, Bq, idx, st2, c2_g1, c2_be1, w2th, w2tl, c2_b2, zmax, zmin, part);
    finalize_parts_kernel<<<128, 256, 0, stream>>>(part, 2048, 128, 1.0/655360.0, st3);
    conv_fin_kernel<128><<<BN_*128/256, 256, 0, stream>>>(zmax, zmin, st3, c2_g2, c2_be2, x2b);

    // ---- classifier
    cls1_kernel<<<dim3(512,2), 256, 0, stream>>>(x1b, x2b, cls_w1, cls_b1, A, partC);
    finalize_parts_kernel<<<128, 256, 0, stream>>>(partC, 512, 128, 1.0/32768.0, st4);
    cls_fin_kernel<<<BN_/4, 256, 0, stream>>>(A, st4, cls_g1, cls_be1, cls_w2, cls_b2, (float*)d_out);
}

// Round 10
// 1245.320 us; speedup vs baseline: 1.2308x; 1.0020x over previous
//
#include <hip/hip_runtime.h>
#include <math.h>

#define B_ 8
#define N_ 4096
#define K_ 20
#define KS_ 24          // approx-select width; exact rescore trims to K_ (R3-validated margin)
#define BN_ (B_*N_)

typedef __attribute__((ext_vector_type(8))) short bf16x8;
typedef __attribute__((ext_vector_type(4))) float f32x4;

// ---------------------------------------------------------------- BN stats finalize (deterministic, fp64)
// R10: float atomicAdd stats were order-nondeterministic across graph replays ->
// kNN2 boundary flip -> post-timing divergence.  R11: the deterministic fp32
// order landed on the WRONG side of a ~1-ULP distance tie (absmax 0.1177).
// All stats now accumulate in DOUBLE (partials + reduce + mean/var/rstd), so our
// stats are ~exact; the x1b-feeding BN applies the reference's elementwise op
// order; rescore uses the reference's full d formula.  DO NOT reintroduce
// atomicAdd or fold these back into fp32/FMA on the conv1 path.
// part layout: [nb][2*H] doubles (sum(H), sumsq(H) per block row).
__global__ __launch_bounds__(256) void finalize_parts_kernel(
    const double* __restrict__ part, int nb, int H, double invCount, float* __restrict__ st)
{
    __shared__ double red[256], red2[256];
    const int c = blockIdx.x, t = threadIdx.x;
    double s = 0., s2 = 0.;
    for (int b = t; b < nb; b += 256) {
        s  += part[(size_t)b*2*H + c];
        s2 += part[(size_t)b*2*H + H + c];
    }
    red[t] = s; red2[t] = s2;
    __syncthreads();
    #pragma unroll
    for (int off = 128; off; off >>= 1) {
        if (t < off) { red[t] += red[t+off]; red2[t] += red2[t+off]; }
        __syncthreads();
    }
    if (t == 0) {
        double mean = red[0] * invCount;
        double var  = fmax(red2[0] * invCount - mean * mean, 0.);
        st[2*H + c] = (float)mean;
        st[3*H + c] = (float)(1.0 / sqrt(var + 1e-5));
    }
}

// ---------------------------------------------------------------- kNN, C=4
// R7-validated (value, candidate-index) lexicographic argmin — matches jax
// top_k tie-break; reference-defining (no rescore guard) -> selection EXACT.
// R15: rolled loops (L1I); d[64] eliminated via fused compute+insert; rescans
// recompute dists (bit-identical).  DO NOT replace with DPP (R9), and DO NOT
// apply the knn64 key-embed trick here (would alter reference tie-breaks).
__global__ __launch_bounds__(1024, 8) void knn4_kernel(const float* __restrict__ x, int* __restrict__ idxout)
{
    __shared__ float4 xt[N_];   // 64 KB
    const int b = blockIdx.y;
    const int t = threadIdx.x;
    const float4* xg = (const float4*)x + b*N_;
    for (int e = t; e < N_; e += 1024) xt[e] = xg[e];
    __syncthreads();
    const int w = t >> 6, L = t & 63;
    const int n = blockIdx.x*16 + w;
    const float4 q = xt[n];
    const float MX = 3.4e38f;
    float m1 = MX, m2 = MX, m3 = MX; int i1 = 0, i2 = 0, i3 = 0;
    #pragma unroll 1
    for (int j = 0; j < 64; ++j) {
        float4 vv = xt[(j<<6) | L];
        float nn = vv.x*vv.x + vv.y*vv.y + vv.z*vv.z + vv.w*vv.w;
        float dp = q.x*vv.x + q.y*vv.y + q.z*vv.z + q.w*vv.w;
        float v = nn - 2.f*dp;   // |xn|^2 dropped: rank-equivalent
        bool c1 = v < m1, c2 = v < m2, c3 = v < m3;
        m3 = c2 ? m2 : (c3 ? v : m3);
        i3 = c2 ? i2 : (c3 ? j : i3);
        m2 = c1 ? m1 : (c2 ? v : m2);
        i2 = c1 ? i1 : (c2 ? j : i2);
        m1 = c1 ? v : m1;
        i1 = c1 ? j : i1;
    }
    unsigned long long used = 0;
    int mywin = 0;
    #pragma unroll 1
    for (int r = 0; r < K_; ++r) {
        float bv = m1; int bg = (i1<<6) | L;
        #pragma unroll
        for (int off = 32; off; off >>= 1) {
            float ov = __shfl_xor(bv, off);
            int   og = __shfl_xor(bg, off);
            bool tk = (ov < bv) || (ov == bv && og < bg);
            bv = tk ? ov : bv; bg = tk ? og : bg;
        }
        if (L == r) mywin = bg;
        if (L == (bg & 63)) {
            used |= 1ull << i1;
            m1 = m2; i1 = i2; m2 = m3; i2 = i3; m3 = MX;
            if (m1 == MX) {
                m2 = MX; m3 = MX; i1 = 0; i2 = 0; i3 = 0;
                #pragma unroll 1
                for (int j = 0; j < 64; ++j) {
                    float4 vv = xt[(j<<6) | L];
                    float nn = vv.x*vv.x + vv.y*vv.y + vv.z*vv.z + vv.w*vv.w;
                    float dp = q.x*vv.x + q.y*vv.y + q.z*vv.z + q.w*vv.w;
                    float dj = nn - 2.f*dp;
                    float v = ((used >> j) & 1ull) ? MX : dj;
                    bool c1 = v < m1, c2 = v < m2, c3 = v < m3;
                    m3 = c2 ? m2 : (c3 ? v : m3);
                    i3 = c2 ? i2 : (c3 ? j : i3);
                    m2 = c1 ? m1 : (c2 ? v : m2);
                    i2 = c1 ? i1 : (c2 ? j : i2);
                    m1 = c1 ? v : m1;
                    i1 = c1 ? j : i1;
                }
            }
        }
    }
    if (L < K_) idxout[(b*N_ + n)*K_ + L] = mywin;
}

// ---------------------------------------------------------------- fp32 -> bf16 RNE
static __device__ inline unsigned short f2bf(float f)
{
    unsigned u = __float_as_uint(f);
    unsigned r = (u + 0x7fffu + ((u >> 16) & 1u)) >> 16;   // RNE
    return (unsigned short)r;
}

// ---------------------------------------------------------------- x1 norms (bit-identical to the R2-validated reduce)
// nrm feeds the flip-sensitive exact rescore (R11): the 64-lane butterfly sum
// order must NOT change.
__global__ __launch_bounds__(256) void nrm64_kernel(const float* __restrict__ x, float* __restrict__ nrm)
{
    const int t = threadIdx.x, L = t & 63;
    const int row = blockIdx.x*4 + (t >> 6);
    const float v = x[row*64 + L];
    float s = v * v;
    #pragma unroll
    for (int off = 32; off; off >>= 1) s += __shfl_xor(s, off);
    if (L == 0) nrm[row] = s;
}

// ---------------------------------------------------------------- split-bf16 prep, TILED layout (R17)
// R17: fragment gathers saturated VMEM (transposed 128B-stride, half-used
// lines).  Tiled layout: addr(shorts) = (row>>4)*1024 + (ch>>3)*128 +
// (row&15)*8 + (ch&7) -> fragment loads perfectly coalesced.
__global__ __launch_bounds__(256) void prep64t_kernel(const float* __restrict__ x,
                                                      unsigned short* __restrict__ Xh,
                                                      unsigned short* __restrict__ Xl)
{
    const int t = threadIdx.x;
    const int j = t >> 5, rl = t & 31;          // chunk 0..7, local row 0..31
    const int row = blockIdx.x*32 + rl;
    const float4* xp = (const float4*)(x + (size_t)row*64 + j*8);
    const float4 a = xp[0], c = xp[1];
    float v[8] = {a.x, a.y, a.z, a.w, c.x, c.y, c.z, c.w};
    bf16x8 hv, lv;
    #pragma unroll
    for (int s = 0; s < 8; ++s) {
        unsigned short h = f2bf(v[s]);
        float hf = __uint_as_float((unsigned)h << 16);
        hv[s] = (short)h;
        lv[s] = (short)f2bf(v[s] - hf);
    }
    const size_t base = (size_t)(row >> 4)*1024 + (size_t)j*128 + (size_t)(row & 15)*8;
    *(bf16x8*)(Xh + base) = hv;
    *(bf16x8*)(Xl + base) = lv;
}

// comparator: (x,y) -> (min,max)
#define CE_(x,y) { float _t = fminf(x,y); y = fmaxf(x,y); x = _t; }
// Batcher odd-even sort-8 (19 CE)
#define SORT8_(g0,g1,g2,g3,g4,g5,g6,g7)                                   \
    CE_(g0,g1) CE_(g2,g3) CE_(g4,g5) CE_(g6,g7)                           \
    CE_(g0,g2) CE_(g1,g3) CE_(g4,g6) CE_(g5,g7)                           \
    CE_(g1,g2) CE_(g5,g6)                                                 \
    CE_(g0,g4) CE_(g1,g5) CE_(g2,g6) CE_(g3,g7)                           \
    CE_(g2,g4) CE_(g3,g5)                                                 \
    CE_(g1,g2) CE_(g3,g4) CE_(g5,g6)
// keep lowest-8 (sorted) of two sorted-asc 8-lists: sm = low8(sm, g)
#define MERGE8_(g0,g1,g2,g3,g4,g5,g6,g7)                                  \
    sm0 = fminf(sm0,g7); sm1 = fminf(sm1,g6); sm2 = fminf(sm2,g5);        \
    sm3 = fminf(sm3,g4); sm4 = fminf(sm4,g3); sm5 = fminf(sm5,g2);        \
    sm6 = fminf(sm6,g1); sm7 = fminf(sm7,g0);                             \
    CE_(sm0,sm4) CE_(sm1,sm5) CE_(sm2,sm6) CE_(sm3,sm7)                   \
    CE_(sm0,sm2) CE_(sm1,sm3) CE_(sm4,sm6) CE_(sm5,sm7)                   \
    CE_(sm0,sm1) CE_(sm2,sm3) CE_(sm4,sm5) CE_(sm6,sm7)

// ---------------------------------------------------------------- kNN, C=64 via MFMA (split-bf16 Gram, approx)
// v12 (R19): R18 counters showed OccupancyPercent 80->50 (one 1024-thr block
// resident; the 64KB dist tile sat exactly at the 2-block LDS boundary) with
// VALUBusy 70% — barrier drains exposed with no co-resident block to hide them.
// dist halved to 32KB: 8 chunks of 512 candidates (each wave stages 2
// sub-tiles of 16), one SORT8+MERGE8 per chunk (identical total CE count and
// identical resulting per-lane top-8).  slot = ck*8 + (cm>>6); lane residue
// property (cand == L mod 64) preserved -> key/ballot reconstruction unchanged.
// Selection (R16), keys (R12), tiled layout (R17), strength-reduced staging
// (R18), top-8 dropout P~5e-9 (R14) all unchanged.
__global__ __launch_bounds__(1024, 4) void knn64v4_kernel(
    const unsigned short* __restrict__ Xh, const unsigned short* __restrict__ Xl,
    const float* __restrict__ nrm, int* __restrict__ idx24)
{
    __shared__ float dist[16*512];   // 32 KB -> 2 blocks/CU resident
    const int b = blockIdx.y, t = threadIdx.x;
    const int w = t >> 6, L = t & 63;
    const int q0 = blockIdx.x * 16;
    const int m = L & 15, q4 = L >> 4;
    const size_t rowbase = (size_t)b * N_ * 64;
    const int swzW = q4 << 4;         // write-side column XOR (qrow>>2 == q4)
    const int swzR = (w >> 2) << 4;   // read-side column XOR (query row w)
    const int fragoff = q4*128 + m*8; // within-tile fragment offset (shorts)

    // A fragments: tile q0>>4
    const unsigned short* aph = Xh + rowbase + (size_t)(q0 >> 4)*1024 + fragoff;
    const unsigned short* apl = Xl + rowbase + (size_t)(q0 >> 4)*1024 + fragoff;
    const bf16x8 a_h0 = *(const bf16x8*)(aph);
    const bf16x8 a_h1 = *(const bf16x8*)(aph + 512);
    const bf16x8 a_l0 = *(const bf16x8*)(apl);
    const bf16x8 a_l1 = *(const bf16x8*)(apl + 512);

    const float MX = 3.4e38f;
    float sm0 = MX, sm1 = MX, sm2 = MX, sm3 = MX, sm4 = MX, sm5 = MX, sm6 = MX, sm7 = MX;

    float* const wrow = dist + q4*2048;        // q4*4*512
    float* const rrow = dist + w*512 + (L ^ swzR);

    #pragma unroll 1
    for (int ck = 0; ck < 8; ++ck) {
        const unsigned slotW0 = (unsigned)(ck*8);
        // strength-reduced staging pointers for this ck (each wave: 2 sub-tiles)
        const unsigned short* bp_h = Xh + rowbase + (size_t)(ck*32 + w*2)*1024 + fragoff;
        const unsigned short* bp_l = Xl + rowbase + (size_t)(ck*32 + w*2)*1024 + fragoff;
        const float* np = nrm + b*N_ + ck*512 + w*32 + m;
        int cm = w*32 + m;
        __syncthreads();
        #pragma unroll
        for (int tt = 0; tt < 2; ++tt) {
            bf16x8 b_h0 = *(const bf16x8*)(bp_h);
            bf16x8 b_h1 = *(const bf16x8*)(bp_h + 512);
            bf16x8 b_l0 = *(const bf16x8*)(bp_l);
            bf16x8 b_l1 = *(const bf16x8*)(bp_l + 512);
            f32x4 acc = {0.f, 0.f, 0.f, 0.f};
            acc = __builtin_amdgcn_mfma_f32_16x16x32_bf16(a_h0, b_h0, acc, 0, 0, 0);
            acc = __builtin_amdgcn_mfma_f32_16x16x32_bf16(a_h1, b_h1, acc, 0, 0, 0);
            acc = __builtin_amdgcn_mfma_f32_16x16x32_bf16(a_l0, b_h0, acc, 0, 0, 0);
            acc = __builtin_amdgcn_mfma_f32_16x16x32_bf16(a_l1, b_h1, acc, 0, 0, 0);
            acc = __builtin_amdgcn_mfma_f32_16x16x32_bf16(a_h0, b_l0, acc, 0, 0, 0);
            acc = __builtin_amdgcn_mfma_f32_16x16x32_bf16(a_h1, b_l1, acc, 0, 0, 0);
            const float nv = *np;
            const int colW = cm ^ swzW;
            const unsigned slotW = slotW0 + (unsigned)(cm >> 6);
            float* wp = wrow + colW;
            #pragma unroll
            for (int r = 0; r < 4; ++r) {
                float dv = nv - 2.f*acc[r];
                unsigned key = (__float_as_uint(dv) & ~63u) | slotW;
                wp[r*512] = __uint_as_float(key);
            }
            bp_h += 1024; bp_l += 1024; np += 16; cm += 16;
        }
        __syncthreads();
        // scan this ck's 8 values: one sorted group of 8, merged into sm
        {
            float g0 = rrow[0*64], g1 = rrow[1*64], g2 = rrow[2*64], g3 = rrow[3*64];
            float g4 = rrow[4*64], g5 = rrow[5*64], g6 = rrow[6*64], g7 = rrow[7*64];
            SORT8_(g0,g1,g2,g3,g4,g5,g6,g7)
            MERGE8_(g0,g1,g2,g3,g4,g5,g6,g7)
        }
    }

    int mywin = 0;
    #pragma unroll 1
    for (int sr = 0; sr < 3; ++sr) {
        // butterfly all-reduce: global sorted top-8 of the union of all lanes' lists
        float a0 = sm0, a1 = sm1, a2 = sm2, a3 = sm3, a4 = sm4, a5 = sm5, a6 = sm6, a7 = sm7;
        #pragma unroll
        for (int off = 32; off; off >>= 1) {
            float b0 = __shfl_xor(a0, off), b1 = __shfl_xor(a1, off);
            float b2 = __shfl_xor(a2, off), b3 = __shfl_xor(a3, off);
            float b4 = __shfl_xor(a4, off), b5 = __shfl_xor(a5, off);
            float b6 = __shfl_xor(a6, off), b7 = __shfl_xor(a7, off);
            float c0 = fminf(a0, b7), c1 = fminf(a1, b6), c2 = fminf(a2, b5), c3 = fminf(a3, b4);
            float c4 = fminf(a4, b3), c5 = fminf(a5, b2), c6 = fminf(a6, b1), c7 = fminf(a7, b0);
            float u;
            u = fminf(c0, c4); c4 = fmaxf(c0, c4); c0 = u;
            u = fminf(c1, c5); c5 = fmaxf(c1, c5); c1 = u;
            u = fminf(c2, c6); c6 = fmaxf(c2, c6); c2 = u;
            u = fminf(c3, c7); c7 = fmaxf(c3, c7); c3 = u;
            u = fminf(c0, c2); c2 = fmaxf(c0, c2); c0 = u;
            u = fminf(c1, c3); c3 = fmaxf(c1, c3); c1 = u;
            u = fminf(c4, c6); c6 = fmaxf(c4, c6); c4 = u;
            u = fminf(c5, c7); c7 = fmaxf(c5, c7); c5 = u;
            u = fminf(c0, c1); c1 = fmaxf(c0, c1); c0 = u;
            u = fminf(c2, c3); c3 = fmaxf(c2, c3); c2 = u;
            u = fminf(c4, c5); c5 = fmaxf(c4, c5); c4 = u;
            u = fminf(c6, c7); c7 = fmaxf(c6, c7); c6 = u;
            a0 = c0; a1 = c1; a2 = c2; a3 = c3; a4 = c4; a5 = c5; a6 = c6; a7 = c7;
        }
        // extract the 8 winners in ascending order (set semantics; min-lane on ties)
        #define POPW(AW, WIDX)                                                              \
        {                                                                                   \
            const unsigned long long bal = __ballot(sm0 == (AW));                           \
            const int owner = (int)__ffsll(bal) - 1;                                        \
            if (L == sr*8 + (WIDX))                                                         \
                mywin = (int)(((__float_as_uint(AW) & 63u) << 6) | (unsigned)owner);        \
            if (L == owner) {                                                               \
                sm0 = sm1; sm1 = sm2; sm2 = sm3; sm3 = sm4;                                 \
                sm4 = sm5; sm5 = sm6; sm6 = sm7; sm7 = MX;                                  \
            }                                                                               \
        }
        POPW(a0, 0) POPW(a1, 1) POPW(a2, 2) POPW(a3, 3)
        POPW(a4, 4) POPW(a5, 5) POPW(a6, 6) POPW(a7, 7)
        #undef POPW
    }
    if (L < KS_) idx24[((size_t)b*N_ + q0 + w)*KS_ + L] = mywin;
}

// ---------------------------------------------------------------- exact fp32 rescore of the KS_ candidates
// R11: d matches the reference formula exactly.  R13: two winners per round.
// Exact: every lane holds ONE always-valid candidate; indices unique.
__global__ __launch_bounds__(256) void rescore_kernel(const float* __restrict__ x1, const float* __restrict__ nrm,
                                                      const int* __restrict__ idx24, int* __restrict__ idxout)
{
    const int t = threadIdx.x, w = t >> 6, L = t & 63;
    const int p = blockIdx.x*4 + w;
    const int bbase = p & ~(N_-1);
    const float MX = 3.4e38f;
    float dv = MX; int di = 0x7fffffff;
    if (L < KS_) {
        const int ci = idx24[(size_t)p*KS_ + L];
        const float4* qr = (const float4*)(x1 + (size_t)p*64);
        const float4* cr = (const float4*)(x1 + (size_t)(bbase + ci)*64);
        float dot = 0.f;
        #pragma unroll
        for (int i = 0; i < 16; ++i) {
            float4 a = qr[i], bx = cr[i];
            dot += a.x*bx.x + a.y*bx.y + a.z*bx.z + a.w*bx.w;
        }
        dv = __fsub_rn(__fadd_rn(nrm[p], nrm[bbase + ci]), 2.f*dot);
        di = ci;
    }
    int myfin = 0;
    #pragma unroll 1
    for (int r = 0; r < K_/2; ++r) {
        float v1 = dv; int g1 = di;
        float v2 = MX; int g2 = 0x7fffffff;
        #pragma unroll
        for (int off = 32; off; off >>= 1) {
            float ov1 = __shfl_xor(v1, off); int og1 = __shfl_xor(g1, off);
            float ov2 = __shfl_xor(v2, off); int og2 = __shfl_xor(g2, off);
            bool c1 = (ov1 < v1) || (ov1 == v1 && og1 < g1);
            float hv = c1 ? v1 : ov1; int hg = c1 ? g1 : og1;
            v1 = c1 ? ov1 : v1;       g1 = c1 ? og1 : g1;
            bool c2 = (ov2 < v2) || (ov2 == v2 && og2 < g2);
            float l2v = c2 ? ov2 : v2; int l2g = c2 ? og2 : g2;
            bool c3 = (l2v < hv) || (l2v == hv && l2g < hg);
            v2 = c3 ? l2v : hv;  g2 = c3 ? l2g : hg;
        }
        if (L == 2*r)   myfin = g1;
        if (L == 2*r+1) myfin = g2;
        if (di == g1 || di == g2) dv = MX;
    }
    if (L < K_) idxout[(size_t)p*K_ + L] = myfin;
}

// ---------------------------------------------------------------- P/Q precompute
__global__ __launch_bounds__(256) void pq1_kernel(const float* __restrict__ x, const float* __restrict__ W,
                                                  const float* __restrict__ b1,
                                                  float* __restrict__ P, float* __restrict__ Q)
{
    __shared__ float wd[256], wb[256];
    const int t = threadIdx.x;
    wd[t] = W[t] - W[256 + t];
    wb[t] = W[256 + t];
    __syncthreads();
    const int p = blockIdx.x*4 + (t >> 6), c = t & 63;
    const float4 xv = ((const float4*)x)[p];
    float Pv = b1[c] + xv.x*wd[c] + xv.y*wd[64+c] + xv.z*wd[128+c] + xv.w*wd[192+c];
    float Qv =         xv.x*wb[c] + xv.y*wb[64+c] + xv.z*wb[128+c] + xv.w*wb[192+c];
    P[p*64 + c] = Pv;
    Q[p*64 + c] = Qv;
}

__global__ __launch_bounds__(256) void pq2_kernel(const float* __restrict__ x1, const float* __restrict__ W,
                                                  const float* __restrict__ b1,
                                                  float* __restrict__ P, float* __restrict__ Q)
{
    __shared__ float wd[64*128], wb[64*128];
    const int t = threadIdx.x;
    for (int e = t; e < 8192; e += 256) {
        float wt = W[e], wbo = W[8192 + e];
        wd[e] = wt - wbo; wb[e] = wbo;
    }
    __syncthreads();
    const int pl = t >> 7, c = t & 127;
    const float b1v = b1[c];
    for (int p0 = blockIdx.x*2; p0 < BN_; p0 += gridDim.x*2) {
        const int p = p0 + pl;
        float Pv = b1v, Qv = 0.f;
        const float* xrow = x1 + p*64;
        #pragma unroll 8
        for (int k = 0; k < 64; ++k) {
            float xv = xrow[k];
            Pv += xv * wd[k*128 + c];
            Qv += xv * wb[k*128 + c];
        }
        P[p*128 + c] = Pv;
        Q[p*128 + c] = Qv;
    }
}

// ---------------------------------------------------------------- layer-1 BN stats (fp64 per-block partials)
template<int HO>
__global__ __launch_bounds__(256) void stats_l1_kernel(const float* __restrict__ P, const float* __restrict__ Q,
                                                       const int* __restrict__ idx, double* __restrict__ partOut)
{
    constexpr int G = 256/HO;
    __shared__ double red[256], red2[256];
    const int t = threadIdx.x, c = t % HO, g = t / HO;
    double s = 0., s2 = 0.;
    for (int p = blockIdx.x; p < BN_; p += gridDim.x) {
        const float Pv = P[p*HO + c];
        const int bbase = p & ~(N_-1);
        for (int j = g; j < K_; j += G) {
            int m = idx[p*K_ + j];
            float z = Pv + Q[(bbase + m)*HO + c];
            double zd = (double)z;
            s += zd; s2 += zd*zd;
        }
    }
    red[t] = s; red2[t] = s2;
    __syncthreads();
    if (t < HO) {
        double a = red[t], a2 = red2[t];
        #pragma unroll
        for (int q = 1; q < G; ++q) { a += red[q*HO + t]; a2 += red2[q*HO + t]; }
        partOut[(size_t)blockIdx.x*(2*HO) + t] = a;
        partOut[(size_t)blockIdx.x*(2*HO) + HO + t] = a2;
    }
}

// ---------------------------------------------------------------- EdgeConv layer-2, exact fp32 (conv1:
// its output feeds kNN2, which is flip-sensitive to ~1e-4 feature perturbation).
// R11: BN applied in the reference's elementwise op order (((z-m)*rstd)*g+be,
// separately rounded) — the folded z*ac+bc form differed by 1-2 ULP on x1 features.
template<int HO>
__global__ __launch_bounds__(256) void conv_l2_kernel(
    const float* __restrict__ P, const float* __restrict__ Q, const int* __restrict__ idx,
    const float* __restrict__ st1, const float* __restrict__ g1, const float* __restrict__ be1,
    const float* __restrict__ w2, const float* __restrict__ b2,
    float* __restrict__ zmax, float* __restrict__ zmin, double* __restrict__ partOut)
{
    __shared__ float w2s[HO*64];
    __shared__ float h1s[K_*HO];
    __shared__ float redA[256], redB[256];
    __shared__ double redD[256], redD2[256];
    const int t = threadIdx.x;
    const int cy = blockIdx.y;
    for (int e = t; e < HO*64; e += 256) {
        int c = e >> 6, cl = e & 63;
        w2s[e] = w2[c*HO + cy*64 + cl];
    }
    const int cA = t % HO;
    const float mA = st1[2*HO + cA], rA = st1[3*HO + cA];
    const float gA = g1[cA], beA = be1[cA];
    const int c2l = t & 63, jh = t >> 6;
    const float b2v = b2[cy*64 + c2l];
    double ssum = 0., ssq = 0.;
    for (int p = blockIdx.x; p < BN_; p += gridDim.x) {
        __syncthreads();
        const int bbase = p & ~(N_-1);
        const float Pv = P[p*HO + cA];
        for (int e = t; e < K_*HO; e += 256) {
            int j = e / HO;
            int m = idx[p*K_ + j];
            float z = Pv + Q[(bbase + m)*HO + cA];
            float bn = __fadd_rn(__fmul_rn(__fmul_rn(__fsub_rn(z, mA), rA), gA), beA);
            h1s[e] = fmaxf(bn, 0.f);
        }
        __syncthreads();
        float acc[5];
        #pragma unroll
        for (int q = 0; q < 5; ++q) acc[q] = b2v;
        for (int c = 0; c < HO; ++c) {
            float wv = w2s[c*64 + c2l];
            #pragma unroll
            for (int q = 0; q < 5; ++q)
                acc[q] += h1s[(jh + q*4)*HO + c] * wv;
        }
        float mx = acc[0], mn = acc[0];
        #pragma unroll
        for (int q = 0; q < 5; ++q) {
            mx = fmaxf(mx, acc[q]); mn = fminf(mn, acc[q]);
            double ad = (double)acc[q];
            ssum += ad; ssq += ad*ad;
        }
        redA[t] = mx; redB[t] = mn;
        __syncthreads();
        if (t < 64) {
            float M = redA[t], Mn = redB[t];
            #pragma unroll
            for (int g = 1; g < 4; ++g) { M = fmaxf(M, redA[g*64 + t]); Mn = fminf(Mn, redB[g*64 + t]); }
            zmax[p*HO + cy*64 + t] = M;
            zmin[p*HO + cy*64 + t] = Mn;
        }
    }
    __syncthreads();
    redD[t] = ssum; redD2[t] = ssq;
    __syncthreads();
    if (t < 64) {
        double s = redD[t], s2 = redD2[t];
        #pragma unroll
        for (int g = 1; g < 4; ++g) { s += redD[g*64 + t]; s2 += redD2[g*64 + t]; }
        partOut[(size_t)blockIdx.x*(2*HO) + cy*64 + t] = s;
        partOut[(size_t)blockIdx.x*(2*HO) + HO + cy*64 + t] = s2;
    }
}

// ---------------------------------------------------------------- W2^T split-bf16 prep
__global__ __launch_bounds__(256) void prep_w2t_kernel(const float* __restrict__ W,
                                                       unsigned short* __restrict__ wh,
                                                       unsigned short* __restrict__ wl, int HO)
{
    const int e = blockIdx.x*256 + threadIdx.x;   // e = k*HO + c
    const int k = e / HO, c = e % HO;
    const float v = W[e];
    unsigned short h = f2bf(v);
    float hf = __uint_as_float((unsigned)h << 16);
    wh[c*HO + k] = h;
    wl[c*HO + k] = f2bf(v - hf);
}

// ---------------------------------------------------------------- EdgeConv layer-2 via MFMA (split-bf16)
// conv2 only: output feeds the classifier (value-continuous), bf16-split safe.
template<int HO>
__global__ __launch_bounds__(256) void conv_l2_mfma_kernel(
    const float* __restrict__ P, const float* __restrict__ Q, const int* __restrict__ idx,
    const float* __restrict__ st1, const float* __restrict__ g1, const float* __restrict__ be1,
    const unsigned short* __restrict__ w2h, const unsigned short* __restrict__ w2l,
    const float* __restrict__ b2,
    float* __restrict__ zmax, float* __restrict__ zmin, double* __restrict__ partOut)
{
    constexpr int HOP = HO + 8;
    constexpr int CDP = HO + 1;
    constexpr int CTW = HO / 64;
    constexpr int KSn = HO / 32;
    constexpr int HSH = (HO == 128) ? 7 : 6;
    __shared__ __align__(16) short hs[2*80*HOP];
    __shared__ int sidx[80];
    float* cd = (float*)hs;

    const int t = threadIdx.x, w = t >> 6, L = t & 63;
    const int m16 = L & 15, q4 = L >> 4;

    const int kT = t & (HO - 1);
    const float ac = st1[3*HO + kT] * g1[kT];
    const float bc = be1[kT] - st1[2*HO + kT] * ac;

    bf16x8 Bh[CTW][KSn], Bl[CTW][KSn];
    #pragma unroll
    for (int ctl = 0; ctl < CTW; ++ctl)
        #pragma unroll
        for (int ks = 0; ks < KSn; ++ks) {
            const int c  = w*16*CTW + ctl*16 + m16;
            const int k0 = ks*32 + q4*8;
            Bh[ctl][ks] = *(const bf16x8*)(w2h + c*HO + k0);
            Bl[ctl][ks] = *(const bf16x8*)(w2l + c*HO + k0);
        }

    const float b2c = (t < HO) ? b2[t] : 0.f;
    double ssum = 0., ssq = 0.;

    for (int p0 = blockIdx.x*4; p0 < BN_; p0 += gridDim.x*4) {
        const int bbase = p0 & ~(N_-1);
        __syncthreads();
        if (t < 80) sidx[t] = idx[p0*K_ + t];
        __syncthreads();
        for (int e = t; e < 80*HO; e += 256) {
            const int r  = e >> HSH;
            const int pl = (r*3277) >> 16;     // r/20 for r<80
            const int mI = sidx[r];
            float z = P[(size_t)(p0+pl)*HO + kT] + Q[(size_t)(bbase+mI)*HO + kT];
            float h = fmaxf(z*ac + bc, 0.f);
            unsigned short hh = f2bf(h);
            float hf = __uint_as_float((unsigned)hh << 16);
            unsigned short hl = f2bf(h - hf);
            hs[r*HOP + kT] = (short)hh;
            hs[80*HOP + r*HOP + kT] = (short)hl;
        }
        __syncthreads();
        f32x4 acc[5][CTW];
        #pragma unroll
        for (int rt = 0; rt < 5; ++rt)
            #pragma unroll
            for (int ctl = 0; ctl < CTW; ++ctl)
                acc[rt][ctl] = (f32x4){0.f, 0.f, 0.f, 0.f};
        #pragma unroll
        for (int rt = 0; rt < 5; ++rt)
            #pragma unroll
            for (int ks = 0; ks < KSn; ++ks) {
                const short* ap = hs + (rt*16 + m16)*HOP + ks*32 + q4*8;
                bf16x8 Ah = *(const bf16x8*)ap;
                bf16x8 Al = *(const bf16x8*)(ap + 80*HOP);
                #pragma unroll
                for (int ctl = 0; ctl < CTW; ++ctl) {
                    acc[rt][ctl] = __builtin_amdgcn_mfma_f32_16x16x32_bf16(Ah, Bh[ctl][ks], acc[rt][ctl], 0, 0, 0);
                    acc[rt][ctl] = __builtin_amdgcn_mfma_f32_16x16x32_bf16(Al, Bh[ctl][ks], acc[rt][ctl], 0, 0, 0);
                    acc[rt][ctl] = __builtin_amdgcn_mfma_f32_16x16x32_bf16(Ah, Bl[ctl][ks], acc[rt][ctl], 0, 0, 0);
                }
            }
        __syncthreads();
        #pragma unroll
        for (int rt = 0; rt < 5; ++rt)
            #pragma unroll
            for (int ctl = 0; ctl < CTW; ++ctl) {
                const int col = w*16*CTW + ctl*16 + m16;
                #pragma unroll
                for (int ri = 0; ri < 4; ++ri) {
                    const int row = rt*16 + q4*4 + ri;
                    cd[row*CDP + col] = acc[rt][ctl][ri];
                }
            }
        __syncthreads();
        if (t < HO) {
            #pragma unroll
            for (int pl = 0; pl < 4; ++pl) {
                float mx = -3.4e38f, mn = 3.4e38f;
                #pragma unroll
                for (int j = 0; j < K_; ++j) {
                    float v = cd[(pl*20 + j)*CDP + t] + b2c;
                    mx = fmaxf(mx, v); mn = fminf(mn, v);
                    double vd = (double)v;
                    ssum += vd; ssq += vd*vd;
                }
                zmax[(size_t)(p0+pl)*HO + t] = mx;
                zmin[(size_t)(p0+pl)*HO + t] = mn;
            }
        }
    }
    if (t < HO) {
        partOut[(size_t)blockIdx.x*(2*HO) + t] = ssum;
        partOut[(size_t)blockIdx.x*(2*HO) + HO + t] = ssq;
    }
}

// max_j relu(BN(z)) = relu(BN(max_j z)) for gamma>=0, min for gamma<0.
// R11: reference elementwise op order for the x1b-producing instance.
template<int HO>
__global__ __launch_bounds__(256) void conv_fin_kernel(
    const float* __restrict__ zmax, const float* __restrict__ zmin,
    const float* __restrict__ st2, const float* __restrict__ g2, const float* __restrict__ be2,
    float* __restrict__ out)
{
    int e = blockIdx.x*256 + threadIdx.x;
    int c = e & (HO-1);
    float g = g2[c];
    float sel = (g >= 0.f) ? zmax[e] : zmin[e];
    float bn = __fadd_rn(__fmul_rn(__fmul_rn(__fsub_rn(sel, st2[2*HO + c]), st2[3*HO + c]), g), be2[c]);
    out[e] = fmaxf(bn, 0.f);
}

// ---------------------------------------------------------------- classifier
__global__ __launch_bounds__(256) void cls1_kernel(
    const float* __restrict__ x1, const float* __restrict__ x2f,
    const float* __restrict__ W, const float* __restrict__ b1,
    float* __restrict__ z, double* __restrict__ partOut)
{
    __shared__ float ws[192*64];
    __shared__ float xr[4*192];
    __shared__ double red[256], red2[256];
    const int t = threadIdx.x, cy = blockIdx.y;
    for (int e = t; e < 192*64; e += 256) {
        int c = e >> 6, cl = e & 63;
        ws[e] = W[c*128 + cy*64 + cl];
    }
    const int pl = t >> 6, c2l = t & 63;
    const float b1v = b1[cy*64 + c2l];
    double ssum = 0., ssq = 0.;
    for (int p0 = blockIdx.x*4; p0 < BN_; p0 += gridDim.x*4) {
        __syncthreads();
        for (int l = t; l < 4*192; l += 256) {
            int pp = l / 192, cc = l % 192;
            xr[l] = (cc < 64) ? x1[(p0+pp)*64 + cc] : x2f[(p0+pp)*128 + cc - 64];
        }
        __syncthreads();
        float acc = b1v;
        const float* xx = xr + pl*192;
        #pragma unroll 8
        for (int c = 0; c < 192; ++c) acc += xx[c] * ws[c*64 + c2l];
        z[(p0+pl)*128 + cy*64 + c2l] = acc;
        double ad = (double)acc;
        ssum += ad; ssq += ad*ad;
    }
    __syncthreads();
    red[t] = ssum; red2[t] = ssq;
    __syncthreads();
    if (t < 64) {
        double s = red[t], s2 = red2[t];
        #pragma unroll
        for (int g = 1; g < 4; ++g) { s += red[g*64 + t]; s2 += red2[g*64 + t]; }
        // partial row layout [512][256]: (sum ch0..127, sumsq ch0..127); the two
        // cy-planes of the same blockIdx.x fill disjoint 64-ch ranges.
        partOut[(size_t)blockIdx.x*256 + cy*64 + t] = s;
        partOut[(size_t)blockIdx.x*256 + 128 + cy*64 + t] = s2;
    }
}

__global__ __launch_bounds__(256) void cls_fin_kernel(
    const float* __restrict__ z, const float* __restrict__ st,
    const float* __restrict__ g, const float* __restrict__ be,
    const float* __restrict__ w2, const float* __restrict__ b2,
    float* __restrict__ out)
{
    const int t = threadIdx.x, w = t >> 6, L = t & 63;
    const int p = blockIdx.x*4 + w;
    float s = 0.f;
    #pragma unroll
    for (int h = 0; h < 2; ++h) {
        int c = L + h*64;
        float v = (z[p*128 + c] - st[256 + c]) * st[384 + c] * g[c] + be[c];
        s += fmaxf(v, 0.f) * w2[c];
    }
    #pragma unroll
    for (int off = 32; off; off >>= 1) s += __shfl_xor(s, off);
    if (L == 0) out[p] = s + b2[0];
}

// ---------------------------------------------------------------- launch
extern "C" void kernel_launch(void* const* d_in, const int* in_sizes, int n_in,
                              void* d_out, int out_size, void* d_ws, size_t ws_size,
                              hipStream_t stream)
{
    const float* x      = (const float*)d_in[0];
    const float* c1_w1  = (const float*)d_in[1];
    const float* c1_b1  = (const float*)d_in[2];
    const float* c1_g1  = (const float*)d_in[3];
    const float* c1_be1 = (const float*)d_in[4];
    const float* c1_w2  = (const float*)d_in[5];
    const float* c1_b2  = (const float*)d_in[6];
    const float* c1_g2  = (const float*)d_in[7];
    const float* c1_be2 = (const float*)d_in[8];
    const float* c2_w1  = (const float*)d_in[9];
    const float* c2_b1  = (const float*)d_in[10];
    const float* c2_g1  = (const float*)d_in[11];
    const float* c2_be1 = (const float*)d_in[12];
    const float* c2_w2  = (const float*)d_in[13];
    const float* c2_b2  = (const float*)d_in[14];
    const float* c2_g2  = (const float*)d_in[15];
    const float* c2_be2 = (const float*)d_in[16];
    const float* cls_w1 = (const float*)d_in[17];
    const float* cls_b1 = (const float*)d_in[18];
    const float* cls_g1 = (const float*)d_in[19];
    const float* cls_be1= (const float*)d_in[20];
    const float* cls_w2 = (const float*)d_in[21];
    const float* cls_b2 = (const float*)d_in[22];
    (void)in_sizes; (void)n_in; (void)out_size; (void)ws_size;

    char* ws = (char*)d_ws;
    size_t off = 0;
    auto alloc = [&](size_t bytes) { char* p = ws + off; off += (bytes + 255) & ~255ull; return p; };
    float* A    = (float*)alloc((size_t)16<<20);   // P1 -> P2 -> zcls
    float* Bq   = (float*)alloc((size_t)16<<20);   // Q1 -> Q2 -> cls partials
    float* zmax = (float*)alloc((size_t)16<<20);   // also hosts Xh/Xl between conv1 and conv2
    float* zmin = (float*)alloc((size_t)16<<20);
    float* x1b  = (float*)alloc((size_t)8<<20);
    float* x2b  = (float*)alloc((size_t)16<<20);   // also hosts idx24 + stats partials (dead windows)
    int*   idx  = (int*)  alloc((size_t)BN_*K_*4); // idx1 -> idx2
    float* nrm  = (float*)alloc((size_t)BN_*4);
    float* st   = (float*)alloc((size_t)5*512*4);
    unsigned short* w2th = (unsigned short*)alloc((size_t)128*128*2);  // W2^T hi
    unsigned short* w2tl = (unsigned short*)alloc((size_t)128*128*2);  // W2^T lo
    float *st0 = st, *st1 = st+512, *st2 = st+1024, *st3 = st+1536, *st4 = st+2048;

    unsigned short* Xh = (unsigned short*)zmax;                       // 4 MB (tiled layout, R17)
    unsigned short* Xl = (unsigned short*)((char*)zmax + (4<<20));    // 4 MB
    int* idx24 = (int*)x2b;
    double* part  = (double*)x2b;  // fp64 stats partials (max 4 MB): free during both conv phases
    double* partC = (double*)Bq;   // cls stats partials (1 MB): Q2 dead after conv_l2_mfma

    // ---- EdgeConv 1 (exact fp32 conv: x1b feeds flip-sensitive kNN2)
    knn4_kernel<<<dim3(N_/16, B_), 1024, 0, stream>>>(x, idx);
    pq1_kernel<<<BN_/4, 256, 0, stream>>>(x, c1_w1, c1_b1, A, Bq);
    stats_l1_kernel<64><<<2048, 256, 0, stream>>>(A, Bq, idx, part);
    finalize_parts_kernel<<<64, 256, 0, stream>>>(part, 2048, 64, 1.0/655360.0, st0);
    conv_l2_kernel<64><<<dim3(2048,1), 256, 0, stream>>>(A, Bq, idx, st0, c1_g1, c1_be1, c1_w2, c1_b2, zmax, zmin, part);
    finalize_parts_kernel<<<64, 256, 0, stream>>>(part, 2048, 64, 1.0/655360.0, st1);
    conv_fin_kernel<64><<<BN_*64/256, 256, 0, stream>>>(zmax, zmin, st1, c1_g2, c1_be2, x1b);

    // ---- EdgeConv 2 (MFMA conv: x2b only feeds classifier)
    nrm64_kernel<<<BN_/4, 256, 0, stream>>>(x1b, nrm);
    prep64t_kernel<<<BN_/32, 256, 0, stream>>>(x1b, Xh, Xl);
    knn64v4_kernel<<<dim3(N_/16, B_), 1024, 0, stream>>>(Xh, Xl, nrm, idx24);
    rescore_kernel<<<BN_/4, 256, 0, stream>>>(x1b, nrm, idx24, idx);
    pq2_kernel<<<1024, 256, 0, stream>>>(x1b, c2_w1, c2_b1, A, Bq);
    stats_l1_kernel<128><<<2048, 256, 0, stream>>>(A, Bq, idx, part);
    finalize_parts_kernel<<<128, 256, 0, stream>>>(part, 2048, 128, 1.0/655360.0, st2);
    prep_w2t_kernel<<<128*128/256, 256, 0, stream>>>(c2_w2, w2th, w2tl, 128);
    conv_l2_mfma_kernel<128><<<2048, 256, 0, stream>>>(A, Bq, idx, st2, c2_g1, c2_be1, w2th, w2tl, c2_b2, zmax, zmin, part);
    finalize_parts_kernel<<<128, 256, 0, stream>>>(part, 2048, 128, 1.0/655360.0, st3);
    conv_fin_kernel<128><<<BN_*128/256, 256, 0, stream>>>(zmax, zmin, st3, c2_g2, c2_be2, x2b);

    // ---- classifier
    cls1_kernel<<<dim3(512,2), 256, 0, stream>>>(x1b, x2b, cls_w1, cls_b1, A, partC);
    finalize_parts_kernel<<<128, 256, 0, stream>>>(partC, 512, 128, 1.0/32768.0, st4);
    cls_fin_kernel<<<BN_/4, 256, 0, stream>>>(A, st4, cls_g1, cls_be1, cls_w2, cls_b2, (float*)d_out);
}

// Round 12
// 1244.534 us; speedup vs baseline: 1.2316x; 1.0006x over previous
//
#include <hip/hip_runtime.h>
#include <math.h>

#define B_ 8
#define N_ 4096
#define K_ 20
#define KS_ 24          // approx-select width; exact rescore trims to K_ (R3-validated margin)
#define BN_ (B_*N_)

typedef __attribute__((ext_vector_type(8))) short bf16x8;
typedef __attribute__((ext_vector_type(4))) float f32x4;

// ---------------------------------------------------------------- BN stats finalize (deterministic, fp64)
// R10: float atomicAdd stats were order-nondeterministic across graph replays ->
// kNN2 boundary flip -> post-timing divergence.  R11: the deterministic fp32
// order landed on the WRONG side of a ~1-ULP distance tie (absmax 0.1177).
// All stats now accumulate in DOUBLE (partials + reduce + mean/var/rstd), so our
// stats are ~exact; the x1b-feeding BN applies the reference's elementwise op
// order; rescore uses the reference's full d formula.  DO NOT reintroduce
// atomicAdd or fold these back into fp32/FMA on the conv1 path.
// part layout: [nb][2*H] doubles (sum(H), sumsq(H) per block row).
__global__ __launch_bounds__(256) void finalize_parts_kernel(
    const double* __restrict__ part, int nb, int H, double invCount, float* __restrict__ st)
{
    __shared__ double red[256], red2[256];
    const int c = blockIdx.x, t = threadIdx.x;
    double s = 0., s2 = 0.;
    for (int b = t; b < nb; b += 256) {
        s  += part[(size_t)b*2*H + c];
        s2 += part[(size_t)b*2*H + H + c];
    }
    red[t] = s; red2[t] = s2;
    __syncthreads();
    #pragma unroll
    for (int off = 128; off; off >>= 1) {
        if (t < off) { red[t] += red[t+off]; red2[t] += red2[t+off]; }
        __syncthreads();
    }
    if (t == 0) {
        double mean = red[0] * invCount;
        double var  = fmax(red2[0] * invCount - mean * mean, 0.);
        st[2*H + c] = (float)mean;
        st[3*H + c] = (float)(1.0 / sqrt(var + 1e-5));
    }
}

// ---------------------------------------------------------------- kNN, C=4
// R7-validated (value, candidate-index) lexicographic argmin — matches jax
// top_k tie-break; reference-defining (no rescore guard) -> selection EXACT.
// R15: rolled loops (L1I); d[64] eliminated via fused compute+insert; rescans
// recompute dists (bit-identical).  DO NOT replace with DPP (R9).
// R21 ERRATA: R20's nt[] |c|^2 precompute (+unroll 4) changed FMA contraction
// of the distance -> flipped a reference top_k tie -> absmax 0.164 FAIL.
// knn4's distance arithmetic is FROZEN in exactly this form.  DO NOT hoist,
// precompute, or re-unroll anything in the scan/rescan bodies.
__global__ __launch_bounds__(1024, 8) void knn4_kernel(const float* __restrict__ x, int* __restrict__ idxout)
{
    __shared__ float4 xt[N_];   // 64 KB
    const int b = blockIdx.y;
    const int t = threadIdx.x;
    const float4* xg = (const float4*)x + b*N_;
    for (int e = t; e < N_; e += 1024) xt[e] = xg[e];
    __syncthreads();
    const int w = t >> 6, L = t & 63;
    const int n = blockIdx.x*16 + w;
    const float4 q = xt[n];
    const float MX = 3.4e38f;
    float m1 = MX, m2 = MX, m3 = MX; int i1 = 0, i2 = 0, i3 = 0;
    #pragma unroll 1
    for (int j = 0; j < 64; ++j) {
        float4 vv = xt[(j<<6) | L];
        float nn = vv.x*vv.x + vv.y*vv.y + vv.z*vv.z + vv.w*vv.w;
        float dp = q.x*vv.x + q.y*vv.y + q.z*vv.z + q.w*vv.w;
        float v = nn - 2.f*dp;   // |xn|^2 dropped: rank-equivalent
        bool c1 = v < m1, c2 = v < m2, c3 = v < m3;
        m3 = c2 ? m2 : (c3 ? v : m3);
        i3 = c2 ? i2 : (c3 ? j : i3);
        m2 = c1 ? m1 : (c2 ? v : m2);
        i2 = c1 ? i1 : (c2 ? j : i2);
        m1 = c1 ? v : m1;
        i1 = c1 ? j : i1;
    }
    unsigned long long used = 0;
    int mywin = 0;
    #pragma unroll 1
    for (int r = 0; r < K_; ++r) {
        float bv = m1; int bg = (i1<<6) | L;
        #pragma unroll
        for (int off = 32; off; off >>= 1) {
            float ov = __shfl_xor(bv, off);
            int   og = __shfl_xor(bg, off);
            bool tk = (ov < bv) || (ov == bv && og < bg);
            bv = tk ? ov : bv; bg = tk ? og : bg;
        }
        if (L == r) mywin = bg;
        if (L == (bg & 63)) {
            used |= 1ull << i1;
            m1 = m2; i1 = i2; m2 = m3; i2 = i3; m3 = MX;
            if (m1 == MX) {
                m2 = MX; m3 = MX; i1 = 0; i2 = 0; i3 = 0;
                #pragma unroll 1
                for (int j = 0; j < 64; ++j) {
                    float4 vv = xt[(j<<6) | L];
                    float nn = vv.x*vv.x + vv.y*vv.y + vv.z*vv.z + vv.w*vv.w;
                    float dp = q.x*vv.x + q.y*vv.y + q.z*vv.z + q.w*vv.w;
                    float dj = nn - 2.f*dp;
                    float v = ((used >> j) & 1ull) ? MX : dj;
                    bool c1 = v < m1, c2 = v < m2, c3 = v < m3;
                    m3 = c2 ? m2 : (c3 ? v : m3);
                    i3 = c2 ? i2 : (c3 ? j : i3);
                    m2 = c1 ? m1 : (c2 ? v : m2);
                    i2 = c1 ? i1 : (c2 ? j : i2);
                    m1 = c1 ? v : m1;
                    i1 = c1 ? j : i1;
                }
            }
        }
    }
    if (L < K_) idxout[(b*N_ + n)*K_ + L] = mywin;
}

// ---------------------------------------------------------------- fp32 -> bf16 RNE
static __device__ inline unsigned short f2bf(float f)
{
    unsigned u = __float_as_uint(f);
    unsigned r = (u + 0x7fffu + ((u >> 16) & 1u)) >> 16;   // RNE
    return (unsigned short)r;
}

// ---------------------------------------------------------------- fused x1 norms + split-bf16 tiled prep (R21)
// nrm: bit-identical to the R2-validated 64-lane butterfly (R11-frozen order —
// feeds the flip-sensitive exact rescore).  Xh/Xl: identical f2bf values in the
// R17 tiled layout (addr = (row>>4)*1024 + (ch>>3)*128 + (row&15)*8 + (ch&7));
// only the store pattern differs from the old prep64t (2B stores in 16B runs).
// Fusion saves one full 2MB read pass over x1b + one launch.
__global__ __launch_bounds__(256) void nrmprep_kernel(const float* __restrict__ x,
                                                      unsigned short* __restrict__ Xh,
                                                      unsigned short* __restrict__ Xl,
                                                      float* __restrict__ nrm)
{
    const int t = threadIdx.x, L = t & 63;
    const int row = blockIdx.x*4 + (t >> 6);
    const float v = x[row*64 + L];
    float s = v * v;
    #pragma unroll
    for (int off = 32; off; off >>= 1) s += __shfl_xor(s, off);
    if (L == 0) nrm[row] = s;
    unsigned short h = f2bf(v);
    float hf = __uint_as_float((unsigned)h << 16);
    unsigned short l = f2bf(v - hf);
    const size_t base = (size_t)(row >> 4)*1024 + (size_t)(L >> 3)*128 + (size_t)(row & 15)*8 + (size_t)(L & 7);
    Xh[base] = h;
    Xl[base] = l;
}

// comparator: (x,y) -> (min,max)
#define CE_(x,y) { float _t = fminf(x,y); y = fmaxf(x,y); x = _t; }
// Batcher odd-even sort-8 (19 CE)
#define SORT8_(g0,g1,g2,g3,g4,g5,g6,g7)                                   \
    CE_(g0,g1) CE_(g2,g3) CE_(g4,g5) CE_(g6,g7)                           \
    CE_(g0,g2) CE_(g1,g3) CE_(g4,g6) CE_(g5,g7)                           \
    CE_(g1,g2) CE_(g5,g6)                                                 \
    CE_(g0,g4) CE_(g1,g5) CE_(g2,g6) CE_(g3,g7)                           \
    CE_(g2,g4) CE_(g3,g5)                                                 \
    CE_(g1,g2) CE_(g3,g4) CE_(g5,g6)
// keep lowest-8 (sorted) of two sorted-asc 8-lists: sm = low8(sm, g)
#define MERGE8_(g0,g1,g2,g3,g4,g5,g6,g7)                                  \
    sm0 = fminf(sm0,g7); sm1 = fminf(sm1,g6); sm2 = fminf(sm2,g5);        \
    sm3 = fminf(sm3,g4); sm4 = fminf(sm4,g3); sm5 = fminf(sm5,g2);        \
    sm6 = fminf(sm6,g1); sm7 = fminf(sm7,g0);                             \
    CE_(sm0,sm4) CE_(sm1,sm5) CE_(sm2,sm6) CE_(sm3,sm7)                   \
    CE_(sm0,sm2) CE_(sm1,sm3) CE_(sm4,sm6) CE_(sm5,sm7)                   \
    CE_(sm0,sm1) CE_(sm2,sm3) CE_(sm4,sm5) CE_(sm6,sm7)

// ---------------------------------------------------------------- kNN, C=64 via MFMA (split-bf16 Gram, approx)
// v12 (R19): 32KB dist tile (8 chunks of 512) -> 2 blocks/CU resident;
// SORT8+MERGE8 scan per chunk; slot = ck*8 + (cm>>6); lane residue preserved.
// Selection (R16 bitonic 8-merge butterfly + ballot pops), keys (R12), tiled
// layout (R17), strength-reduced staging (R18), top-8 dropout P~5e-9 (R14).
__global__ __launch_bounds__(1024, 4) void knn64v4_kernel(
    const unsigned short* __restrict__ Xh, const unsigned short* __restrict__ Xl,
    const float* __restrict__ nrm, int* __restrict__ idx24)
{
    __shared__ float dist[16*512];   // 32 KB -> 2 blocks/CU resident
    const int b = blockIdx.y, t = threadIdx.x;
    const int w = t >> 6, L = t & 63;
    const int q0 = blockIdx.x * 16;
    const int m = L & 15, q4 = L >> 4;
    const size_t rowbase = (size_t)b * N_ * 64;
    const int swzW = q4 << 4;         // write-side column XOR (qrow>>2 == q4)
    const int swzR = (w >> 2) << 4;   // read-side column XOR (query row w)
    const int fragoff = q4*128 + m*8; // within-tile fragment offset (shorts)

    // A fragments: tile q0>>4
    const unsigned short* aph = Xh + rowbase + (size_t)(q0 >> 4)*1024 + fragoff;
    const unsigned short* apl = Xl + rowbase + (size_t)(q0 >> 4)*1024 + fragoff;
    const bf16x8 a_h0 = *(const bf16x8*)(aph);
    const bf16x8 a_h1 = *(const bf16x8*)(aph + 512);
    const bf16x8 a_l0 = *(const bf16x8*)(apl);
    const bf16x8 a_l1 = *(const bf16x8*)(apl + 512);

    const float MX = 3.4e38f;
    float sm0 = MX, sm1 = MX, sm2 = MX, sm3 = MX, sm4 = MX, sm5 = MX, sm6 = MX, sm7 = MX;

    float* const wrow = dist + q4*2048;        // q4*4*512
    float* const rrow = dist + w*512 + (L ^ swzR);

    #pragma unroll 1
    for (int ck = 0; ck < 8; ++ck) {
        const unsigned slotW0 = (unsigned)(ck*8);
        // strength-reduced staging pointers for this ck (each wave: 2 sub-tiles)
        const unsigned short* bp_h = Xh + rowbase + (size_t)(ck*32 + w*2)*1024 + fragoff;
        const unsigned short* bp_l = Xl + rowbase + (size_t)(ck*32 + w*2)*1024 + fragoff;
        const float* np = nrm + b*N_ + ck*512 + w*32 + m;
        int cm = w*32 + m;
        __syncthreads();
        #pragma unroll
        for (int tt = 0; tt < 2; ++tt) {
            bf16x8 b_h0 = *(const bf16x8*)(bp_h);
            bf16x8 b_h1 = *(const bf16x8*)(bp_h + 512);
            bf16x8 b_l0 = *(const bf16x8*)(bp_l);
            bf16x8 b_l1 = *(const bf16x8*)(bp_l + 512);
            f32x4 acc = {0.f, 0.f, 0.f, 0.f};
            acc = __builtin_amdgcn_mfma_f32_16x16x32_bf16(a_h0, b_h0, acc, 0, 0, 0);
            acc = __builtin_amdgcn_mfma_f32_16x16x32_bf16(a_h1, b_h1, acc, 0, 0, 0);
            acc = __builtin_amdgcn_mfma_f32_16x16x32_bf16(a_l0, b_h0, acc, 0, 0, 0);
            acc = __builtin_amdgcn_mfma_f32_16x16x32_bf16(a_l1, b_h1, acc, 0, 0, 0);
            acc = __builtin_amdgcn_mfma_f32_16x16x32_bf16(a_h0, b_l0, acc, 0, 0, 0);
            acc = __builtin_amdgcn_mfma_f32_16x16x32_bf16(a_h1, b_l1, acc, 0, 0, 0);
            const float nv = *np;
            const int colW = cm ^ swzW;
            const unsigned slotW = slotW0 + (unsigned)(cm >> 6);
            float* wp = wrow + colW;
            #pragma unroll
            for (int r = 0; r < 4; ++r) {
                float dv = nv - 2.f*acc[r];
                unsigned key = (__float_as_uint(dv) & ~63u) | slotW;
                wp[r*512] = __uint_as_float(key);
            }
            bp_h += 1024; bp_l += 1024; np += 16; cm += 16;
        }
        __syncthreads();
        // scan this ck's 8 values: one sorted group of 8, merged into sm
        {
            float g0 = rrow[0*64], g1 = rrow[1*64], g2 = rrow[2*64], g3 = rrow[3*64];
            float g4 = rrow[4*64], g5 = rrow[5*64], g6 = rrow[6*64], g7 = rrow[7*64];
            SORT8_(g0,g1,g2,g3,g4,g5,g6,g7)
            MERGE8_(g0,g1,g2,g3,g4,g5,g6,g7)
        }
    }

    int mywin = 0;
    #pragma unroll 1
    for (int sr = 0; sr < 3; ++sr) {
        // butterfly all-reduce: global sorted top-8 of the union of all lanes' lists
        float a0 = sm0, a1 = sm1, a2 = sm2, a3 = sm3, a4 = sm4, a5 = sm5, a6 = sm6, a7 = sm7;
        #pragma unroll
        for (int off = 32; off; off >>= 1) {
            float b0 = __shfl_xor(a0, off), b1 = __shfl_xor(a1, off);
            float b2 = __shfl_xor(a2, off), b3 = __shfl_xor(a3, off);
            float b4 = __shfl_xor(a4, off), b5 = __shfl_xor(a5, off);
            float b6 = __shfl_xor(a6, off), b7 = __shfl_xor(a7, off);
            float c0 = fminf(a0, b7), c1 = fminf(a1, b6), c2 = fminf(a2, b5), c3 = fminf(a3, b4);
            float c4 = fminf(a4, b3), c5 = fminf(a5, b2), c6 = fminf(a6, b1), c7 = fminf(a7, b0);
            float u;
            u = fminf(c0, c4); c4 = fmaxf(c0, c4); c0 = u;
            u = fminf(c1, c5); c5 = fmaxf(c1, c5); c1 = u;
            u = fminf(c2, c6); c6 = fmaxf(c2, c6); c2 = u;
            u = fminf(c3, c7); c7 = fmaxf(c3, c7); c3 = u;
            u = fminf(c0, c2); c2 = fmaxf(c0, c2); c0 = u;
            u = fminf(c1, c3); c3 = fmaxf(c1, c3); c1 = u;
            u = fminf(c4, c6); c6 = fmaxf(c4, c6); c4 = u;
            u = fminf(c5, c7); c7 = fmaxf(c5, c7); c5 = u;
            u = fminf(c0, c1); c1 = fmaxf(c0, c1); c0 = u;
            u = fminf(c2, c3); c3 = fmaxf(c2, c3); c2 = u;
            u = fminf(c4, c5); c5 = fmaxf(c4, c5); c4 = u;
            u = fminf(c6, c7); c7 = fmaxf(c6, c7); c6 = u;
            a0 = c0; a1 = c1; a2 = c2; a3 = c3; a4 = c4; a5 = c5; a6 = c6; a7 = c7;
        }
        // extract the 8 winners in ascending order (set semantics; min-lane on ties)
        #define POPW(AW, WIDX)                                                              \
        {                                                                                   \
            const unsigned long long bal = __ballot(sm0 == (AW));                           \
            const int owner = (int)__ffsll(bal) - 1;                                        \
            if (L == sr*8 + (WIDX))                                                         \
                mywin = (int)(((__float_as_uint(AW) & 63u) << 6) | (unsigned)owner);        \
            if (L == owner) {                                                               \
                sm0 = sm1; sm1 = sm2; sm2 = sm3; sm3 = sm4;                                 \
                sm4 = sm5; sm5 = sm6; sm6 = sm7; sm7 = MX;                                  \
            }                                                                               \
        }
        POPW(a0, 0) POPW(a1, 1) POPW(a2, 2) POPW(a3, 3)
        POPW(a4, 4) POPW(a5, 5) POPW(a6, 6) POPW(a7, 7)
        #undef POPW
    }
    if (L < KS_) idx24[((size_t)b*N_ + q0 + w)*KS_ + L] = mywin;
}

// ---------------------------------------------------------------- exact fp32 rescore of the KS_ candidates
// R11: d matches the reference formula exactly.  R13: two winners per round.
// Exact: every lane holds ONE always-valid candidate; indices unique.
__global__ __launch_bounds__(256) void rescore_kernel(const float* __restrict__ x1, const float* __restrict__ nrm,
                                                      const int* __restrict__ idx24, int* __restrict__ idxout)
{
    const int t = threadIdx.x, w = t >> 6, L = t & 63;
    const int p = blockIdx.x*4 + w;
    const int bbase = p & ~(N_-1);
    const float MX = 3.4e38f;
    float dv = MX; int di = 0x7fffffff;
    if (L < KS_) {
        const int ci = idx24[(size_t)p*KS_ + L];
        const float4* qr = (const float4*)(x1 + (size_t)p*64);
        const float4* cr = (const float4*)(x1 + (size_t)(bbase + ci)*64);
        float dot = 0.f;
        #pragma unroll
        for (int i = 0; i < 16; ++i) {
            float4 a = qr[i], bx = cr[i];
            dot += a.x*bx.x + a.y*bx.y + a.z*bx.z + a.w*bx.w;
        }
        dv = __fsub_rn(__fadd_rn(nrm[p], nrm[bbase + ci]), 2.f*dot);
        di = ci;
    }
    int myfin = 0;
    #pragma unroll 1
    for (int r = 0; r < K_/2; ++r) {
        float v1 = dv; int g1 = di;
        float v2 = MX; int g2 = 0x7fffffff;
        #pragma unroll
        for (int off = 32; off; off >>= 1) {
            float ov1 = __shfl_xor(v1, off); int og1 = __shfl_xor(g1, off);
            float ov2 = __shfl_xor(v2, off); int og2 = __shfl_xor(g2, off);
            bool c1 = (ov1 < v1) || (ov1 == v1 && og1 < g1);
            float hv = c1 ? v1 : ov1; int hg = c1 ? g1 : og1;
            v1 = c1 ? ov1 : v1;       g1 = c1 ? og1 : g1;
            bool c2 = (ov2 < v2) || (ov2 == v2 && og2 < g2);
            float l2v = c2 ? ov2 : v2; int l2g = c2 ? og2 : g2;
            bool c3 = (l2v < hv) || (l2v == hv && l2g < hg);
            v2 = c3 ? l2v : hv;  g2 = c3 ? l2g : hg;
        }
        if (L == 2*r)   myfin = g1;
        if (L == 2*r+1) myfin = g2;
        if (di == g1 || di == g2) dv = MX;
    }
    if (L < K_) idxout[(size_t)p*K_ + L] = myfin;
}

// ---------------------------------------------------------------- P/Q precompute
__global__ __launch_bounds__(256) void pq1_kernel(const float* __restrict__ x, const float* __restrict__ W,
                                                  const float* __restrict__ b1,
                                                  float* __restrict__ P, float* __restrict__ Q)
{
    __shared__ float wd[256], wb[256];
    const int t = threadIdx.x;
    wd[t] = W[t] - W[256 + t];
    wb[t] = W[256 + t];
    __syncthreads();
    const int p = blockIdx.x*4 + (t >> 6), c = t & 63;
    const float4 xv = ((const float4*)x)[p];
    float Pv = b1[c] + xv.x*wd[c] + xv.y*wd[64+c] + xv.z*wd[128+c] + xv.w*wd[192+c];
    float Qv =         xv.x*wb[c] + xv.y*wb[64+c] + xv.z*wb[128+c] + xv.w*wb[192+c];
    P[p*64 + c] = Pv;
    Q[p*64 + c] = Qv;
}

__global__ __launch_bounds__(256) void pq2_kernel(const float* __restrict__ x1, const float* __restrict__ W,
                                                  const float* __restrict__ b1,
                                                  float* __restrict__ P, float* __restrict__ Q)
{
    __shared__ float wd[64*128], wb[64*128];
    const int t = threadIdx.x;
    for (int e = t; e < 8192; e += 256) {
        float wt = W[e], wbo = W[8192 + e];
        wd[e] = wt - wbo; wb[e] = wbo;
    }
    __syncthreads();
    const int pl = t >> 7, c = t & 127;
    const float b1v = b1[c];
    for (int p0 = blockIdx.x*2; p0 < BN_; p0 += gridDim.x*2) {
        const int p = p0 + pl;
        float Pv = b1v, Qv = 0.f;
        const float* xrow = x1 + p*64;
        #pragma unroll 8
        for (int k = 0; k < 64; ++k) {
            float xv = xrow[k];
            Pv += xv * wd[k*128 + c];
            Qv += xv * wb[k*128 + c];
        }
        P[p*128 + c] = Pv;
        Q[p*128 + c] = Qv;
    }
}

// ---------------------------------------------------------------- layer-1 BN stats (fp64 per-block partials)
template<int HO>
__global__ __launch_bounds__(256) void stats_l1_kernel(const float* __restrict__ P, const float* __restrict__ Q,
                                                       const int* __restrict__ idx, double* __restrict__ partOut)
{
    constexpr int G = 256/HO;
    __shared__ double red[256], red2[256];
    const int t = threadIdx.x, c = t % HO, g = t / HO;
    double s = 0., s2 = 0.;
    for (int p = blockIdx.x; p < BN_; p += gridDim.x) {
        const float Pv = P[p*HO + c];
        const int bbase = p & ~(N_-1);
        for (int j = g; j < K_; j += G) {
            int m = idx[p*K_ + j];
            float z = Pv + Q[(bbase + m)*HO + c];
            double zd = (double)z;
            s += zd; s2 += zd*zd;
        }
    }
    red[t] = s; red2[t] = s2;
    __syncthreads();
    if (t < HO) {
        double a = red[t], a2 = red2[t];
        #pragma unroll
        for (int q = 1; q < G; ++q) { a += red[q*HO + t]; a2 += red2[q*HO + t]; }
        partOut[(size_t)blockIdx.x*(2*HO) + t] = a;
        partOut[(size_t)blockIdx.x*(2*HO) + HO + t] = a2;
    }
}

// ---------------------------------------------------------------- EdgeConv layer-2, exact fp32 (conv1:
// its output feeds kNN2, which is flip-sensitive to ~1e-4 feature perturbation).
// R11: BN applied in the reference's elementwise op order (((z-m)*rstd)*g+be,
// separately rounded) — the folded z*ac+bc form differed by 1-2 ULP on x1 features.
template<int HO>
__global__ __launch_bounds__(256) void conv_l2_kernel(
    const float* __restrict__ P, const float* __restrict__ Q, const int* __restrict__ idx,
    const float* __restrict__ st1, const float* __restrict__ g1, const float* __restrict__ be1,
    const float* __restrict__ w2, const float* __restrict__ b2,
    float* __restrict__ zmax, float* __restrict__ zmin, double* __restrict__ partOut)
{
    __shared__ float w2s[HO*64];
    __shared__ float h1s[K_*HO];
    __shared__ float redA[256], redB[256];
    __shared__ double redD[256], redD2[256];
    const int t = threadIdx.x;
    const int cy = blockIdx.y;
    for (int e = t; e < HO*64; e += 256) {
        int c = e >> 6, cl = e & 63;
        w2s[e] = w2[c*HO + cy*64 + cl];
    }
    const int cA = t % HO;
    const float mA = st1[2*HO + cA], rA = st1[3*HO + cA];
    const float gA = g1[cA], beA = be1[cA];
    const int c2l = t & 63, jh = t >> 6;
    const float b2v = b2[cy*64 + c2l];
    double ssum = 0., ssq = 0.;
    for (int p = blockIdx.x; p < BN_; p += gridDim.x) {
        __syncthreads();
        const int bbase = p & ~(N_-1);
        const float Pv = P[p*HO + cA];
        for (int e = t; e < K_*HO; e += 256) {
            int j = e / HO;
            int m = idx[p*K_ + j];
            float z = Pv + Q[(bbase + m)*HO + cA];
            float bn = __fadd_rn(__fmul_rn(__fmul_rn(__fsub_rn(z, mA), rA), gA), beA);
            h1s[e] = fmaxf(bn, 0.f);
        }
        __syncthreads();
        float acc[5];
        #pragma unroll
        for (int q = 0; q < 5; ++q) acc[q] = b2v;
        for (int c = 0; c < HO; ++c) {
            float wv = w2s[c*64 + c2l];
            #pragma unroll
            for (int q = 0; q < 5; ++q)
                acc[q] += h1s[(jh + q*4)*HO + c] * wv;
        }
        float mx = acc[0], mn = acc[0];
        #pragma unroll
        for (int q = 0; q < 5; ++q) {
            mx = fmaxf(mx, acc[q]); mn = fminf(mn, acc[q]);
            double ad = (double)acc[q];
            ssum += ad; ssq += ad*ad;
        }
        redA[t] = mx; redB[t] = mn;
        __syncthreads();
        if (t < 64) {
            float M = redA[t], Mn = redB[t];
            #pragma unroll
            for (int g = 1; g < 4; ++g) { M = fmaxf(M, redA[g*64 + t]); Mn = fminf(Mn, redB[g*64 + t]); }
            zmax[p*HO + cy*64 + t] = M;
            zmin[p*HO + cy*64 + t] = Mn;
        }
    }
    __syncthreads();
    redD[t] = ssum; redD2[t] = ssq;
    __syncthreads();
    if (t < 64) {
        double s = redD[t], s2 = redD2[t];
        #pragma unroll
        for (int g = 1; g < 4; ++g) { s += redD[g*64 + t]; s2 += redD2[g*64 + t]; }
        partOut[(size_t)blockIdx.x*(2*HO) + cy*64 + t] = s;
        partOut[(size_t)blockIdx.x*(2*HO) + HO + cy*64 + t] = s2;
    }
}

// ---------------------------------------------------------------- W2^T split-bf16 prep
__global__ __launch_bounds__(256) void prep_w2t_kernel(const float* __restrict__ W,
                                                       unsigned short* __restrict__ wh,
                                                       unsigned short* __restrict__ wl, int HO)
{
    const int e = blockIdx.x*256 + threadIdx.x;   // e = k*HO + c
    const int k = e / HO, c = e % HO;
    const float v = W[e];
    unsigned short h = f2bf(v);
    float hf = __uint_as_float((unsigned)h << 16);
    wh[c*HO + k] = h;
    wl[c*HO + k] = f2bf(v - hf);
}

// ---------------------------------------------------------------- EdgeConv layer-2 via MFMA (split-bf16)
// conv2 only: output feeds the classifier (value-continuous), bf16-split safe.
template<int HO>
__global__ __launch_bounds__(256) void conv_l2_mfma_kernel(
    const float* __restrict__ P, const float* __restrict__ Q, const int* __restrict__ idx,
    const float* __restrict__ st1, const float* __restrict__ g1, const float* __restrict__ be1,
    const unsigned short* __restrict__ w2h, const unsigned short* __restrict__ w2l,
    const float* __restrict__ b2,
    float* __restrict__ zmax, float* __restrict__ zmin, double* __restrict__ partOut)
{
    constexpr int HOP = HO + 8;
    constexpr int CDP = HO + 1;
    constexpr int CTW = HO / 64;
    constexpr int KSn = HO / 32;
    constexpr int HSH = (HO == 128) ? 7 : 6;
    __shared__ __align__(16) short hs[2*80*HOP];
    __shared__ int sidx[80];
    float* cd = (float*)hs;

    const int t = threadIdx.x, w = t >> 6, L = t & 63;
    const int m16 = L & 15, q4 = L >> 4;

    const int kT = t & (HO - 1);
    const float ac = st1[3*HO + kT] * g1[kT];
    const float bc = be1[kT] - st1[2*HO + kT] * ac;

    bf16x8 Bh[CTW][KSn], Bl[CTW][KSn];
    #pragma unroll
    for (int ctl = 0; ctl < CTW; ++ctl)
        #pragma unroll
        for (int ks = 0; ks < KSn; ++ks) {
            const int c  = w*16*CTW + ctl*16 + m16;
            const int k0 = ks*32 + q4*8;
            Bh[ctl][ks] = *(const bf16x8*)(w2h + c*HO + k0);
            Bl[ctl][ks] = *(const bf16x8*)(w2l + c*HO + k0);
        }

    const float b2c = (t < HO) ? b2[t] : 0.f;
    double ssum = 0., ssq = 0.;

    for (int p0 = blockIdx.x*4; p0 < BN_; p0 += gridDim.x*4) {
        const int bbase = p0 & ~(N_-1);
        __syncthreads();
        if (t < 80) sidx[t] = idx[p0*K_ + t];
        __syncthreads();
        for (int e = t; e < 80*HO; e += 256) {
            const int r  = e >> HSH;
            const int pl = (r*3277) >> 16;     // r/20 for r<80
            const int mI = sidx[r];
            float z = P[(size_t)(p0+pl)*HO + kT] + Q[(size_t)(bbase+mI)*HO + kT];
            float h = fmaxf(z*ac + bc, 0.f);
            unsigned short hh = f2bf(h);
            float hf = __uint_as_float((unsigned)hh << 16);
            unsigned short hl = f2bf(h - hf);
            hs[r*HOP + kT] = (short)hh;
            hs[80*HOP + r*HOP + kT] = (short)hl;
        }
        __syncthreads();
        f32x4 acc[5][CTW];
        #pragma unroll
        for (int rt = 0; rt < 5; ++rt)
            #pragma unroll
            for (int ctl = 0; ctl < CTW; ++ctl)
                acc[rt][ctl] = (f32x4){0.f, 0.f, 0.f, 0.f};
        #pragma unroll
        for (int rt = 0; rt < 5; ++rt)
            #pragma unroll
            for (int ks = 0; ks < KSn; ++ks) {
                const short* ap = hs + (rt*16 + m16)*HOP + ks*32 + q4*8;
                bf16x8 Ah = *(const bf16x8*)ap;
                bf16x8 Al = *(const bf16x8*)(ap + 80*HOP);
                #pragma unroll
                for (int ctl = 0; ctl < CTW; ++ctl) {
                    acc[rt][ctl] = __builtin_amdgcn_mfma_f32_16x16x32_bf16(Ah, Bh[ctl][ks], acc[rt][ctl], 0, 0, 0);
                    acc[rt][ctl] = __builtin_amdgcn_mfma_f32_16x16x32_bf16(Al, Bh[ctl][ks], acc[rt][ctl], 0, 0, 0);
                    acc[rt][ctl] = __builtin_amdgcn_mfma_f32_16x16x32_bf16(Ah, Bl[ctl][ks], acc[rt][ctl], 0, 0, 0);
                }
            }
        __syncthreads();
        #pragma unroll
        for (int rt = 0; rt < 5; ++rt)
            #pragma unroll
            for (int ctl = 0; ctl < CTW; ++ctl) {
                const int col = w*16*CTW + ctl*16 + m16;
                #pragma unroll
                for (int ri = 0; ri < 4; ++ri) {
                    const int row = rt*16 + q4*4 + ri;
                    cd[row*CDP + col] = acc[rt][ctl][ri];
                }
            }
        __syncthreads();
        if (t < HO) {
            #pragma unroll
            for (int pl = 0; pl < 4; ++pl) {
                float mx = -3.4e38f, mn = 3.4e38f;
                #pragma unroll
                for (int j = 0; j < K_; ++j) {
                    float v = cd[(pl*20 + j)*CDP + t] + b2c;
                    mx = fmaxf(mx, v); mn = fminf(mn, v);
                    double vd = (double)v;
                    ssum += vd; ssq += vd*vd;
                }
                zmax[(size_t)(p0+pl)*HO + t] = mx;
                zmin[(size_t)(p0+pl)*HO + t] = mn;
            }
        }
    }
    if (t < HO) {
        partOut[(size_t)blockIdx.x*(2*HO) + t] = ssum;
        partOut[(size_t)blockIdx.x*(2*HO) + HO + t] = ssq;
    }
}

// max_j relu(BN(z)) = relu(BN(max_j z)) for gamma>=0, min for gamma<0.
// R11: reference elementwise op order for the x1b-producing instance.
template<int HO>
__global__ __launch_bounds__(256) void conv_fin_kernel(
    const float* __restrict__ zmax, const float* __restrict__ zmin,
    const float* __restrict__ st2, const float* __restrict__ g2, const float* __restrict__ be2,
    float* __restrict__ out)
{
    int e = blockIdx.x*256 + threadIdx.x;
    int c = e & (HO-1);
    float g = g2[c];
    float sel = (g >= 0.f) ? zmax[e] : zmin[e];
    float bn = __fadd_rn(__fmul_rn(__fmul_rn(__fsub_rn(sel, st2[2*HO + c]), st2[3*HO + c]), g), be2[c]);
    out[e] = fmaxf(bn, 0.f);
}

// ---------------------------------------------------------------- classifier
__global__ __launch_bounds__(256) void cls1_kernel(
    const float* __restrict__ x1, const float* __restrict__ x2f,
    const float* __restrict__ W, const float* __restrict__ b1,
    float* __restrict__ z, double* __restrict__ partOut)
{
    __shared__ float ws[192*64];
    __shared__ float xr[4*192];
    __shared__ double red[256], red2[256];
    const int t = threadIdx.x, cy = blockIdx.y;
    for (int e = t; e < 192*64; e += 256) {
        int c = e >> 6, cl = e & 63;
        ws[e] = W[c*128 + cy*64 + cl];
    }
    const int pl = t >> 6, c2l = t & 63;
    const float b1v = b1[cy*64 + c2l];
    double ssum = 0., ssq = 0.;
    for (int p0 = blockIdx.x*4; p0 < BN_; p0 += gridDim.x*4) {
        __syncthreads();
        for (int l = t; l < 4*192; l += 256) {
            int pp = l / 192, cc = l % 192;
            xr[l] = (cc < 64) ? x1[(p0+pp)*64 + cc] : x2f[(p0+pp)*128 + cc - 64];
        }
        __syncthreads();
        float acc = b1v;
        const float* xx = xr + pl*192;
        #pragma unroll 8
        for (int c = 0; c < 192; ++c) acc += xx[c] * ws[c*64 + c2l];
        z[(p0+pl)*128 + cy*64 + c2l] = acc;
        double ad = (double)acc;
        ssum += ad; ssq += ad*ad;
    }
    __syncthreads();
    red[t] = ssum; red2[t] = ssq;
    __syncthreads();
    if (t < 64) {
        double s = red[t], s2 = red2[t];
        #pragma unroll
        for (int g = 1; g < 4; ++g) { s += red[g*64 + t]; s2 += red2[g*64 + t]; }
        // partial row layout [512][256]: (sum ch0..127, sumsq ch0..127); the two
        // cy-planes of the same blockIdx.x fill disjoint 64-ch ranges.
        partOut[(size_t)blockIdx.x*256 + cy*64 + t] = s;
        partOut[(size_t)blockIdx.x*256 + 128 + cy*64 + t] = s2;
    }
}

__global__ __launch_bounds__(256) void cls_fin_kernel(
    const float* __restrict__ z, const float* __restrict__ st,
    const float* __restrict__ g, const float* __restrict__ be,
    const float* __restrict__ w2, const float* __restrict__ b2,
    float* __restrict__ out)
{
    const int t = threadIdx.x, w = t >> 6, L = t & 63;
    const int p = blockIdx.x*4 + w;
    float s = 0.f;
    #pragma unroll
    for (int h = 0; h < 2; ++h) {
        int c = L + h*64;
        float v = (z[p*128 + c] - st[256 + c]) * st[384 + c] * g[c] + be[c];
        s += fmaxf(v, 0.f) * w2[c];
    }
    #pragma unroll
    for (int off = 32; off; off >>= 1) s += __shfl_xor(s, off);
    if (L == 0) out[p] = s + b2[0];
}

// ---------------------------------------------------------------- launch
extern "C" void kernel_launch(void* const* d_in, const int* in_sizes, int n_in,
                              void* d_out, int out_size, void* d_ws, size_t ws_size,
                              hipStream_t stream)
{
    const float* x      = (const float*)d_in[0];
    const float* c1_w1  = (const float*)d_in[1];
    const float* c1_b1  = (const float*)d_in[2];
    const float* c1_g1  = (const float*)d_in[3];
    const float* c1_be1 = (const float*)d_in[4];
    const float* c1_w2  = (const float*)d_in[5];
    const float* c1_b2  = (const float*)d_in[6];
    const float* c1_g2  = (const float*)d_in[7];
    const float* c1_be2 = (const float*)d_in[8];
    const float* c2_w1  = (const float*)d_in[9];
    const float* c2_b1  = (const float*)d_in[10];
    const float* c2_g1  = (const float*)d_in[11];
    const float* c2_be1 = (const float*)d_in[12];
    const float* c2_w2  = (const float*)d_in[13];
    const float* c2_b2  = (const float*)d_in[14];
    const float* c2_g2  = (const float*)d_in[15];
    const float* c2_be2 = (const float*)d_in[16];
    const float* cls_w1 = (const float*)d_in[17];
    const float* cls_b1 = (const float*)d_in[18];
    const float* cls_g1 = (const float*)d_in[19];
    const float* cls_be1= (const float*)d_in[20];
    const float* cls_w2 = (const float*)d_in[21];
    const float* cls_b2 = (const float*)d_in[22];
    (void)in_sizes; (void)n_in; (void)out_size; (void)ws_size;

    char* ws = (char*)d_ws;
    size_t off = 0;
    auto alloc = [&](size_t bytes) { char* p = ws + off; off += (bytes + 255) & ~255ull; return p; };
    float* A    = (float*)alloc((size_t)16<<20);   // P1 -> P2 -> zcls
    float* Bq   = (float*)alloc((size_t)16<<20);   // Q1 -> Q2 -> cls partials
    float* zmax = (float*)alloc((size_t)16<<20);   // also hosts Xh/Xl between conv1 and conv2
    float* zmin = (float*)alloc((size_t)16<<20);
    float* x1b  = (float*)alloc((size_t)8<<20);
    float* x2b  = (float*)alloc((size_t)16<<20);   // also hosts idx24 + stats partials (dead windows)
    int*   idx  = (int*)  alloc((size_t)BN_*K_*4); // idx1 -> idx2
    float* nrm  = (float*)alloc((size_t)BN_*4);
    float* st   = (float*)alloc((size_t)5*512*4);
    unsigned short* w2th = (unsigned short*)alloc((size_t)128*128*2);  // W2^T hi
    unsigned short* w2tl = (unsigned short*)alloc((size_t)128*128*2);  // W2^T lo
    float *st0 = st, *st1 = st+512, *st2 = st+1024, *st3 = st+1536, *st4 = st+2048;

    unsigned short* Xh = (unsigned short*)zmax;                       // 4 MB (tiled layout, R17)
    unsigned short* Xl = (unsigned short*)((char*)zmax + (4<<20));    // 4 MB
    int* idx24 = (int*)x2b;
    double* part  = (double*)x2b;  // fp64 stats partials (max 4 MB): free during both conv phases
    double* partC = (double*)Bq;   // cls stats partials (1 MB): Q2 dead after conv_l2_mfma

    // ---- EdgeConv 1 (exact fp32 conv: x1b feeds flip-sensitive kNN2)
    knn4_kernel<<<dim3(N_/16, B_), 1024, 0, stream>>>(x, idx);
    pq1_kernel<<<BN_/4, 256, 0, stream>>>(x, c1_w1, c1_b1, A, Bq);
    stats_l1_kernel<64><<<2048, 256, 0, stream>>>(A, Bq, idx, part);
    finalize_parts_kernel<<<64, 256, 0, stream>>>(part, 2048, 64, 1.0/655360.0, st0);
    conv_l2_kernel<64><<<dim3(2048,1), 256, 0, stream>>>(A, Bq, idx, st0, c1_g1, c1_be1, c1_w2, c1_b2, zmax, zmin, part);
    finalize_parts_kernel<<<64, 256, 0, stream>>>(part, 2048, 64, 1.0/655360.0, st1);
    conv_fin_kernel<64><<<BN_*64/256, 256, 0, stream>>>(zmax, zmin, st1, c1_g2, c1_be2, x1b);

    // ---- EdgeConv 2 (MFMA conv: x2b only feeds classifier)
    nrmprep_kernel<<<BN_/4, 256, 0, stream>>>(x1b, Xh, Xl, nrm);
    knn64v4_kernel<<<dim3(N_/16, B_), 1024, 0, stream>>>(Xh, Xl, nrm, idx24);
    rescore_kernel<<<BN_/4, 256, 0, stream>>>(x1b, nrm, idx24, idx);
    pq2_kernel<<<1024, 256, 0, stream>>>(x1b, c2_w1, c2_b1, A, Bq);
    stats_l1_kernel<128><<<2048, 256, 0, stream>>>(A, Bq, idx, part);
    finalize_parts_kernel<<<128, 256, 0, stream>>>(part, 2048, 128, 1.0/655360.0, st2);
    prep_w2t_kernel<<<128*128/256, 256, 0, stream>>>(c2_w2, w2th, w2tl, 128);
    conv_l2_mfma_kernel<128><<<2048, 256, 0, stream>>>(A, Bq, idx, st2, c2_g1, c2_be1, w2th, w2tl, c2_b2, zmax, zmin, part);
    finalize_parts_kernel<<<128, 256, 0, stream>>>(part, 2048, 128, 1.0/655360.0, st3);
    conv_fin_kernel<128><<<BN_*128/256, 256, 0, stream>>>(zmax, zmin, st3, c2_g2, c2_be2, x2b);

    // ---- classifier
    cls1_kernel<<<dim3(512,2), 256, 0, stream>>>(x1b, x2b, cls_w1, cls_b1, A, partC);
    finalize_parts_kernel<<<128, 256, 0, stream>>>(partC, 512, 128, 1.0/32768.0, st4);
    cls_fin_kernel<<<BN_/4, 256, 0, stream>>>(A, st4, cls_g1, cls_be1, cls_w2, cls_b2, (float*)d_out);
}

// Round 13
// 1206.785 us; speedup vs baseline: 1.2701x; 1.0313x over previous
//
#include <hip/hip_runtime.h>
#include <math.h>

#define B_ 8
#define N_ 4096
#define K_ 20
#define KS_ 24          // approx-select width; exact rescore trims to K_ (R3-validated margin)
#define BN_ (B_*N_)

typedef __attribute__((ext_vector_type(8))) short bf16x8;
typedef __attribute__((ext_vector_type(4))) float f32x4;

// ---------------------------------------------------------------- BN stats finalize (deterministic, fp64)
// R10: float atomicAdd stats were order-nondeterministic across graph replays ->
// kNN2 boundary flip -> post-timing divergence.  R11: the deterministic fp32
// order landed on the WRONG side of a ~1-ULP distance tie (absmax 0.1177).
// All stats now accumulate in DOUBLE (partials + reduce + mean/var/rstd), so our
// stats are ~exact; the x1b-feeding BN applies the reference's elementwise op
// order; rescore uses the reference's full d formula.  DO NOT reintroduce
// atomicAdd or fold these back into fp32/FMA on the conv1 path.
// part layout: [nb][2*H] doubles (sum(H), sumsq(H) per block row).
__global__ __launch_bounds__(256) void finalize_parts_kernel(
    const double* __restrict__ part, int nb, int H, double invCount, float* __restrict__ st)
{
    __shared__ double red[256], red2[256];
    const int c = blockIdx.x, t = threadIdx.x;
    double s = 0., s2 = 0.;
    for (int b = t; b < nb; b += 256) {
        s  += part[(size_t)b*2*H + c];
        s2 += part[(size_t)b*2*H + H + c];
    }
    red[t] = s; red2[t] = s2;
    __syncthreads();
    #pragma unroll
    for (int off = 128; off; off >>= 1) {
        if (t < off) { red[t] += red[t+off]; red2[t] += red2[t+off]; }
        __syncthreads();
    }
    if (t == 0) {
        double mean = red[0] * invCount;
        double var  = fmax(red2[0] * invCount - mean * mean, 0.);
        st[2*H + c] = (float)mean;
        st[3*H + c] = (float)(1.0 / sqrt(var + 1e-5));
    }
}

// ---------------------------------------------------------------- kNN, C=4
// R7-validated (value, candidate-index) lexicographic argmin — matches jax
// top_k tie-break; reference-defining (no rescore guard) -> selection EXACT.
// R15: rolled loops (L1I); d[64] eliminated via fused compute+insert; rescans
// recompute dists (bit-identical).  DO NOT replace with DPP (R9).
// R21 ERRATA: R20's nt[] |c|^2 precompute (+unroll 4) changed FMA contraction
// of the distance -> flipped a reference top_k tie -> absmax 0.164 FAIL.
// knn4's distance arithmetic is FROZEN in exactly this form.  DO NOT hoist,
// precompute, or re-unroll anything in the scan/rescan bodies.  R22: selection
// restructure also ruled out (R5: issue-bound, 2-winner rounds add VALU).
__global__ __launch_bounds__(1024, 8) void knn4_kernel(const float* __restrict__ x, int* __restrict__ idxout)
{
    __shared__ float4 xt[N_];   // 64 KB
    const int b = blockIdx.y;
    const int t = threadIdx.x;
    const float4* xg = (const float4*)x + b*N_;
    for (int e = t; e < N_; e += 1024) xt[e] = xg[e];
    __syncthreads();
    const int w = t >> 6, L = t & 63;
    const int n = blockIdx.x*16 + w;
    const float4 q = xt[n];
    const float MX = 3.4e38f;
    float m1 = MX, m2 = MX, m3 = MX; int i1 = 0, i2 = 0, i3 = 0;
    #pragma unroll 1
    for (int j = 0; j < 64; ++j) {
        float4 vv = xt[(j<<6) | L];
        float nn = vv.x*vv.x + vv.y*vv.y + vv.z*vv.z + vv.w*vv.w;
        float dp = q.x*vv.x + q.y*vv.y + q.z*vv.z + q.w*vv.w;
        float v = nn - 2.f*dp;   // |xn|^2 dropped: rank-equivalent
        bool c1 = v < m1, c2 = v < m2, c3 = v < m3;
        m3 = c2 ? m2 : (c3 ? v : m3);
        i3 = c2 ? i2 : (c3 ? j : i3);
        m2 = c1 ? m1 : (c2 ? v : m2);
        i2 = c1 ? i1 : (c2 ? j : i2);
        m1 = c1 ? v : m1;
        i1 = c1 ? j : i1;
    }
    unsigned long long used = 0;
    int mywin = 0;
    #pragma unroll 1
    for (int r = 0; r < K_; ++r) {
        float bv = m1; int bg = (i1<<6) | L;
        #pragma unroll
        for (int off = 32; off; off >>= 1) {
            float ov = __shfl_xor(bv, off);
            int   og = __shfl_xor(bg, off);
            bool tk = (ov < bv) || (ov == bv && og < bg);
            bv = tk ? ov : bv; bg = tk ? og : bg;
        }
        if (L == r) mywin = bg;
        if (L == (bg & 63)) {
            used |= 1ull << i1;
            m1 = m2; i1 = i2; m2 = m3; i2 = i3; m3 = MX;
            if (m1 == MX) {
                m2 = MX; m3 = MX; i1 = 0; i2 = 0; i3 = 0;
                #pragma unroll 1
                for (int j = 0; j < 64; ++j) {
                    float4 vv = xt[(j<<6) | L];
                    float nn = vv.x*vv.x + vv.y*vv.y + vv.z*vv.z + vv.w*vv.w;
                    float dp = q.x*vv.x + q.y*vv.y + q.z*vv.z + q.w*vv.w;
                    float dj = nn - 2.f*dp;
                    float v = ((used >> j) & 1ull) ? MX : dj;
                    bool c1 = v < m1, c2 = v < m2, c3 = v < m3;
                    m3 = c2 ? m2 : (c3 ? v : m3);
                    i3 = c2 ? i2 : (c3 ? j : i3);
                    m2 = c1 ? m1 : (c2 ? v : m2);
                    i2 = c1 ? i1 : (c2 ? j : i2);
                    m1 = c1 ? v : m1;
                    i1 = c1 ? j : i1;
                }
            }
        }
    }
    if (L < K_) idxout[(b*N_ + n)*K_ + L] = mywin;
}

// ---------------------------------------------------------------- fp32 -> bf16 RNE
static __device__ inline unsigned short f2bf(float f)
{
    unsigned u = __float_as_uint(f);
    unsigned r = (u + 0x7fffu + ((u >> 16) & 1u)) >> 16;   // RNE
    return (unsigned short)r;
}

// comparator: (x,y) -> (min,max)
#define CE_(x,y) { float _t = fminf(x,y); y = fmaxf(x,y); x = _t; }
// Batcher odd-even sort-8 (19 CE)
#define SORT8_(g0,g1,g2,g3,g4,g5,g6,g7)                                   \
    CE_(g0,g1) CE_(g2,g3) CE_(g4,g5) CE_(g6,g7)                           \
    CE_(g0,g2) CE_(g1,g3) CE_(g4,g6) CE_(g5,g7)                           \
    CE_(g1,g2) CE_(g5,g6)                                                 \
    CE_(g0,g4) CE_(g1,g5) CE_(g2,g6) CE_(g3,g7)                           \
    CE_(g2,g4) CE_(g3,g5)                                                 \
    CE_(g1,g2) CE_(g3,g4) CE_(g5,g6)
// keep lowest-8 (sorted) of two sorted-asc 8-lists: sm = low8(sm, g)
#define MERGE8_(g0,g1,g2,g3,g4,g5,g6,g7)                                  \
    sm0 = fminf(sm0,g7); sm1 = fminf(sm1,g6); sm2 = fminf(sm2,g5);        \
    sm3 = fminf(sm3,g4); sm4 = fminf(sm4,g3); sm5 = fminf(sm5,g2);        \
    sm6 = fminf(sm6,g1); sm7 = fminf(sm7,g0);                             \
    CE_(sm0,sm4) CE_(sm1,sm5) CE_(sm2,sm6) CE_(sm3,sm7)                   \
    CE_(sm0,sm2) CE_(sm1,sm3) CE_(sm4,sm6) CE_(sm5,sm7)                   \
    CE_(sm0,sm1) CE_(sm2,sm3) CE_(sm4,sm5) CE_(sm6,sm7)

// ---------------------------------------------------------------- kNN, C=64 via MFMA (split-bf16 Gram, approx)
// v12 (R19): 32KB dist tile (8 chunks of 512) -> 2 blocks/CU resident;
// SORT8+MERGE8 scan per chunk; slot = ck*8 + (cm>>6); lane residue preserved.
// Selection (R16 bitonic 8-merge butterfly + ballot pops), keys (R12), tiled
// layout (R17), strength-reduced staging (R18), top-8 dropout P~5e-9 (R14).
__global__ __launch_bounds__(1024, 4) void knn64v4_kernel(
    const unsigned short* __restrict__ Xh, const unsigned short* __restrict__ Xl,
    const float* __restrict__ nrm, int* __restrict__ idx24)
{
    __shared__ float dist[16*512];   // 32 KB -> 2 blocks/CU resident
    const int b = blockIdx.y, t = threadIdx.x;
    const int w = t >> 6, L = t & 63;
    const int q0 = blockIdx.x * 16;
    const int m = L & 15, q4 = L >> 4;
    const size_t rowbase = (size_t)b * N_ * 64;
    const int swzW = q4 << 4;         // write-side column XOR (qrow>>2 == q4)
    const int swzR = (w >> 2) << 4;   // read-side column XOR (query row w)
    const int fragoff = q4*128 + m*8; // within-tile fragment offset (shorts)

    // A fragments: tile q0>>4
    const unsigned short* aph = Xh + rowbase + (size_t)(q0 >> 4)*1024 + fragoff;
    const unsigned short* apl = Xl + rowbase + (size_t)(q0 >> 4)*1024 + fragoff;
    const bf16x8 a_h0 = *(const bf16x8*)(aph);
    const bf16x8 a_h1 = *(const bf16x8*)(aph + 512);
    const bf16x8 a_l0 = *(const bf16x8*)(apl);
    const bf16x8 a_l1 = *(const bf16x8*)(apl + 512);

    const float MX = 3.4e38f;
    float sm0 = MX, sm1 = MX, sm2 = MX, sm3 = MX, sm4 = MX, sm5 = MX, sm6 = MX, sm7 = MX;

    float* const wrow = dist + q4*2048;        // q4*4*512
    float* const rrow = dist + w*512 + (L ^ swzR);

    #pragma unroll 1
    for (int ck = 0; ck < 8; ++ck) {
        const unsigned slotW0 = (unsigned)(ck*8);
        // strength-reduced staging pointers for this ck (each wave: 2 sub-tiles)
        const unsigned short* bp_h = Xh + rowbase + (size_t)(ck*32 + w*2)*1024 + fragoff;
        const unsigned short* bp_l = Xl + rowbase + (size_t)(ck*32 + w*2)*1024 + fragoff;
        const float* np = nrm + b*N_ + ck*512 + w*32 + m;
        int cm = w*32 + m;
        __syncthreads();
        #pragma unroll
        for (int tt = 0; tt < 2; ++tt) {
            bf16x8 b_h0 = *(const bf16x8*)(bp_h);
            bf16x8 b_h1 = *(const bf16x8*)(bp_h + 512);
            bf16x8 b_l0 = *(const bf16x8*)(bp_l);
            bf16x8 b_l1 = *(const bf16x8*)(bp_l + 512);
            f32x4 acc = {0.f, 0.f, 0.f, 0.f};
            acc = __builtin_amdgcn_mfma_f32_16x16x32_bf16(a_h0, b_h0, acc, 0, 0, 0);
            acc = __builtin_amdgcn_mfma_f32_16x16x32_bf16(a_h1, b_h1, acc, 0, 0, 0);
            acc = __builtin_amdgcn_mfma_f32_16x16x32_bf16(a_l0, b_h0, acc, 0, 0, 0);
            acc = __builtin_amdgcn_mfma_f32_16x16x32_bf16(a_l1, b_h1, acc, 0, 0, 0);
            acc = __builtin_amdgcn_mfma_f32_16x16x32_bf16(a_h0, b_l0, acc, 0, 0, 0);
            acc = __builtin_amdgcn_mfma_f32_16x16x32_bf16(a_h1, b_l1, acc, 0, 0, 0);
            const float nv = *np;
            const int colW = cm ^ swzW;
            const unsigned slotW = slotW0 + (unsigned)(cm >> 6);
            float* wp = wrow + colW;
            #pragma unroll
            for (int r = 0; r < 4; ++r) {
                float dv = nv - 2.f*acc[r];
                unsigned key = (__float_as_uint(dv) & ~63u) | slotW;
                wp[r*512] = __uint_as_float(key);
            }
            bp_h += 1024; bp_l += 1024; np += 16; cm += 16;
        }
        __syncthreads();
        // scan this ck's 8 values: one sorted group of 8, merged into sm
        {
            float g0 = rrow[0*64], g1 = rrow[1*64], g2 = rrow[2*64], g3 = rrow[3*64];
            float g4 = rrow[4*64], g5 = rrow[5*64], g6 = rrow[6*64], g7 = rrow[7*64];
            SORT8_(g0,g1,g2,g3,g4,g5,g6,g7)
            MERGE8_(g0,g1,g2,g3,g4,g5,g6,g7)
        }
    }

    int mywin = 0;
    #pragma unroll 1
    for (int sr = 0; sr < 3; ++sr) {
        // butterfly all-reduce: global sorted top-8 of the union of all lanes' lists
        float a0 = sm0, a1 = sm1, a2 = sm2, a3 = sm3, a4 = sm4, a5 = sm5, a6 = sm6, a7 = sm7;
        #pragma unroll
        for (int off = 32; off; off >>= 1) {
            float b0 = __shfl_xor(a0, off), b1 = __shfl_xor(a1, off);
            float b2 = __shfl_xor(a2, off), b3 = __shfl_xor(a3, off);
            float b4 = __shfl_xor(a4, off), b5 = __shfl_xor(a5, off);
            float b6 = __shfl_xor(a6, off), b7 = __shfl_xor(a7, off);
            float c0 = fminf(a0, b7), c1 = fminf(a1, b6), c2 = fminf(a2, b5), c3 = fminf(a3, b4);
            float c4 = fminf(a4, b3), c5 = fminf(a5, b2), c6 = fminf(a6, b1), c7 = fminf(a7, b0);
            float u;
            u = fminf(c0, c4); c4 = fmaxf(c0, c4); c0 = u;
            u = fminf(c1, c5); c5 = fmaxf(c1, c5); c1 = u;
            u = fminf(c2, c6); c6 = fmaxf(c2, c6); c2 = u;
            u = fminf(c3, c7); c7 = fmaxf(c3, c7); c3 = u;
            u = fminf(c0, c2); c2 = fmaxf(c0, c2); c0 = u;
            u = fminf(c1, c3); c3 = fmaxf(c1, c3); c1 = u;
            u = fminf(c4, c6); c6 = fmaxf(c4, c6); c4 = u;
            u = fminf(c5, c7); c7 = fmaxf(c5, c7); c5 = u;
            u = fminf(c0, c1); c1 = fmaxf(c0, c1); c0 = u;
            u = fminf(c2, c3); c3 = fmaxf(c2, c3); c2 = u;
            u = fminf(c4, c5); c5 = fmaxf(c4, c5); c4 = u;
            u = fminf(c6, c7); c7 = fmaxf(c6, c7); c6 = u;
            a0 = c0; a1 = c1; a2 = c2; a3 = c3; a4 = c4; a5 = c5; a6 = c6; a7 = c7;
        }
        // extract the 8 winners in ascending order (set semantics; min-lane on ties)
        #define POPW(AW, WIDX)                                                              \
        {                                                                                   \
            const unsigned long long bal = __ballot(sm0 == (AW));                           \
            const int owner = (int)__ffsll(bal) - 1;                                        \
            if (L == sr*8 + (WIDX))                                                         \
                mywin = (int)(((__float_as_uint(AW) & 63u) << 6) | (unsigned)owner);        \
            if (L == owner) {                                                               \
                sm0 = sm1; sm1 = sm2; sm2 = sm3; sm3 = sm4;                                 \
                sm4 = sm5; sm5 = sm6; sm6 = sm7; sm7 = MX;                                  \
            }                                                                               \
        }
        POPW(a0, 0) POPW(a1, 1) POPW(a2, 2) POPW(a3, 3)
        POPW(a4, 4) POPW(a5, 5) POPW(a6, 6) POPW(a7, 7)
        #undef POPW
    }
    if (L < KS_) idx24[((size_t)b*N_ + q0 + w)*KS_ + L] = mywin;
}

// ---------------------------------------------------------------- exact fp32 rescore of the KS_ candidates
// R11: d matches the reference formula exactly.  R13: two winners per round.
// Exact: every lane holds ONE always-valid candidate; indices unique.
__global__ __launch_bounds__(256) void rescore_kernel(const float* __restrict__ x1, const float* __restrict__ nrm,
                                                      const int* __restrict__ idx24, int* __restrict__ idxout)
{
    const int t = threadIdx.x, w = t >> 6, L = t & 63;
    const int p = blockIdx.x*4 + w;
    const int bbase = p & ~(N_-1);
    const float MX = 3.4e38f;
    float dv = MX; int di = 0x7fffffff;
    if (L < KS_) {
        const int ci = idx24[(size_t)p*KS_ + L];
        const float4* qr = (const float4*)(x1 + (size_t)p*64);
        const float4* cr = (const float4*)(x1 + (size_t)(bbase + ci)*64);
        float dot = 0.f;
        #pragma unroll
        for (int i = 0; i < 16; ++i) {
            float4 a = qr[i], bx = cr[i];
            dot += a.x*bx.x + a.y*bx.y + a.z*bx.z + a.w*bx.w;
        }
        dv = __fsub_rn(__fadd_rn(nrm[p], nrm[bbase + ci]), 2.f*dot);
        di = ci;
    }
    int myfin = 0;
    #pragma unroll 1
    for (int r = 0; r < K_/2; ++r) {
        float v1 = dv; int g1 = di;
        float v2 = MX; int g2 = 0x7fffffff;
        #pragma unroll
        for (int off = 32; off; off >>= 1) {
            float ov1 = __shfl_xor(v1, off); int og1 = __shfl_xor(g1, off);
            float ov2 = __shfl_xor(v2, off); int og2 = __shfl_xor(g2, off);
            bool c1 = (ov1 < v1) || (ov1 == v1 && og1 < g1);
            float hv = c1 ? v1 : ov1; int hg = c1 ? g1 : og1;
            v1 = c1 ? ov1 : v1;       g1 = c1 ? og1 : g1;
            bool c2 = (ov2 < v2) || (ov2 == v2 && og2 < g2);
            float l2v = c2 ? ov2 : v2; int l2g = c2 ? og2 : g2;
            bool c3 = (l2v < hv) || (l2v == hv && l2g < hg);
            v2 = c3 ? l2v : hv;  g2 = c3 ? l2g : hg;
        }
        if (L == 2*r)   myfin = g1;
        if (L == 2*r+1) myfin = g2;
        if (di == g1 || di == g2) dv = MX;
    }
    if (L < K_) idxout[(size_t)p*K_ + L] = myfin;
}

// ---------------------------------------------------------------- P/Q precompute
__global__ __launch_bounds__(256) void pq1_kernel(const float* __restrict__ x, const float* __restrict__ W,
                                                  const float* __restrict__ b1,
                                                  float* __restrict__ P, float* __restrict__ Q)
{
    __shared__ float wd[256], wb[256];
    const int t = threadIdx.x;
    wd[t] = W[t] - W[256 + t];
    wb[t] = W[256 + t];
    __syncthreads();
    const int p = blockIdx.x*4 + (t >> 6), c = t & 63;
    const float4 xv = ((const float4*)x)[p];
    float Pv = b1[c] + xv.x*wd[c] + xv.y*wd[64+c] + xv.z*wd[128+c] + xv.w*wd[192+c];
    float Qv =         xv.x*wb[c] + xv.y*wb[64+c] + xv.z*wb[128+c] + xv.w*wb[192+c];
    P[p*64 + c] = Pv;
    Q[p*64 + c] = Qv;
}

__global__ __launch_bounds__(256) void pq2_kernel(const float* __restrict__ x1, const float* __restrict__ W,
                                                  const float* __restrict__ b1,
                                                  float* __restrict__ P, float* __restrict__ Q)
{
    __shared__ float wd[64*128], wb[64*128];
    const int t = threadIdx.x;
    for (int e = t; e < 8192; e += 256) {
        float wt = W[e], wbo = W[8192 + e];
        wd[e] = wt - wbo; wb[e] = wbo;
    }
    __syncthreads();
    const int pl = t >> 7, c = t & 127;
    const float b1v = b1[c];
    for (int p0 = blockIdx.x*2; p0 < BN_; p0 += gridDim.x*2) {
        const int p = p0 + pl;
        float Pv = b1v, Qv = 0.f;
        const float* xrow = x1 + p*64;
        #pragma unroll 8
        for (int k = 0; k < 64; ++k) {
            float xv = xrow[k];
            Pv += xv * wd[k*128 + c];
            Qv += xv * wb[k*128 + c];
        }
        P[p*128 + c] = Pv;
        Q[p*128 + c] = Qv;
    }
}

// ---------------------------------------------------------------- layer-1 BN stats (fp64 per-block partials)
template<int HO>
__global__ __launch_bounds__(256) void stats_l1_kernel(const float* __restrict__ P, const float* __restrict__ Q,
                                                       const int* __restrict__ idx, double* __restrict__ partOut)
{
    constexpr int G = 256/HO;
    __shared__ double red[256], red2[256];
    const int t = threadIdx.x, c = t % HO, g = t / HO;
    double s = 0., s2 = 0.;
    for (int p = blockIdx.x; p < BN_; p += gridDim.x) {
        const float Pv = P[p*HO + c];
        const int bbase = p & ~(N_-1);
        for (int j = g; j < K_; j += G) {
            int m = idx[p*K_ + j];
            float z = Pv + Q[(bbase + m)*HO + c];
            double zd = (double)z;
            s += zd; s2 += zd*zd;
        }
    }
    red[t] = s; red2[t] = s2;
    __syncthreads();
    if (t < HO) {
        double a = red[t], a2 = red2[t];
        #pragma unroll
        for (int q = 1; q < G; ++q) { a += red[q*HO + t]; a2 += red2[q*HO + t]; }
        partOut[(size_t)blockIdx.x*(2*HO) + t] = a;
        partOut[(size_t)blockIdx.x*(2*HO) + HO + t] = a2;
    }
}

// ---------------------------------------------------------------- EdgeConv layer-2, exact fp32 (conv1:
// its output feeds kNN2, which is flip-sensitive to ~1e-4 feature perturbation).
// R11: BN applied in the reference's elementwise op order (((z-m)*rstd)*g+be,
// separately rounded).  R22: MAC loop vectorized — h1s reads are wave-uniform
// -> broadcast b128 (4 c's at once); each acc[q] chain still accumulates in
// ascending-c order with the same `acc += h*w` contraction form -> BIT-IDENTICAL
// (independent serial chains; interleaving across q doesn't reorder any chain).
// LDS instrs/point 384 -> 144.
template<int HO>
__global__ __launch_bounds__(256) void conv_l2_kernel(
    const float* __restrict__ P, const float* __restrict__ Q, const int* __restrict__ idx,
    const float* __restrict__ st1, const float* __restrict__ g1, const float* __restrict__ be1,
    const float* __restrict__ w2, const float* __restrict__ b2,
    float* __restrict__ zmax, float* __restrict__ zmin, double* __restrict__ partOut)
{
    __shared__ float w2s[HO*64];
    __shared__ __align__(16) float h1s[K_*HO];
    __shared__ float redA[256], redB[256];
    __shared__ double redD[256], redD2[256];
    const int t = threadIdx.x;
    const int cy = blockIdx.y;
    for (int e = t; e < HO*64; e += 256) {
        int c = e >> 6, cl = e & 63;
        w2s[e] = w2[c*HO + cy*64 + cl];
    }
    const int cA = t % HO;
    const float mA = st1[2*HO + cA], rA = st1[3*HO + cA];
    const float gA = g1[cA], beA = be1[cA];
    const int c2l = t & 63, jh = t >> 6;
    const float b2v = b2[cy*64 + c2l];
    double ssum = 0., ssq = 0.;
    for (int p = blockIdx.x; p < BN_; p += gridDim.x) {
        __syncthreads();
        const int bbase = p & ~(N_-1);
        const float Pv = P[p*HO + cA];
        for (int e = t; e < K_*HO; e += 256) {
            int j = e / HO;
            int m = idx[p*K_ + j];
            float z = Pv + Q[(bbase + m)*HO + cA];
            float bn = __fadd_rn(__fmul_rn(__fmul_rn(__fsub_rn(z, mA), rA), gA), beA);
            h1s[e] = fmaxf(bn, 0.f);
        }
        __syncthreads();
        float acc[5];
        #pragma unroll
        for (int q = 0; q < 5; ++q) acc[q] = b2v;
        const float4* h1v = (const float4*)h1s;
        for (int c4 = 0; c4 < HO/4; ++c4) {
            const float w0 = w2s[(c4*4+0)*64 + c2l];
            const float w1 = w2s[(c4*4+1)*64 + c2l];
            const float w2v = w2s[(c4*4+2)*64 + c2l];
            const float w3 = w2s[(c4*4+3)*64 + c2l];
            #pragma unroll
            for (int q = 0; q < 5; ++q) {
                float4 hv = h1v[(jh + q*4)*(HO/4) + c4];   // wave-uniform -> broadcast
                acc[q] += hv.x*w0;
                acc[q] += hv.y*w1;
                acc[q] += hv.z*w2v;
                acc[q] += hv.w*w3;
            }
        }
        float mx = acc[0], mn = acc[0];
        #pragma unroll
        for (int q = 0; q < 5; ++q) {
            mx = fmaxf(mx, acc[q]); mn = fminf(mn, acc[q]);
            double ad = (double)acc[q];
            ssum += ad; ssq += ad*ad;
        }
        redA[t] = mx; redB[t] = mn;
        __syncthreads();
        if (t < 64) {
            float M = redA[t], Mn = redB[t];
            #pragma unroll
            for (int g = 1; g < 4; ++g) { M = fmaxf(M, redA[g*64 + t]); Mn = fminf(Mn, redB[g*64 + t]); }
            zmax[p*HO + cy*64 + t] = M;
            zmin[p*HO + cy*64 + t] = Mn;
        }
    }
    __syncthreads();
    redD[t] = ssum; redD2[t] = ssq;
    __syncthreads();
    if (t < 64) {
        double s = redD[t], s2 = redD2[t];
        #pragma unroll
        for (int g = 1; g < 4; ++g) { s += redD[g*64 + t]; s2 += redD2[g*64 + t]; }
        partOut[(size_t)blockIdx.x*(2*HO) + cy*64 + t] = s;
        partOut[(size_t)blockIdx.x*(2*HO) + HO + cy*64 + t] = s2;
    }
}

// ---------------------------------------------------------------- W2^T split-bf16 prep
__global__ __launch_bounds__(256) void prep_w2t_kernel(const float* __restrict__ W,
                                                       unsigned short* __restrict__ wh,
                                                       unsigned short* __restrict__ wl, int HO)
{
    const int e = blockIdx.x*256 + threadIdx.x;   // e = k*HO + c
    const int k = e / HO, c = e % HO;
    const float v = W[e];
    unsigned short h = f2bf(v);
    float hf = __uint_as_float((unsigned)h << 16);
    wh[c*HO + k] = h;
    wl[c*HO + k] = f2bf(v - hf);
}

// ---------------------------------------------------------------- EdgeConv layer-2 via MFMA (split-bf16)
// conv2 only: output feeds the classifier (value-continuous), bf16-split safe.
template<int HO>
__global__ __launch_bounds__(256) void conv_l2_mfma_kernel(
    const float* __restrict__ P, const float* __restrict__ Q, const int* __restrict__ idx,
    const float* __restrict__ st1, const float* __restrict__ g1, const float* __restrict__ be1,
    const unsigned short* __restrict__ w2h, const unsigned short* __restrict__ w2l,
    const float* __restrict__ b2,
    float* __restrict__ zmax, float* __restrict__ zmin, double* __restrict__ partOut)
{
    constexpr int HOP = HO + 8;
    constexpr int CDP = HO + 1;
    constexpr int CTW = HO / 64;
    constexpr int KSn = HO / 32;
    constexpr int HSH = (HO == 128) ? 7 : 6;
    __shared__ __align__(16) short hs[2*80*HOP];
    __shared__ int sidx[80];
    float* cd = (float*)hs;

    const int t = threadIdx.x, w = t >> 6, L = t & 63;
    const int m16 = L & 15, q4 = L >> 4;

    const int kT = t & (HO - 1);
    const float ac = st1[3*HO + kT] * g1[kT];
    const float bc = be1[kT] - st1[2*HO + kT] * ac;

    bf16x8 Bh[CTW][KSn], Bl[CTW][KSn];
    #pragma unroll
    for (int ctl = 0; ctl < CTW; ++ctl)
        #pragma unroll
        for (int ks = 0; ks < KSn; ++ks) {
            const int c  = w*16*CTW + ctl*16 + m16;
            const int k0 = ks*32 + q4*8;
            Bh[ctl][ks] = *(const bf16x8*)(w2h + c*HO + k0);
            Bl[ctl][ks] = *(const bf16x8*)(w2l + c*HO + k0);
        }

    const float b2c = (t < HO) ? b2[t] : 0.f;
    double ssum = 0., ssq = 0.;

    for (int p0 = blockIdx.x*4; p0 < BN_; p0 += gridDim.x*4) {
        const int bbase = p0 & ~(N_-1);
        __syncthreads();
        if (t < 80) sidx[t] = idx[p0*K_ + t];
        __syncthreads();
        for (int e = t; e < 80*HO; e += 256) {
            const int r  = e >> HSH;
            const int pl = (r*3277) >> 16;     // r/20 for r<80
            const int mI = sidx[r];
            float z = P[(size_t)(p0+pl)*HO + kT] + Q[(size_t)(bbase+mI)*HO + kT];
            float h = fmaxf(z*ac + bc, 0.f);
            unsigned short hh = f2bf(h);
            float hf = __uint_as_float((unsigned)hh << 16);
            unsigned short hl = f2bf(h - hf);
            hs[r*HOP + kT] = (short)hh;
            hs[80*HOP + r*HOP + kT] = (short)hl;
        }
        __syncthreads();
        f32x4 acc[5][CTW];
        #pragma unroll
        for (int rt = 0; rt < 5; ++rt)
            #pragma unroll
            for (int ctl = 0; ctl < CTW; ++ctl)
                acc[rt][ctl] = (f32x4){0.f, 0.f, 0.f, 0.f};
        #pragma unroll
        for (int rt = 0; rt < 5; ++rt)
            #pragma unroll
            for (int ks = 0; ks < KSn; ++ks) {
                const short* ap = hs + (rt*16 + m16)*HOP + ks*32 + q4*8;
                bf16x8 Ah = *(const bf16x8*)ap;
                bf16x8 Al = *(const bf16x8*)(ap + 80*HOP);
                #pragma unroll
                for (int ctl = 0; ctl < CTW; ++ctl) {
                    acc[rt][ctl] = __builtin_amdgcn_mfma_f32_16x16x32_bf16(Ah, Bh[ctl][ks], acc[rt][ctl], 0, 0, 0);
                    acc[rt][ctl] = __builtin_amdgcn_mfma_f32_16x16x32_bf16(Al, Bh[ctl][ks], acc[rt][ctl], 0, 0, 0);
                    acc[rt][ctl] = __builtin_amdgcn_mfma_f32_16x16x32_bf16(Ah, Bl[ctl][ks], acc[rt][ctl], 0, 0, 0);
                }
            }
        __syncthreads();
        #pragma unroll
        for (int rt = 0; rt < 5; ++rt)
            #pragma unroll
            for (int ctl = 0; ctl < CTW; ++ctl) {
                const int col = w*16*CTW + ctl*16 + m16;
                #pragma unroll
                for (int ri = 0; ri < 4; ++ri) {
                    const int row = rt*16 + q4*4 + ri;
                    cd[row*CDP + col] = acc[rt][ctl][ri];
                }
            }
        __syncthreads();
        if (t < HO) {
            #pragma unroll
            for (int pl = 0; pl < 4; ++pl) {
                float mx = -3.4e38f, mn = 3.4e38f;
                #pragma unroll
                for (int j = 0; j < K_; ++j) {
                    float v = cd[(pl*20 + j)*CDP + t] + b2c;
                    mx = fmaxf(mx, v); mn = fminf(mn, v);
                    double vd = (double)v;
                    ssum += vd; ssq += vd*vd;
                }
                zmax[(size_t)(p0+pl)*HO + t] = mx;
                zmin[(size_t)(p0+pl)*HO + t] = mn;
            }
        }
    }
    if (t < HO) {
        partOut[(size_t)blockIdx.x*(2*HO) + t] = ssum;
        partOut[(size_t)blockIdx.x*(2*HO) + HO + t] = ssq;
    }
}

// max_j relu(BN(z)) = relu(BN(max_j z)) for gamma>=0, min for gamma<0.
// R11: reference elementwise op order for the x1b-producing instance.
template<int HO>
__global__ __launch_bounds__(256) void conv_fin_kernel(
    const float* __restrict__ zmax, const float* __restrict__ zmin,
    const float* __restrict__ st2, const float* __restrict__ g2, const float* __restrict__ be2,
    float* __restrict__ out)
{
    int e = blockIdx.x*256 + threadIdx.x;
    int c = e & (HO-1);
    float g = g2[c];
    float sel = (g >= 0.f) ? zmax[e] : zmin[e];
    float bn = __fadd_rn(__fmul_rn(__fmul_rn(__fsub_rn(sel, st2[2*HO + c]), st2[3*HO + c]), g), be2[c]);
    out[e] = fmaxf(bn, 0.f);
}

// ---------------------------------------------------------------- fused conv_fin<64> + nrm + split-bf16 tiled prep (R22)
// Same thread->(row,channel) mapping as the old nrmprep (row=e>>6, L=e&63; one
// wave == one row), so the R11-frozen nrm butterfly consumes the just-computed
// x1b value in-register — fp32 store/load is exact, hence BIT-IDENTICAL nrm,
// Xh/Xl (R17 tiled layout), and x1b.  Saves a 2MB x1b read pass + one launch.
__global__ __launch_bounds__(256) void conv_fin64_prep_kernel(
    const float* __restrict__ zmax, const float* __restrict__ zmin,
    const float* __restrict__ st2, const float* __restrict__ g2, const float* __restrict__ be2,
    float* __restrict__ out, unsigned short* __restrict__ Xh, unsigned short* __restrict__ Xl,
    float* __restrict__ nrm)
{
    const int e = blockIdx.x*256 + threadIdx.x;
    const int c = e & 63;
    float g = g2[c];
    float sel = (g >= 0.f) ? zmax[e] : zmin[e];
    float bn = __fadd_rn(__fmul_rn(__fmul_rn(__fsub_rn(sel, st2[128 + c]), st2[192 + c]), g), be2[c]);
    const float v = fmaxf(bn, 0.f);
    out[e] = v;
    float s = v * v;
    #pragma unroll
    for (int off = 32; off; off >>= 1) s += __shfl_xor(s, off);
    const int row = e >> 6;
    if (c == 0) nrm[row] = s;
    unsigned short h = f2bf(v);
    float hf = __uint_as_float((unsigned)h << 16);
    unsigned short l = f2bf(v - hf);
    const size_t base = (size_t)(row >> 4)*1024 + (size_t)(c >> 3)*128 + (size_t)(row & 15)*8 + (size_t)(c & 7);
    Xh[base] = h;
    Xl[base] = l;
}

// ---------------------------------------------------------------- classifier
// R22: xr staging vectorized to float4 copies (value-identical) and MAC reads
// xx via broadcast b128 — single acc chain keeps ascending-c order, same
// `acc += h*w` contraction -> bit-identical.
__global__ __launch_bounds__(256) void cls1_kernel(
    const float* __restrict__ x1, const float* __restrict__ x2f,
    const float* __restrict__ W, const float* __restrict__ b1,
    float* __restrict__ z, double* __restrict__ partOut)
{
    __shared__ float ws[192*64];
    __shared__ __align__(16) float xr[4*192];
    __shared__ double red[256], red2[256];
    const int t = threadIdx.x, cy = blockIdx.y;
    for (int e = t; e < 192*64; e += 256) {
        int c = e >> 6, cl = e & 63;
        ws[e] = W[c*128 + cy*64 + cl];
    }
    const int pl = t >> 6, c2l = t & 63;
    const float b1v = b1[cy*64 + c2l];
    double ssum = 0., ssq = 0.;
    for (int p0 = blockIdx.x*4; p0 < BN_; p0 += gridDim.x*4) {
        __syncthreads();
        for (int l = t; l < 192; l += 256) {   // 192 float4s = 768 floats
            int pp = l / 48, cc4 = l % 48;
            float4 vsrc = (cc4 < 16)
                ? ((const float4*)(x1 + (size_t)(p0+pp)*64))[cc4]
                : ((const float4*)(x2f + (size_t)(p0+pp)*128))[cc4 - 16];
            ((float4*)xr)[pp*48 + cc4] = vsrc;
        }
        __syncthreads();
        float acc = b1v;
        const float4* xx4 = (const float4*)(xr + pl*192);
        for (int c4 = 0; c4 < 48; ++c4) {
            float4 hv = xx4[c4];               // wave-uniform -> broadcast
            acc += hv.x * ws[(c4*4+0)*64 + c2l];
            acc += hv.y * ws[(c4*4+1)*64 + c2l];
            acc += hv.z * ws[(c4*4+2)*64 + c2l];
            acc += hv.w * ws[(c4*4+3)*64 + c2l];
        }
        z[(p0+pl)*128 + cy*64 + c2l] = acc;
        double ad = (double)acc;
        ssum += ad; ssq += ad*ad;
    }
    __syncthreads();
    red[t] = ssum; red2[t] = ssq;
    __syncthreads();
    if (t < 64) {
        double s = red[t], s2 = red2[t];
        #pragma unroll
        for (int g = 1; g < 4; ++g) { s += red[g*64 + t]; s2 += red2[g*64 + t]; }
        // partial row layout [512][256]: (sum ch0..127, sumsq ch0..127); the two
        // cy-planes of the same blockIdx.x fill disjoint 64-ch ranges.
        partOut[(size_t)blockIdx.x*256 + cy*64 + t] = s;
        partOut[(size_t)blockIdx.x*256 + 128 + cy*64 + t] = s2;
    }
}

__global__ __launch_bounds__(256) void cls_fin_kernel(
    const float* __restrict__ z, const float* __restrict__ st,
    const float* __restrict__ g, const float* __restrict__ be,
    const float* __restrict__ w2, const float* __restrict__ b2,
    float* __restrict__ out)
{
    const int t = threadIdx.x, w = t >> 6, L = t & 63;
    const int p = blockIdx.x*4 + w;
    float s = 0.f;
    #pragma unroll
    for (int h = 0; h < 2; ++h) {
        int c = L + h*64;
        float v = (z[p*128 + c] - st[256 + c]) * st[384 + c] * g[c] + be[c];
        s += fmaxf(v, 0.f) * w2[c];
    }
    #pragma unroll
    for (int off = 32; off; off >>= 1) s += __shfl_xor(s, off);
    if (L == 0) out[p] = s + b2[0];
}

// ---------------------------------------------------------------- launch
extern "C" void kernel_launch(void* const* d_in, const int* in_sizes, int n_in,
                              void* d_out, int out_size, void* d_ws, size_t ws_size,
                              hipStream_t stream)
{
    const float* x      = (const float*)d_in[0];
    const float* c1_w1  = (const float*)d_in[1];
    const float* c1_b1  = (const float*)d_in[2];
    const float* c1_g1  = (const float*)d_in[3];
    const float* c1_be1 = (const float*)d_in[4];
    const float* c1_w2  = (const float*)d_in[5];
    const float* c1_b2  = (const float*)d_in[6];
    const float* c1_g2  = (const float*)d_in[7];
    const float* c1_be2 = (const float*)d_in[8];
    const float* c2_w1  = (const float*)d_in[9];
    const float* c2_b1  = (const float*)d_in[10];
    const float* c2_g1  = (const float*)d_in[11];
    const float* c2_be1 = (const float*)d_in[12];
    const float* c2_w2  = (const float*)d_in[13];
    const float* c2_b2  = (const float*)d_in[14];
    const float* c2_g2  = (const float*)d_in[15];
    const float* c2_be2 = (const float*)d_in[16];
    const float* cls_w1 = (const float*)d_in[17];
    const float* cls_b1 = (const float*)d_in[18];
    const float* cls_g1 = (const float*)d_in[19];
    const float* cls_be1= (const float*)d_in[20];
    const float* cls_w2 = (const float*)d_in[21];
    const float* cls_b2 = (const float*)d_in[22];
    (void)in_sizes; (void)n_in; (void)out_size; (void)ws_size;

    char* ws = (char*)d_ws;
    size_t off = 0;
    auto alloc = [&](size_t bytes) { char* p = ws + off; off += (bytes + 255) & ~255ull; return p; };
    float* A    = (float*)alloc((size_t)16<<20);   // P1 -> P2 -> zcls
    float* Bq   = (float*)alloc((size_t)16<<20);   // Q1 -> Q2 -> cls partials
    float* zmax = (float*)alloc((size_t)16<<20);   // also hosts Xh/Xl between conv1 and conv2
    float* zmin = (float*)alloc((size_t)16<<20);
    float* x1b  = (float*)alloc((size_t)8<<20);
    float* x2b  = (float*)alloc((size_t)16<<20);   // also hosts idx24 + stats partials (dead windows)
    int*   idx  = (int*)  alloc((size_t)BN_*K_*4); // idx1 -> idx2
    float* nrm  = (float*)alloc((size_t)BN_*4);
    float* st   = (float*)alloc((size_t)5*512*4);
    unsigned short* w2th = (unsigned short*)alloc((size_t)128*128*2);  // W2^T hi
    unsigned short* w2tl = (unsigned short*)alloc((size_t)128*128*2);  // W2^T lo
    float *st0 = st, *st1 = st+512, *st2 = st+1024, *st3 = st+1536, *st4 = st+2048;

    unsigned short* Xh = (unsigned short*)zmax;                       // 4 MB (tiled layout, R17)
    unsigned short* Xl = (unsigned short*)((char*)zmax + (4<<20));    // 4 MB
    int* idx24 = (int*)x2b;
    double* part  = (double*)x2b;  // fp64 stats partials (max 4 MB): free during both conv phases
    double* partC = (double*)Bq;   // cls stats partials (1 MB): Q2 dead after conv_l2_mfma

    // ---- EdgeConv 1 (exact fp32 conv: x1b feeds flip-sensitive kNN2)
    knn4_kernel<<<dim3(N_/16, B_), 1024, 0, stream>>>(x, idx);
    pq1_kernel<<<BN_/4, 256, 0, stream>>>(x, c1_w1, c1_b1, A, Bq);
    stats_l1_kernel<64><<<2048, 256, 0, stream>>>(A, Bq, idx, part);
    finalize_parts_kernel<<<64, 256, 0, stream>>>(part, 2048, 64, 1.0/655360.0, st0);
    conv_l2_kernel<64><<<dim3(2048,1), 256, 0, stream>>>(A, Bq, idx, st0, c1_g1, c1_be1, c1_w2, c1_b2, zmax, zmin, part);
    finalize_parts_kernel<<<64, 256, 0, stream>>>(part, 2048, 64, 1.0/655360.0, st1);
    // NOTE: conv_fin<64> + nrm + prep fused — but Xh/Xl alias zmax, which this
    // kernel still READS (zmax/zmin inputs).  Writes land at e-dependent tiled
    // addresses within the same 8MB window... zmax[e] is read BEFORE Xh[base]
    // is written within a thread, but other threads' reads may race with our
    // writes.  AVOIDED: write Xh/Xl into the zmin-adjacent free region instead
    // (x2b+8MB window is free here) — see pointer args below.
    conv_fin64_prep_kernel<<<BN_*64/256, 256, 0, stream>>>(zmax, zmin, st1, c1_g2, c1_be2, x1b,
                                                           (unsigned short*)((char*)x2b + (8<<20)),
                                                           (unsigned short*)((char*)x2b + (12<<20)), nrm);
    unsigned short* Xh2 = (unsigned short*)((char*)x2b + (8<<20));
    unsigned short* Xl2 = (unsigned short*)((char*)x2b + (12<<20));

    // ---- EdgeConv 2 (MFMA conv: x2b only feeds classifier)
    knn64v4_kernel<<<dim3(N_/16, B_), 1024, 0, stream>>>(Xh2, Xl2, nrm, idx24);
    rescore_kernel<<<BN_/4, 256, 0, stream>>>(x1b, nrm, idx24, idx);
    pq2_kernel<<<1024, 256, 0, stream>>>(x1b, c2_w1, c2_b1, A, Bq);
    stats_l1_kernel<128><<<2048, 256, 0, stream>>>(A, Bq, idx, part);
    finalize_parts_kernel<<<128, 256, 0, stream>>>(part, 2048, 128, 1.0/655360.0, st2);
    prep_w2t_kernel<<<128*128/256, 256, 0, stream>>>(c2_w2, w2th, w2tl, 128);
    conv_l2_mfma_kernel<128><<<2048, 256, 0, stream>>>(A, Bq, idx, st2, c2_g1, c2_be1, w2th, w2tl, c2_b2, zmax, zmin, part);
    finalize_parts_kernel<<<128, 256, 0, stream>>>(part, 2048, 128, 1.0/655360.0, st3);
    conv_fin_kernel<128><<<BN_*128/256, 256, 0, stream>>>(zmax, zmin, st3, c2_g2, c2_be2, x2b);

    // ---- classifier
    cls1_kernel<<<dim3(512,2), 256, 0, stream>>>(x1b, x2b, cls_w1, cls_b1, A, partC);
    finalize_parts_kernel<<<128, 256, 0, stream>>>(partC, 512, 128, 1.0/32768.0, st4);
    cls_fin_kernel<<<BN_/4, 256, 0, stream>>>(A, st4, cls_g1, cls_be1, cls_w2, cls_b2, (float*)d_out);
}

// Round 14
// 1174.586 us; speedup vs baseline: 1.3050x; 1.0274x over previous
//
#include <hip/hip_runtime.h>
#include <math.h>

#define B_ 8
#define N_ 4096
#define K_ 20
#define KS_ 24          // approx-select width; exact rescore trims to K_ (R3-validated margin)
#define BN_ (B_*N_)

typedef __attribute__((ext_vector_type(8))) short bf16x8;
typedef __attribute__((ext_vector_type(4))) float f32x4;

// ---------------------------------------------------------------- BN stats finalize (deterministic, fp64)
// R10: float atomicAdd stats were order-nondeterministic across graph replays ->
// kNN2 boundary flip -> post-timing divergence.  R11: the deterministic fp32
// order landed on the WRONG side of a ~1-ULP distance tie (absmax 0.1177).
// All stats now accumulate in DOUBLE (partials + reduce + mean/var/rstd); the
// x1b-feeding BN applies the reference's elementwise op order; rescore uses the
// reference's full d formula.  DO NOT reintroduce atomicAdd or fold these back
// into fp32/FMA on the conv1 path.
// part layout: [nb][2*H] doubles (sum(H), sumsq(H) per block row).
__global__ __launch_bounds__(256) void finalize_parts_kernel(
    const double* __restrict__ part, int nb, int H, double invCount, float* __restrict__ st)
{
    __shared__ double red[256], red2[256];
    const int c = blockIdx.x, t = threadIdx.x;
    double s = 0., s2 = 0.;
    for (int b = t; b < nb; b += 256) {
        s  += part[(size_t)b*2*H + c];
        s2 += part[(size_t)b*2*H + H + c];
    }
    red[t] = s; red2[t] = s2;
    __syncthreads();
    #pragma unroll
    for (int off = 128; off; off >>= 1) {
        if (t < off) { red[t] += red[t+off]; red2[t] += red2[t+off]; }
        __syncthreads();
    }
    if (t == 0) {
        double mean = red[0] * invCount;
        double var  = fmax(red2[0] * invCount - mean * mean, 0.);
        st[2*H + c] = (float)mean;
        st[3*H + c] = (float)(1.0 / sqrt(var + 1e-5));
    }
}

// ---------------------------------------------------------------- kNN, C=4
// R7-validated (value, candidate-index) lexicographic argmin — matches jax
// top_k tie-break; reference-defining (no rescore guard) -> selection EXACT.
// R15: rolled loops (L1I); d[64] eliminated via fused compute+insert; rescans
// recompute dists (bit-identical).  DO NOT replace with DPP (R9).
// R21 ERRATA: R20's nt[] |c|^2 precompute (+unroll 4) changed FMA contraction
// of the distance -> flipped a reference top_k tie -> absmax 0.164 FAIL.
// knn4's distance arithmetic is FROZEN in exactly this form.  DO NOT hoist,
// precompute, or re-unroll anything in the scan/rescan bodies.  R22: selection
// restructure also ruled out (R5: issue-bound, 2-winner rounds add VALU).
__global__ __launch_bounds__(1024, 8) void knn4_kernel(const float* __restrict__ x, int* __restrict__ idxout)
{
    __shared__ float4 xt[N_];   // 64 KB
    const int b = blockIdx.y;
    const int t = threadIdx.x;
    const float4* xg = (const float4*)x + b*N_;
    for (int e = t; e < N_; e += 1024) xt[e] = xg[e];
    __syncthreads();
    const int w = t >> 6, L = t & 63;
    const int n = blockIdx.x*16 + w;
    const float4 q = xt[n];
    const float MX = 3.4e38f;
    float m1 = MX, m2 = MX, m3 = MX; int i1 = 0, i2 = 0, i3 = 0;
    #pragma unroll 1
    for (int j = 0; j < 64; ++j) {
        float4 vv = xt[(j<<6) | L];
        float nn = vv.x*vv.x + vv.y*vv.y + vv.z*vv.z + vv.w*vv.w;
        float dp = q.x*vv.x + q.y*vv.y + q.z*vv.z + q.w*vv.w;
        float v = nn - 2.f*dp;   // |xn|^2 dropped: rank-equivalent
        bool c1 = v < m1, c2 = v < m2, c3 = v < m3;
        m3 = c2 ? m2 : (c3 ? v : m3);
        i3 = c2 ? i2 : (c3 ? j : i3);
        m2 = c1 ? m1 : (c2 ? v : m2);
        i2 = c1 ? i1 : (c2 ? j : i2);
        m1 = c1 ? v : m1;
        i1 = c1 ? j : i1;
    }
    unsigned long long used = 0;
    int mywin = 0;
    #pragma unroll 1
    for (int r = 0; r < K_; ++r) {
        float bv = m1; int bg = (i1<<6) | L;
        #pragma unroll
        for (int off = 32; off; off >>= 1) {
            float ov = __shfl_xor(bv, off);
            int   og = __shfl_xor(bg, off);
            bool tk = (ov < bv) || (ov == bv && og < bg);
            bv = tk ? ov : bv; bg = tk ? og : bg;
        }
        if (L == r) mywin = bg;
        if (L == (bg & 63)) {
            used |= 1ull << i1;
            m1 = m2; i1 = i2; m2 = m3; i2 = i3; m3 = MX;
            if (m1 == MX) {
                m2 = MX; m3 = MX; i1 = 0; i2 = 0; i3 = 0;
                #pragma unroll 1
                for (int j = 0; j < 64; ++j) {
                    float4 vv = xt[(j<<6) | L];
                    float nn = vv.x*vv.x + vv.y*vv.y + vv.z*vv.z + vv.w*vv.w;
                    float dp = q.x*vv.x + q.y*vv.y + q.z*vv.z + q.w*vv.w;
                    float dj = nn - 2.f*dp;
                    float v = ((used >> j) & 1ull) ? MX : dj;
                    bool c1 = v < m1, c2 = v < m2, c3 = v < m3;
                    m3 = c2 ? m2 : (c3 ? v : m3);
                    i3 = c2 ? i2 : (c3 ? j : i3);
                    m2 = c1 ? m1 : (c2 ? v : m2);
                    i2 = c1 ? i1 : (c2 ? j : i2);
                    m1 = c1 ? v : m1;
                    i1 = c1 ? j : i1;
                }
            }
        }
    }
    if (L < K_) idxout[(b*N_ + n)*K_ + L] = mywin;
}

// ---------------------------------------------------------------- fp32 -> bf16 RNE
static __device__ inline unsigned short f2bf(float f)
{
    unsigned u = __float_as_uint(f);
    unsigned r = (u + 0x7fffu + ((u >> 16) & 1u)) >> 16;   // RNE
    return (unsigned short)r;
}

// comparator: (x,y) -> (min,max)
#define CE_(x,y) { float _t = fminf(x,y); y = fmaxf(x,y); x = _t; }
// Batcher odd-even sort-8 (19 CE)
#define SORT8_(g0,g1,g2,g3,g4,g5,g6,g7)                                   \
    CE_(g0,g1) CE_(g2,g3) CE_(g4,g5) CE_(g6,g7)                           \
    CE_(g0,g2) CE_(g1,g3) CE_(g4,g6) CE_(g5,g7)                           \
    CE_(g1,g2) CE_(g5,g6)                                                 \
    CE_(g0,g4) CE_(g1,g5) CE_(g2,g6) CE_(g3,g7)                           \
    CE_(g2,g4) CE_(g3,g5)                                                 \
    CE_(g1,g2) CE_(g3,g4) CE_(g5,g6)
// keep lowest-8 (sorted) of two sorted-asc 8-lists: sm = low8(sm, g)
#define MERGE8_(g0,g1,g2,g3,g4,g5,g6,g7)                                  \
    sm0 = fminf(sm0,g7); sm1 = fminf(sm1,g6); sm2 = fminf(sm2,g5);        \
    sm3 = fminf(sm3,g4); sm4 = fminf(sm4,g3); sm5 = fminf(sm5,g2);        \
    sm6 = fminf(sm6,g1); sm7 = fminf(sm7,g0);                             \
    CE_(sm0,sm4) CE_(sm1,sm5) CE_(sm2,sm6) CE_(sm3,sm7)                   \
    CE_(sm0,sm2) CE_(sm1,sm3) CE_(sm4,sm6) CE_(sm5,sm7)                   \
    CE_(sm0,sm1) CE_(sm2,sm3) CE_(sm4,sm5) CE_(sm6,sm7)

// ---------------------------------------------------------------- kNN, C=64 via MFMA (split-bf16 Gram, approx)
// v12 (R19): 32KB dist tile (8 chunks of 512) -> 2 blocks/CU resident;
// SORT8+MERGE8 scan per chunk; slot = ck*8 + (cm>>6); lane residue preserved.
// Selection (R16 bitonic 8-merge butterfly + ballot pops), keys (R12), tiled
// layout (R17), strength-reduced staging (R18), top-8 dropout P~5e-9 (R14).
__global__ __launch_bounds__(1024, 4) void knn64v4_kernel(
    const unsigned short* __restrict__ Xh, const unsigned short* __restrict__ Xl,
    const float* __restrict__ nrm, int* __restrict__ idx24)
{
    __shared__ float dist[16*512];   // 32 KB -> 2 blocks/CU resident
    const int b = blockIdx.y, t = threadIdx.x;
    const int w = t >> 6, L = t & 63;
    const int q0 = blockIdx.x * 16;
    const int m = L & 15, q4 = L >> 4;
    const size_t rowbase = (size_t)b * N_ * 64;
    const int swzW = q4 << 4;         // write-side column XOR (qrow>>2 == q4)
    const int swzR = (w >> 2) << 4;   // read-side column XOR (query row w)
    const int fragoff = q4*128 + m*8; // within-tile fragment offset (shorts)

    // A fragments: tile q0>>4
    const unsigned short* aph = Xh + rowbase + (size_t)(q0 >> 4)*1024 + fragoff;
    const unsigned short* apl = Xl + rowbase + (size_t)(q0 >> 4)*1024 + fragoff;
    const bf16x8 a_h0 = *(const bf16x8*)(aph);
    const bf16x8 a_h1 = *(const bf16x8*)(aph + 512);
    const bf16x8 a_l0 = *(const bf16x8*)(apl);
    const bf16x8 a_l1 = *(const bf16x8*)(apl + 512);

    const float MX = 3.4e38f;
    float sm0 = MX, sm1 = MX, sm2 = MX, sm3 = MX, sm4 = MX, sm5 = MX, sm6 = MX, sm7 = MX;

    float* const wrow = dist + q4*2048;        // q4*4*512
    float* const rrow = dist + w*512 + (L ^ swzR);

    #pragma unroll 1
    for (int ck = 0; ck < 8; ++ck) {
        const unsigned slotW0 = (unsigned)(ck*8);
        // strength-reduced staging pointers for this ck (each wave: 2 sub-tiles)
        const unsigned short* bp_h = Xh + rowbase + (size_t)(ck*32 + w*2)*1024 + fragoff;
        const unsigned short* bp_l = Xl + rowbase + (size_t)(ck*32 + w*2)*1024 + fragoff;
        const float* np = nrm + b*N_ + ck*512 + w*32 + m;
        int cm = w*32 + m;
        __syncthreads();
        #pragma unroll
        for (int tt = 0; tt < 2; ++tt) {
            bf16x8 b_h0 = *(const bf16x8*)(bp_h);
            bf16x8 b_h1 = *(const bf16x8*)(bp_h + 512);
            bf16x8 b_l0 = *(const bf16x8*)(bp_l);
            bf16x8 b_l1 = *(const bf16x8*)(bp_l + 512);
            f32x4 acc = {0.f, 0.f, 0.f, 0.f};
            acc = __builtin_amdgcn_mfma_f32_16x16x32_bf16(a_h0, b_h0, acc, 0, 0, 0);
            acc = __builtin_amdgcn_mfma_f32_16x16x32_bf16(a_h1, b_h1, acc, 0, 0, 0);
            acc = __builtin_amdgcn_mfma_f32_16x16x32_bf16(a_l0, b_h0, acc, 0, 0, 0);
            acc = __builtin_amdgcn_mfma_f32_16x16x32_bf16(a_l1, b_h1, acc, 0, 0, 0);
            acc = __builtin_amdgcn_mfma_f32_16x16x32_bf16(a_h0, b_l0, acc, 0, 0, 0);
            acc = __builtin_amdgcn_mfma_f32_16x16x32_bf16(a_h1, b_l1, acc, 0, 0, 0);
            const float nv = *np;
            const int colW = cm ^ swzW;
            const unsigned slotW = slotW0 + (unsigned)(cm >> 6);
            float* wp = wrow + colW;
            #pragma unroll
            for (int r = 0; r < 4; ++r) {
                float dv = nv - 2.f*acc[r];
                unsigned key = (__float_as_uint(dv) & ~63u) | slotW;
                wp[r*512] = __uint_as_float(key);
            }
            bp_h += 1024; bp_l += 1024; np += 16; cm += 16;
        }
        __syncthreads();
        // scan this ck's 8 values: one sorted group of 8, merged into sm
        {
            float g0 = rrow[0*64], g1 = rrow[1*64], g2 = rrow[2*64], g3 = rrow[3*64];
            float g4 = rrow[4*64], g5 = rrow[5*64], g6 = rrow[6*64], g7 = rrow[7*64];
            SORT8_(g0,g1,g2,g3,g4,g5,g6,g7)
            MERGE8_(g0,g1,g2,g3,g4,g5,g6,g7)
        }
    }

    int mywin = 0;
    #pragma unroll 1
    for (int sr = 0; sr < 3; ++sr) {
        // butterfly all-reduce: global sorted top-8 of the union of all lanes' lists
        float a0 = sm0, a1 = sm1, a2 = sm2, a3 = sm3, a4 = sm4, a5 = sm5, a6 = sm6, a7 = sm7;
        #pragma unroll
        for (int off = 32; off; off >>= 1) {
            float b0 = __shfl_xor(a0, off), b1 = __shfl_xor(a1, off);
            float b2 = __shfl_xor(a2, off), b3 = __shfl_xor(a3, off);
            float b4 = __shfl_xor(a4, off), b5 = __shfl_xor(a5, off);
            float b6 = __shfl_xor(a6, off), b7 = __shfl_xor(a7, off);
            float c0 = fminf(a0, b7), c1 = fminf(a1, b6), c2 = fminf(a2, b5), c3 = fminf(a3, b4);
            float c4 = fminf(a4, b3), c5 = fminf(a5, b2), c6 = fminf(a6, b1), c7 = fminf(a7, b0);
            float u;
            u = fminf(c0, c4); c4 = fmaxf(c0, c4); c0 = u;
            u = fminf(c1, c5); c5 = fmaxf(c1, c5); c1 = u;
            u = fminf(c2, c6); c6 = fmaxf(c2, c6); c2 = u;
            u = fminf(c3, c7); c7 = fmaxf(c3, c7); c3 = u;
            u = fminf(c0, c2); c2 = fmaxf(c0, c2); c0 = u;
            u = fminf(c1, c3); c3 = fmaxf(c1, c3); c1 = u;
            u = fminf(c4, c6); c6 = fmaxf(c4, c6); c4 = u;
            u = fminf(c5, c7); c7 = fmaxf(c5, c7); c5 = u;
            u = fminf(c0, c1); c1 = fmaxf(c0, c1); c0 = u;
            u = fminf(c2, c3); c3 = fmaxf(c2, c3); c2 = u;
            u = fminf(c4, c5); c5 = fmaxf(c4, c5); c4 = u;
            u = fminf(c6, c7); c7 = fmaxf(c6, c7); c6 = u;
            a0 = c0; a1 = c1; a2 = c2; a3 = c3; a4 = c4; a5 = c5; a6 = c6; a7 = c7;
        }
        // extract the 8 winners in ascending order (set semantics; min-lane on ties)
        #define POPW(AW, WIDX)                                                              \
        {                                                                                   \
            const unsigned long long bal = __ballot(sm0 == (AW));                           \
            const int owner = (int)__ffsll(bal) - 1;                                        \
            if (L == sr*8 + (WIDX))                                                         \
                mywin = (int)(((__float_as_uint(AW) & 63u) << 6) | (unsigned)owner);        \
            if (L == owner) {                                                               \
                sm0 = sm1; sm1 = sm2; sm2 = sm3; sm3 = sm4;                                 \
                sm4 = sm5; sm5 = sm6; sm6 = sm7; sm7 = MX;                                  \
            }                                                                               \
        }
        POPW(a0, 0) POPW(a1, 1) POPW(a2, 2) POPW(a3, 3)
        POPW(a4, 4) POPW(a5, 5) POPW(a6, 6) POPW(a7, 7)
        #undef POPW
    }
    if (L < KS_) idx24[((size_t)b*N_ + q0 + w)*KS_ + L] = mywin;
}

// ---------------------------------------------------------------- exact fp32 rescore of the KS_ candidates
// R11: d matches the reference formula exactly.  R13: two winners per round.
// Exact: every lane holds ONE always-valid candidate; indices unique.
__global__ __launch_bounds__(256) void rescore_kernel(const float* __restrict__ x1, const float* __restrict__ nrm,
                                                      const int* __restrict__ idx24, int* __restrict__ idxout)
{
    const int t = threadIdx.x, w = t >> 6, L = t & 63;
    const int p = blockIdx.x*4 + w;
    const int bbase = p & ~(N_-1);
    const float MX = 3.4e38f;
    float dv = MX; int di = 0x7fffffff;
    if (L < KS_) {
        const int ci = idx24[(size_t)p*KS_ + L];
        const float4* qr = (const float4*)(x1 + (size_t)p*64);
        const float4* cr = (const float4*)(x1 + (size_t)(bbase + ci)*64);
        float dot = 0.f;
        #pragma unroll
        for (int i = 0; i < 16; ++i) {
            float4 a = qr[i], bx = cr[i];
            dot += a.x*bx.x + a.y*bx.y + a.z*bx.z + a.w*bx.w;
        }
        dv = __fsub_rn(__fadd_rn(nrm[p], nrm[bbase + ci]), 2.f*dot);
        di = ci;
    }
    int myfin = 0;
    #pragma unroll 1
    for (int r = 0; r < K_/2; ++r) {
        float v1 = dv; int g1 = di;
        float v2 = MX; int g2 = 0x7fffffff;
        #pragma unroll
        for (int off = 32; off; off >>= 1) {
            float ov1 = __shfl_xor(v1, off); int og1 = __shfl_xor(g1, off);
            float ov2 = __shfl_xor(v2, off); int og2 = __shfl_xor(g2, off);
            bool c1 = (ov1 < v1) || (ov1 == v1 && og1 < g1);
            float hv = c1 ? v1 : ov1; int hg = c1 ? g1 : og1;
            v1 = c1 ? ov1 : v1;       g1 = c1 ? og1 : g1;
            bool c2 = (ov2 < v2) || (ov2 == v2 && og2 < g2);
            float l2v = c2 ? ov2 : v2; int l2g = c2 ? og2 : g2;
            bool c3 = (l2v < hv) || (l2v == hv && l2g < hg);
            v2 = c3 ? l2v : hv;  g2 = c3 ? l2g : hg;
        }
        if (L == 2*r)   myfin = g1;
        if (L == 2*r+1) myfin = g2;
        if (di == g1 || di == g2) dv = MX;
    }
    if (L < K_) idxout[(size_t)p*K_ + L] = myfin;
}

// ---------------------------------------------------------------- P/Q precompute
__global__ __launch_bounds__(256) void pq1_kernel(const float* __restrict__ x, const float* __restrict__ W,
                                                  const float* __restrict__ b1,
                                                  float* __restrict__ P, float* __restrict__ Q)
{
    __shared__ float wd[256], wb[256];
    const int t = threadIdx.x;
    wd[t] = W[t] - W[256 + t];
    wb[t] = W[256 + t];
    __syncthreads();
    const int p = blockIdx.x*4 + (t >> 6), c = t & 63;
    const float4 xv = ((const float4*)x)[p];
    float Pv = b1[c] + xv.x*wd[c] + xv.y*wd[64+c] + xv.z*wd[128+c] + xv.w*wd[192+c];
    float Qv =         xv.x*wb[c] + xv.y*wb[64+c] + xv.z*wb[128+c] + xv.w*wb[192+c];
    P[p*64 + c] = Pv;
    Q[p*64 + c] = Qv;
}

// R23: thread remap (2p x 128c) -> (8p x 32 c-quads): each thread computes 4
// consecutive channels, reading wd/wb as coalesced float4 LDS b128 (4x fewer
// LDS instructions, same bytes).  Each channel's accumulator keeps its
// ascending-k `Pv += xv*w` chain with the identical contraction form ->
// BIT-IDENTICAL P2/Q2.  Output: float4 stores.
__global__ __launch_bounds__(256) void pq2_kernel(const float* __restrict__ x1, const float* __restrict__ W,
                                                  const float* __restrict__ b1,
                                                  float* __restrict__ P, float* __restrict__ Q)
{
    __shared__ __align__(16) float wd[64*128], wb[64*128];
    const int t = threadIdx.x;
    for (int e = t; e < 8192; e += 256) {
        float wt = W[e], wbo = W[8192 + e];
        wd[e] = wt - wbo; wb[e] = wbo;
    }
    __syncthreads();
    const int pl = t >> 5, c4 = (t & 31) * 4;
    const float4 b1v = *(const float4*)(b1 + c4);
    for (int p0 = blockIdx.x*8; p0 < BN_; p0 += gridDim.x*8) {
        const int p = p0 + pl;
        float4 Pv = b1v;
        float4 Qv = {0.f, 0.f, 0.f, 0.f};
        const float* xrow = x1 + (size_t)p*64;
        #pragma unroll 8
        for (int k = 0; k < 64; ++k) {
            float xv = xrow[k];
            float4 w4 = *(const float4*)(wd + k*128 + c4);
            float4 v4 = *(const float4*)(wb + k*128 + c4);
            Pv.x += xv * w4.x; Pv.y += xv * w4.y; Pv.z += xv * w4.z; Pv.w += xv * w4.w;
            Qv.x += xv * v4.x; Qv.y += xv * v4.y; Qv.z += xv * v4.z; Qv.w += xv * v4.w;
        }
        *(float4*)(P + (size_t)p*128 + c4) = Pv;
        *(float4*)(Q + (size_t)p*128 + c4) = Qv;
    }
}

// ---------------------------------------------------------------- layer-1 BN stats (fp64 per-block partials)
template<int HO>
__global__ __launch_bounds__(256) void stats_l1_kernel(const float* __restrict__ P, const float* __restrict__ Q,
                                                       const int* __restrict__ idx, double* __restrict__ partOut)
{
    constexpr int G = 256/HO;
    __shared__ double red[256], red2[256];
    const int t = threadIdx.x, c = t % HO, g = t / HO;
    double s = 0., s2 = 0.;
    for (int p = blockIdx.x; p < BN_; p += gridDim.x) {
        const float Pv = P[p*HO + c];
        const int bbase = p & ~(N_-1);
        for (int j = g; j < K_; j += G) {
            int m = idx[p*K_ + j];
            float z = Pv + Q[(bbase + m)*HO + c];
            double zd = (double)z;
            s += zd; s2 += zd*zd;
        }
    }
    red[t] = s; red2[t] = s2;
    __syncthreads();
    if (t < HO) {
        double a = red[t], a2 = red2[t];
        #pragma unroll
        for (int q = 1; q < G; ++q) { a += red[q*HO + t]; a2 += red2[q*HO + t]; }
        partOut[(size_t)blockIdx.x*(2*HO) + t] = a;
        partOut[(size_t)blockIdx.x*(2*HO) + HO + t] = a2;
    }
}

// ---------------------------------------------------------------- EdgeConv layer-2, exact fp32 (conv1:
// its output feeds kNN2, which is flip-sensitive to ~1e-4 feature perturbation).
// R11: BN applied in the reference's elementwise op order (((z-m)*rstd)*g+be,
// separately rounded).  R22: MAC loop vectorized — h1s reads are wave-uniform
// -> broadcast b128 (4 c's at once); each acc[q] chain still accumulates in
// ascending-c order with the same `acc += h*w` contraction form -> BIT-IDENTICAL.
template<int HO>
__global__ __launch_bounds__(256) void conv_l2_kernel(
    const float* __restrict__ P, const float* __restrict__ Q, const int* __restrict__ idx,
    const float* __restrict__ st1, const float* __restrict__ g1, const float* __restrict__ be1,
    const float* __restrict__ w2, const float* __restrict__ b2,
    float* __restrict__ zmax, float* __restrict__ zmin, double* __restrict__ partOut)
{
    __shared__ float w2s[HO*64];
    __shared__ __align__(16) float h1s[K_*HO];
    __shared__ float redA[256], redB[256];
    __shared__ double redD[256], redD2[256];
    const int t = threadIdx.x;
    const int cy = blockIdx.y;
    for (int e = t; e < HO*64; e += 256) {
        int c = e >> 6, cl = e & 63;
        w2s[e] = w2[c*HO + cy*64 + cl];
    }
    const int cA = t % HO;
    const float mA = st1[2*HO + cA], rA = st1[3*HO + cA];
    const float gA = g1[cA], beA = be1[cA];
    const int c2l = t & 63, jh = t >> 6;
    const float b2v = b2[cy*64 + c2l];
    double ssum = 0., ssq = 0.;
    for (int p = blockIdx.x; p < BN_; p += gridDim.x) {
        __syncthreads();
        const int bbase = p & ~(N_-1);
        const float Pv = P[p*HO + cA];
        for (int e = t; e < K_*HO; e += 256) {
            int j = e / HO;
            int m = idx[p*K_ + j];
            float z = Pv + Q[(bbase + m)*HO + cA];
            float bn = __fadd_rn(__fmul_rn(__fmul_rn(__fsub_rn(z, mA), rA), gA), beA);
            h1s[e] = fmaxf(bn, 0.f);
        }
        __syncthreads();
        float acc[5];
        #pragma unroll
        for (int q = 0; q < 5; ++q) acc[q] = b2v;
        const float4* h1v = (const float4*)h1s;
        for (int c4 = 0; c4 < HO/4; ++c4) {
            const float w0 = w2s[(c4*4+0)*64 + c2l];
            const float w1 = w2s[(c4*4+1)*64 + c2l];
            const float w2v = w2s[(c4*4+2)*64 + c2l];
            const float w3 = w2s[(c4*4+3)*64 + c2l];
            #pragma unroll
            for (int q = 0; q < 5; ++q) {
                float4 hv = h1v[(jh + q*4)*(HO/4) + c4];   // wave-uniform -> broadcast
                acc[q] += hv.x*w0;
                acc[q] += hv.y*w1;
                acc[q] += hv.z*w2v;
                acc[q] += hv.w*w3;
            }
        }
        float mx = acc[0], mn = acc[0];
        #pragma unroll
        for (int q = 0; q < 5; ++q) {
            mx = fmaxf(mx, acc[q]); mn = fminf(mn, acc[q]);
            double ad = (double)acc[q];
            ssum += ad; ssq += ad*ad;
        }
        redA[t] = mx; redB[t] = mn;
        __syncthreads();
        if (t < 64) {
            float M = redA[t], Mn = redB[t];
            #pragma unroll
            for (int g = 1; g < 4; ++g) { M = fmaxf(M, redA[g*64 + t]); Mn = fminf(Mn, redB[g*64 + t]); }
            zmax[p*HO + cy*64 + t] = M;
            zmin[p*HO + cy*64 + t] = Mn;
        }
    }
    __syncthreads();
    redD[t] = ssum; redD2[t] = ssq;
    __syncthreads();
    if (t < 64) {
        double s = redD[t], s2 = redD2[t];
        #pragma unroll
        for (int g = 1; g < 4; ++g) { s += redD[g*64 + t]; s2 += redD2[g*64 + t]; }
        partOut[(size_t)blockIdx.x*(2*HO) + cy*64 + t] = s;
        partOut[(size_t)blockIdx.x*(2*HO) + HO + cy*64 + t] = s2;
    }
}

// ---------------------------------------------------------------- W2^T split-bf16 prep
__global__ __launch_bounds__(256) void prep_w2t_kernel(const float* __restrict__ W,
                                                       unsigned short* __restrict__ wh,
                                                       unsigned short* __restrict__ wl, int HO)
{
    const int e = blockIdx.x*256 + threadIdx.x;   // e = k*HO + c
    const int k = e / HO, c = e % HO;
    const float v = W[e];
    unsigned short h = f2bf(v);
    float hf = __uint_as_float((unsigned)h << 16);
    wh[c*HO + k] = h;
    wl[c*HO + k] = f2bf(v - hf);
}

// ---------------------------------------------------------------- EdgeConv layer-2 via MFMA (split-bf16)
// conv2 only: output feeds the classifier (value-continuous), bf16-split safe.
template<int HO>
__global__ __launch_bounds__(256) void conv_l2_mfma_kernel(
    const float* __restrict__ P, const float* __restrict__ Q, const int* __restrict__ idx,
    const float* __restrict__ st1, const float* __restrict__ g1, const float* __restrict__ be1,
    const unsigned short* __restrict__ w2h, const unsigned short* __restrict__ w2l,
    const float* __restrict__ b2,
    float* __restrict__ zmax, float* __restrict__ zmin, double* __restrict__ partOut)
{
    constexpr int HOP = HO + 8;
    constexpr int CDP = HO + 1;
    constexpr int CTW = HO / 64;
    constexpr int KSn = HO / 32;
    constexpr int HSH = (HO == 128) ? 7 : 6;
    __shared__ __align__(16) short hs[2*80*HOP];
    __shared__ int sidx[80];
    float* cd = (float*)hs;

    const int t = threadIdx.x, w = t >> 6, L = t & 63;
    const int m16 = L & 15, q4 = L >> 4;

    const int kT = t & (HO - 1);
    const float ac = st1[3*HO + kT] * g1[kT];
    const float bc = be1[kT] - st1[2*HO + kT] * ac;

    bf16x8 Bh[CTW][KSn], Bl[CTW][KSn];
    #pragma unroll
    for (int ctl = 0; ctl < CTW; ++ctl)
        #pragma unroll
        for (int ks = 0; ks < KSn; ++ks) {
            const int c  = w*16*CTW + ctl*16 + m16;
            const int k0 = ks*32 + q4*8;
            Bh[ctl][ks] = *(const bf16x8*)(w2h + c*HO + k0);
            Bl[ctl][ks] = *(const bf16x8*)(w2l + c*HO + k0);
        }

    const float b2c = (t < HO) ? b2[t] : 0.f;
    double ssum = 0., ssq = 0.;

    for (int p0 = blockIdx.x*4; p0 < BN_; p0 += gridDim.x*4) {
        const int bbase = p0 & ~(N_-1);
        __syncthreads();
        if (t < 80) sidx[t] = idx[p0*K_ + t];
        __syncthreads();
        for (int e = t; e < 80*HO; e += 256) {
            const int r  = e >> HSH;
            const int pl = (r*3277) >> 16;     // r/20 for r<80
            const int mI = sidx[r];
            float z = P[(size_t)(p0+pl)*HO + kT] + Q[(size_t)(bbase+mI)*HO + kT];
            float h = fmaxf(z*ac + bc, 0.f);
            unsigned short hh = f2bf(h);
            float hf = __uint_as_float((unsigned)hh << 16);
            unsigned short hl = f2bf(h - hf);
            hs[r*HOP + kT] = (short)hh;
            hs[80*HOP + r*HOP + kT] = (short)hl;
        }
        __syncthreads();
        f32x4 acc[5][CTW];
        #pragma unroll
        for (int rt = 0; rt < 5; ++rt)
            #pragma unroll
            for (int ctl = 0; ctl < CTW; ++ctl)
                acc[rt][ctl] = (f32x4){0.f, 0.f, 0.f, 0.f};
        #pragma unroll
        for (int rt = 0; rt < 5; ++rt)
            #pragma unroll
            for (int ks = 0; ks < KSn; ++ks) {
                const short* ap = hs + (rt*16 + m16)*HOP + ks*32 + q4*8;
                bf16x8 Ah = *(const bf16x8*)ap;
                bf16x8 Al = *(const bf16x8*)(ap + 80*HOP);
                #pragma unroll
                for (int ctl = 0; ctl < CTW; ++ctl) {
                    acc[rt][ctl] = __builtin_amdgcn_mfma_f32_16x16x32_bf16(Ah, Bh[ctl][ks], acc[rt][ctl], 0, 0, 0);
                    acc[rt][ctl] = __builtin_amdgcn_mfma_f32_16x16x32_bf16(Al, Bh[ctl][ks], acc[rt][ctl], 0, 0, 0);
                    acc[rt][ctl] = __builtin_amdgcn_mfma_f32_16x16x32_bf16(Ah, Bl[ctl][ks], acc[rt][ctl], 0, 0, 0);
                }
            }
        __syncthreads();
        #pragma unroll
        for (int rt = 0; rt < 5; ++rt)
            #pragma unroll
            for (int ctl = 0; ctl < CTW; ++ctl) {
                const int col = w*16*CTW + ctl*16 + m16;
                #pragma unroll
                for (int ri = 0; ri < 4; ++ri) {
                    const int row = rt*16 + q4*4 + ri;
                    cd[row*CDP + col] = acc[rt][ctl][ri];
                }
            }
        __syncthreads();
        if (t < HO) {
            #pragma unroll
            for (int pl = 0; pl < 4; ++pl) {
                float mx = -3.4e38f, mn = 3.4e38f;
                #pragma unroll
                for (int j = 0; j < K_; ++j) {
                    float v = cd[(pl*20 + j)*CDP + t] + b2c;
                    mx = fmaxf(mx, v); mn = fminf(mn, v);
                    double vd = (double)v;
                    ssum += vd; ssq += vd*vd;
                }
                zmax[(size_t)(p0+pl)*HO + t] = mx;
                zmin[(size_t)(p0+pl)*HO + t] = mn;
            }
        }
    }
    if (t < HO) {
        partOut[(size_t)blockIdx.x*(2*HO) + t] = ssum;
        partOut[(size_t)blockIdx.x*(2*HO) + HO + t] = ssq;
    }
}

// max_j relu(BN(z)) = relu(BN(max_j z)) for gamma>=0, min for gamma<0.
// R11: reference elementwise op order for the x1b-producing instance.
template<int HO>
__global__ __launch_bounds__(256) void conv_fin_kernel(
    const float* __restrict__ zmax, const float* __restrict__ zmin,
    const float* __restrict__ st2, const float* __restrict__ g2, const float* __restrict__ be2,
    float* __restrict__ out)
{
    int e = blockIdx.x*256 + threadIdx.x;
    int c = e & (HO-1);
    float g = g2[c];
    float sel = (g >= 0.f) ? zmax[e] : zmin[e];
    float bn = __fadd_rn(__fmul_rn(__fmul_rn(__fsub_rn(sel, st2[2*HO + c]), st2[3*HO + c]), g), be2[c]);
    out[e] = fmaxf(bn, 0.f);
}

// ---------------------------------------------------------------- fused conv_fin<64> + nrm + split-bf16 tiled prep (R22)
// Same thread->(row,channel) mapping as the old nrmprep (row=e>>6, L=e&63; one
// wave == one row), so the R11-frozen nrm butterfly consumes the just-computed
// x1b value in-register — fp32 store/load is exact, hence BIT-IDENTICAL nrm,
// Xh/Xl (R17 tiled layout), and x1b.  Saves a 2MB x1b read pass + one launch.
__global__ __launch_bounds__(256) void conv_fin64_prep_kernel(
    const float* __restrict__ zmax, const float* __restrict__ zmin,
    const float* __restrict__ st2, const float* __restrict__ g2, const float* __restrict__ be2,
    float* __restrict__ out, unsigned short* __restrict__ Xh, unsigned short* __restrict__ Xl,
    float* __restrict__ nrm)
{
    const int e = blockIdx.x*256 + threadIdx.x;
    const int c = e & 63;
    float g = g2[c];
    float sel = (g >= 0.f) ? zmax[e] : zmin[e];
    float bn = __fadd_rn(__fmul_rn(__fmul_rn(__fsub_rn(sel, st2[128 + c]), st2[192 + c]), g), be2[c]);
    const float v = fmaxf(bn, 0.f);
    out[e] = v;
    float s = v * v;
    #pragma unroll
    for (int off = 32; off; off >>= 1) s += __shfl_xor(s, off);
    const int row = e >> 6;
    if (c == 0) nrm[row] = s;
    unsigned short h = f2bf(v);
    float hf = __uint_as_float((unsigned)h << 16);
    unsigned short l = f2bf(v - hf);
    const size_t base = (size_t)(row >> 4)*1024 + (size_t)(c >> 3)*128 + (size_t)(row & 15)*8 + (size_t)(c & 7);
    Xh[base] = h;
    Xl[base] = l;
}

// ---------------------------------------------------------------- classifier
// R22: xr staging vectorized to float4 copies (value-identical) and MAC reads
// xx via broadcast b128 — single acc chain keeps ascending-c order, same
// `acc += h*w` contraction -> bit-identical.
__global__ __launch_bounds__(256) void cls1_kernel(
    const float* __restrict__ x1, const float* __restrict__ x2f,
    const float* __restrict__ W, const float* __restrict__ b1,
    float* __restrict__ z, double* __restrict__ partOut)
{
    __shared__ float ws[192*64];
    __shared__ __align__(16) float xr[4*192];
    __shared__ double red[256], red2[256];
    const int t = threadIdx.x, cy = blockIdx.y;
    for (int e = t; e < 192*64; e += 256) {
        int c = e >> 6, cl = e & 63;
        ws[e] = W[c*128 + cy*64 + cl];
    }
    const int pl = t >> 6, c2l = t & 63;
    const float b1v = b1[cy*64 + c2l];
    double ssum = 0., ssq = 0.;
    for (int p0 = blockIdx.x*4; p0 < BN_; p0 += gridDim.x*4) {
        __syncthreads();
        for (int l = t; l < 192; l += 256) {   // 192 float4s = 768 floats
            int pp = l / 48, cc4 = l % 48;
            float4 vsrc = (cc4 < 16)
                ? ((const float4*)(x1 + (size_t)(p0+pp)*64))[cc4]
                : ((const float4*)(x2f + (size_t)(p0+pp)*128))[cc4 - 16];
            ((float4*)xr)[pp*48 + cc4] = vsrc;
        }
        __syncthreads();
        float acc = b1v;
        const float4* xx4 = (const float4*)(xr + pl*192);
        for (int c4 = 0; c4 < 48; ++c4) {
            float4 hv = xx4[c4];               // wave-uniform -> broadcast
            acc += hv.x * ws[(c4*4+0)*64 + c2l];
            acc += hv.y * ws[(c4*4+1)*64 + c2l];
            acc += hv.z * ws[(c4*4+2)*64 + c2l];
            acc += hv.w * ws[(c4*4+3)*64 + c2l];
        }
        z[(p0+pl)*128 + cy*64 + c2l] = acc;
        double ad = (double)acc;
        ssum += ad; ssq += ad*ad;
    }
    __syncthreads();
    red[t] = ssum; red2[t] = ssq;
    __syncthreads();
    if (t < 64) {
        double s = red[t], s2 = red2[t];
        #pragma unroll
        for (int g = 1; g < 4; ++g) { s += red[g*64 + t]; s2 += red2[g*64 + t]; }
        // partial row layout [512][256]: (sum ch0..127, sumsq ch0..127); the two
        // cy-planes of the same blockIdx.x fill disjoint 64-ch ranges.
        partOut[(size_t)blockIdx.x*256 + cy*64 + t] = s;
        partOut[(size_t)blockIdx.x*256 + 128 + cy*64 + t] = s2;
    }
}

__global__ __launch_bounds__(256) void cls_fin_kernel(
    const float* __restrict__ z, const float* __restrict__ st,
    const float* __restrict__ g, const float* __restrict__ be,
    const float* __restrict__ w2, const float* __restrict__ b2,
    float* __restrict__ out)
{
    const int t = threadIdx.x, w = t >> 6, L = t & 63;
    const int p = blockIdx.x*4 + w;
    float s = 0.f;
    #pragma unroll
    for (int h = 0; h < 2; ++h) {
        int c = L + h*64;
        float v = (z[p*128 + c] - st[256 + c]) * st[384 + c] * g[c] + be[c];
        s += fmaxf(v, 0.f) * w2[c];
    }
    #pragma unroll
    for (int off = 32; off; off >>= 1) s += __shfl_xor(s, off);
    if (L == 0) out[p] = s + b2[0];
}

// ---------------------------------------------------------------- launch
extern "C" void kernel_launch(void* const* d_in, const int* in_sizes, int n_in,
                              void* d_out, int out_size, void* d_ws, size_t ws_size,
                              hipStream_t stream)
{
    const float* x      = (const float*)d_in[0];
    const float* c1_w1  = (const float*)d_in[1];
    const float* c1_b1  = (const float*)d_in[2];
    const float* c1_g1  = (const float*)d_in[3];
    const float* c1_be1 = (const float*)d_in[4];
    const float* c1_w2  = (const float*)d_in[5];
    const float* c1_b2  = (const float*)d_in[6];
    const float* c1_g2  = (const float*)d_in[7];
    const float* c1_be2 = (const float*)d_in[8];
    const float* c2_w1  = (const float*)d_in[9];
    const float* c2_b1  = (const float*)d_in[10];
    const float* c2_g1  = (const float*)d_in[11];
    const float* c2_be1 = (const float*)d_in[12];
    const float* c2_w2  = (const float*)d_in[13];
    const float* c2_b2  = (const float*)d_in[14];
    const float* c2_g2  = (const float*)d_in[15];
    const float* c2_be2 = (const float*)d_in[16];
    const float* cls_w1 = (const float*)d_in[17];
    const float* cls_b1 = (const float*)d_in[18];
    const float* cls_g1 = (const float*)d_in[19];
    const float* cls_be1= (const float*)d_in[20];
    const float* cls_w2 = (const float*)d_in[21];
    const float* cls_b2 = (const float*)d_in[22];
    (void)in_sizes; (void)n_in; (void)out_size; (void)ws_size;

    char* ws = (char*)d_ws;
    size_t off = 0;
    auto alloc = [&](size_t bytes) { char* p = ws + off; off += (bytes + 255) & ~255ull; return p; };
    float* A    = (float*)alloc((size_t)16<<20);   // P1 -> P2 -> zcls
    float* Bq   = (float*)alloc((size_t)16<<20);   // Q1 -> Q2 -> cls partials
    float* zmax = (float*)alloc((size_t)16<<20);
    float* zmin = (float*)alloc((size_t)16<<20);
    float* x1b  = (float*)alloc((size_t)8<<20);
    float* x2b  = (float*)alloc((size_t)16<<20);   // also hosts idx24 + stats partials + Xh2/Xl2 (dead windows)
    int*   idx  = (int*)  alloc((size_t)BN_*K_*4); // idx1 -> idx2
    float* nrm  = (float*)alloc((size_t)BN_*4);
    float* st   = (float*)alloc((size_t)5*512*4);
    unsigned short* w2th = (unsigned short*)alloc((size_t)128*128*2);  // W2^T hi
    unsigned short* w2tl = (unsigned short*)alloc((size_t)128*128*2);  // W2^T lo
    float *st0 = st, *st1 = st+512, *st2 = st+1024, *st3 = st+1536, *st4 = st+2048;

    int* idx24 = (int*)x2b;
    double* part  = (double*)x2b;  // fp64 stats partials (max 4 MB): free during both conv phases
    double* partC = (double*)Bq;   // cls stats partials (1 MB): Q2 dead after conv_l2_mfma

    // ---- EdgeConv 1 (exact fp32 conv: x1b feeds flip-sensitive kNN2)
    knn4_kernel<<<dim3(N_/16, B_), 1024, 0, stream>>>(x, idx);
    pq1_kernel<<<BN_/4, 256, 0, stream>>>(x, c1_w1, c1_b1, A, Bq);
    stats_l1_kernel<64><<<2048, 256, 0, stream>>>(A, Bq, idx, part);
    finalize_parts_kernel<<<64, 256, 0, stream>>>(part, 2048, 64, 1.0/655360.0, st0);
    conv_l2_kernel<64><<<dim3(2048,1), 256, 0, stream>>>(A, Bq, idx, st0, c1_g1, c1_be1, c1_w2, c1_b2, zmax, zmin, part);
    finalize_parts_kernel<<<64, 256, 0, stream>>>(part, 2048, 64, 1.0/655360.0, st1);
    // fused conv_fin<64>+nrm+prep writes Xh2/Xl2 into x2b+8MB..+16MB (dead
    // there: idx24/part occupy <8MB; consumed by knn64v4 before conv_fin<128>
    // overwrites x2b — stream-ordered, R22 aliasing audit).
    conv_fin64_prep_kernel<<<BN_*64/256, 256, 0, stream>>>(zmax, zmin, st1, c1_g2, c1_be2, x1b,
                                                           (unsigned short*)((char*)x2b + (8<<20)),
                                                           (unsigned short*)((char*)x2b + (12<<20)), nrm);
    unsigned short* Xh2 = (unsigned short*)((char*)x2b + (8<<20));
    unsigned short* Xl2 = (unsigned short*)((char*)x2b + (12<<20));

    // ---- EdgeConv 2 (MFMA conv: x2b only feeds classifier)
    knn64v4_kernel<<<dim3(N_/16, B_), 1024, 0, stream>>>(Xh2, Xl2, nrm, idx24);
    rescore_kernel<<<BN_/4, 256, 0, stream>>>(x1b, nrm, idx24, idx);
    pq2_kernel<<<1024, 256, 0, stream>>>(x1b, c2_w1, c2_b1, A, Bq);
    stats_l1_kernel<128><<<2048, 256, 0, stream>>>(A, Bq, idx, part);
    finalize_parts_kernel<<<128, 256, 0, stream>>>(part, 2048, 128, 1.0/655360.0, st2);
    prep_w2t_kernel<<<128*128/256, 256, 0, stream>>>(c2_w2, w2th, w2tl, 128);
    conv_l2_mfma_kernel<128><<<2048, 256, 0, stream>>>(A, Bq, idx, st2, c2_g1, c2_be1, w2th, w2tl, c2_b2, zmax, zmin, part);
    finalize_parts_kernel<<<128, 256, 0, stream>>>(part, 2048, 128, 1.0/655360.0, st3);
    conv_fin_kernel<128><<<BN_*128/256, 256, 0, stream>>>(zmax, zmin, st3, c2_g2, c2_be2, x2b);

    // ---- classifier
    cls1_kernel<<<dim3(512,2), 256, 0, stream>>>(x1b, x2b, cls_w1, cls_b1, A, partC);
    finalize_parts_kernel<<<128, 256, 0, stream>>>(partC, 512, 128, 1.0/32768.0, st4);
    cls_fin_kernel<<<BN_/4, 256, 0, stream>>>(A, st4, cls_g1, cls_be1, cls_w2, cls_b2, (float*)d_out);
}